// Round 1
// 496.120 us; speedup vs baseline: 1.2008x; 1.2008x over previous
//
#include <hip/hip_runtime.h>
#include <cstddef>

// Problem constants: B=8, C=512, N=4096, M=1024. Inputs f32, output f32.
#define Bn 8
#define Cd 512
#define Nn 4096
#define Mm 1024

typedef __attribute__((ext_vector_type(8))) short s8v;
typedef __attribute__((ext_vector_type(4))) float v4f;
typedef __attribute__((ext_vector_type(16))) float v16f;

__device__ __forceinline__ float b2f(unsigned short u) {
    union { unsigned int i; float f; } v; v.i = ((unsigned int)u) << 16; return v.f;
}
__device__ __forceinline__ unsigned short f2b(float f) {
    union { float f; unsigned int i; } v; v.f = f;
    unsigned int x = v.i;
    unsigned int r = (x + 0x7FFFu + ((x >> 16) & 1u)) >> 16;  // RNE
    return (unsigned short)r;
}
__device__ __forceinline__ v4f mfma16(s8v a, s8v b, v4f c) {
    return __builtin_amdgcn_mfma_f32_16x16x32_bf16(a, b, c, 0, 0, 0);
}
__device__ __forceinline__ v16f mfma32(s8v a, s8v b, v16f c) {
    return __builtin_amdgcn_mfma_f32_32x32x16_bf16(a, b, c, 0, 0, 0);
}

// ---------------------------------------------------------------------------
// MFMA GEMM: D[o][n] = sum_c W[o][c] * X[c][n], per batch.
// MODE 0: f32  store D[o][n]              (skip -> out)
// MODE 1: bf16 store D[o][n]              (legacy V layout, unused fast path)
// MODE 2: bf16 store D^T[n][o]            (Q -> Qt[n][c]; fallback K/V)
// MODE 3: bf16 store K as 32x32x16 MFMA A-fragments:
//         Kf[((mt*32 + kb)*64 + lane)*8 + e], mt=m/32, kb=c/16,
//         lane=(m&31)+32*((c>>3)&1), e=c&7.   (o-dim = c, n-dim = m)
// MODE 4: bf16 store V as 32x32x16 MFMA B-fragments:
//         Vf[((ct*64 + mb)*64 + lane)*8 + e], ct=c/32, mb=m/16,
//         lane=(c&31)+32*((m>>3)&1), e=m&7.   (o-dim = c, n-dim = m)
// Fragment layouts make the attention K/V loads wave-coalesced (base+lane*16B).
// ---------------------------------------------------------------------------
template <int MODE>
__global__ __launch_bounds__(256) void gemm_mfma(const float* __restrict__ W,
                                                 const float* __restrict__ X,
                                                 float* __restrict__ Yf,
                                                 unsigned short* __restrict__ Yb,
                                                 int Nx) {
    __shared__ short Xs[64][40];
    __shared__ short Tt[16][72];
    __shared__ __align__(16) short Vst[4][16][80];   // MODE 4 per-wave transpose
    const int t = threadIdx.x;
    const int w = t >> 6, lq = t & 15, quad = (t >> 4) & 3;
    const int b = blockIdx.z, o0 = blockIdx.y * 64, n0 = blockIdx.x * 64;
    const float* Xb = X + (size_t)b * Cd * Nx;
    const float* Wrow = W + (size_t)(o0 + w * 16 + lq) * Cd;

    v4f acc[4];
#pragma unroll
    for (int i = 0; i < 4; ++i) acc[i] = (v4f){0.f, 0.f, 0.f, 0.f};

    for (int c0 = 0; c0 < Cd; c0 += 32) {
#pragma unroll
        for (int p = 0; p < 2; ++p) {
            int i = t + p * 256;
            int c = i >> 4;
            int n4 = (i & 15) * 4;
            float4 x = *(const float4*)(Xb + (size_t)(c0 + c) * Nx + n0 + n4);
            Xs[n4 + 0][c] = (short)f2b(x.x); Xs[n4 + 1][c] = (short)f2b(x.y);
            Xs[n4 + 2][c] = (short)f2b(x.z); Xs[n4 + 3][c] = (short)f2b(x.w);
        }
        union { unsigned short h[8]; s8v s; } af;
        {
            float4 wa = *(const float4*)(Wrow + c0 + quad * 8);
            float4 wb = *(const float4*)(Wrow + c0 + quad * 8 + 4);
            af.h[0] = f2b(wa.x); af.h[1] = f2b(wa.y); af.h[2] = f2b(wa.z); af.h[3] = f2b(wa.w);
            af.h[4] = f2b(wb.x); af.h[5] = f2b(wb.y); af.h[6] = f2b(wb.z); af.h[7] = f2b(wb.w);
        }
        __syncthreads();
#pragma unroll
        for (int nt = 0; nt < 4; ++nt) {
            s8v bf = *(const s8v*)(&Xs[nt * 16 + lq][quad * 8]);
            acc[nt] = mfma16(af.s, bf, acc[nt]);
        }
        __syncthreads();
    }

    if (MODE == 0 || MODE == 1) {
#pragma unroll
        for (int nt = 0; nt < 4; ++nt)
#pragma unroll
            for (int r = 0; r < 4; ++r) {
                int o = o0 + w * 16 + quad * 4 + r;
                int n = n0 + nt * 16 + lq;
                size_t idx = ((size_t)b * Cd + o) * Nx + n;
                if (MODE == 0) Yf[idx] = acc[nt][r];
                else           Yb[idx] = f2b(acc[nt][r]);
            }
    } else if (MODE == 2) {
#pragma unroll
        for (int nt = 0; nt < 4; ++nt) {
#pragma unroll
            for (int r = 0; r < 4; ++r)
                Tt[lq][w * 16 + quad * 4 + r] = (short)f2b(acc[nt][r]);
            __syncthreads();
            int nrow = t >> 4, o4 = (t & 15) * 4;
            ushort4 val = *(const ushort4*)(&Tt[nrow][o4]);
            *(ushort4*)(Yb + ((size_t)b * Nx + n0 + nt * 16 + nrow) * Cd + o0 + o4) = val;
            __syncthreads();
        }
    } else if (MODE == 3) {
        // K-fragment store, direct from acc.
        // c = o0 + w*16 + quad*4 + r  (4 consecutive c per thread)
        // m = n0 + nt*16 + lq
        const int kb = (o0 + w * 16) >> 4;       // quad*4+r < 16 never crosses kb
        const int half = quad >> 1;              // (c>>3)&1
        const int ebase = (quad & 1) * 4;        // c&7 base
        unsigned short* Kb = Yb + (size_t)b * Nx * Cd;
#pragma unroll
        for (int nt = 0; nt < 4; ++nt) {
            int m = n0 + nt * 16 + lq;
            int mt = m >> 5;
            int lf = (m & 31) + 32 * half;
            ushort4 v;
            v.x = f2b(acc[nt][0]); v.y = f2b(acc[nt][1]);
            v.z = f2b(acc[nt][2]); v.w = f2b(acc[nt][3]);
            *(ushort4*)(Kb + ((size_t)(mt * 32 + kb) * 64 + lf) * 8 + ebase) = v;
        }
    } else {   // MODE == 4: V-fragment store via per-wave LDS transpose
#pragma unroll
        for (int nt = 0; nt < 4; ++nt)
#pragma unroll
            for (int r = 0; r < 4; ++r)
                Vst[w][quad * 4 + r][nt * 16 + lq] = (short)f2b(acc[nt][r]);
        __syncthreads();
        unsigned short* Vbp = Yb + (size_t)b * Nx * Cd;
        const int lane = t & 63;
#pragma unroll
        for (int k = 0; k < 2; ++k) {
            int u = lane + k * 64;               // unit 0..127: 16 c x 8 m-units
            int c_loc = u >> 3, m8 = u & 7;
            int c = o0 + w * 16 + c_loc;
            int m = n0 + m8 * 8;
            int ct = c >> 5, mb = m >> 4;
            int lf = (c & 31) + 32 * (m8 & 1);
            uint4 v = *(const uint4*)(&Vst[w][c_loc][m8 * 8]);
            *(uint4*)(Vbp + ((size_t)(ct * 64 + mb) * 64 + lf) * 8) = v;
        }
    }
}

// ---------------------------------------------------------------------------
// attn_v2: flash attention, 32x32x16 MFMAs. K/V read directly from global in
// MFMA-fragment-tiled layout (wave-uniform base + lane*16B => fully coalesced
// 1KiB/instr; previously per-lane gathers at 1-2KB lane stride = ~32 cache
// lines/instr, which made the kernel L1-request-bound at 10% MfmaUtil).
// Q staged once in LDS (shared by 4 waves), P through LDS.
// Block = 256 thr / 4 waves handles (b, 32 q-rows). m-chunk = 128.
// QK^T computed as S^T = K x Q^T: wave w owns m-tile w (32 m); softmax over m
// is per-lane in-register (+1 shfl). PV: D[n][c] = P x V, wave w owns c-tiles
// {ti*128 + w*32}. Epilogue: out += O/l via LDS transpose, coalesced.
// Grid: 1024 linear; b = bid&7 (XCD affinity: batch's K+V (4MB bf16 frags)
// fits XCD L2).
// ---------------------------------------------------------------------------
__global__ __launch_bounds__(256, 2) void attn_v2(const unsigned short* __restrict__ Qt,
                                                  const unsigned short* __restrict__ Kf,
                                                  const unsigned short* __restrict__ Vf,
                                                  float* __restrict__ out) {
    __shared__ __align__(16) unsigned char Ls[42880];
    unsigned char* Lq = Ls;                                   // Qs: 32x512 bf16 swizzled (32768 B)
    unsigned short* Pb = (unsigned short*)(Ls + 32768);       // Pb[32][136] bf16 (8704 B)
    float* pmaxS  = (float*)(Ls + 41472);                     // [32][4]
    float* psumS  = (float*)(Ls + 41984);                     // [32][4]
    float* muS    = (float*)(Ls + 42496);                     // [32]
    float* ssumS  = (float*)(Ls + 42624);                     // [32]
    float* alphaS = (float*)(Ls + 42752);                     // [32]
    float* OtA    = (float*)Ls;                               // epilogue alias: [4][32][36] f32

    const int t = threadIdx.x;
    const int l = t & 63, w = t >> 6;
    const int lcol = l & 31, lhalf = l >> 5;
    const int bid = blockIdx.x;
    const int b = bid & 7, n0 = (bid >> 3) * 32;

    // ---- stage Q (32 rows x 512 c, bf16) swizzled: unit u of row n at u^(n&15)
    {
        const unsigned short* qb = Qt + ((size_t)b * Nn + n0) * Cd;
#pragma unroll
        for (int i = 0; i < 8; ++i) {
            int s = i * 256 + t;           // unit id 0..2047
            int n = s >> 6, u = s & 63;
            uint4 v = *(const uint4*)(qb + (size_t)n * Cd + u * 8);
            *(uint4*)(Lq + ((n * 64 + (u ^ (n & 15))) << 4)) = v;
        }
    }
    if (t < 32) { muS[t] = -1e30f; ssumS[t] = 0.f; }

    v16f o_acc[4];
#pragma unroll
    for (int i = 0; i < 4; ++i)
#pragma unroll
        for (int r = 0; r < 16; ++r) o_acc[i][r] = 0.f;
    __syncthreads();

    // Fragment bases: per-lane 16B at lane*16 within each 1KiB unit group.
    const unsigned short* Kfb = Kf + (size_t)b * Mm * Cd + (size_t)l * 8;
    const unsigned short* Vfb = Vf + (size_t)b * Cd * Mm + (size_t)l * 8;
    const int qrow = lcol * 64;     // Q LDS unit base for col n=lcol
    const int swz = lcol & 15;
    const float sc = 0.04419417382415922f;   // 1/sqrt(512)

    for (int m0 = 0; m0 < Mm; m0 += 128) {
        // ---- QK^T: S^T[m = w*32 + regmap][n = lcol], K fragments from global
        v16f st;
#pragma unroll
        for (int r = 0; r < 16; ++r) st[r] = 0.f;
        // kb step = 64 lanes * 8 elems = 512 elems (1KiB)
        const unsigned short* kp = Kfb + (size_t)(((m0 >> 5) + w) * 32) * 512;
#pragma unroll
        for (int kb8 = 0; kb8 < 4; ++kb8) {
            uint4 ka[8];
#pragma unroll
            for (int j = 0; j < 8; ++j) ka[j] = *(const uint4*)(kp + (size_t)(kb8 * 8 + j) * 512);
#pragma unroll
            for (int j = 0; j < 8; ++j) {
                int kb = kb8 * 8 + j;
                s8v qf = *(const s8v*)(Lq + ((qrow + ((kb * 2 + lhalf) ^ swz)) << 4));
                union { uint4 u; s8v s; } av; av.u = ka[j];
                st = mfma32(av.s, qf, st);
            }
        }
        // ---- softmax bookkeeping (per-lane over 16 regs = 16 of 32 m) ----
#pragma unroll
        for (int r = 0; r < 16; ++r) st[r] *= sc;
        float tm = st[0];
#pragma unroll
        for (int r = 1; r < 16; ++r) tm = fmaxf(tm, st[r]);
        tm = fmaxf(tm, __shfl_xor(tm, 32));
        if (l < 32) pmaxS[l * 4 + w] = tm;
        __syncthreads();   // S1
        if (t < 32) {
            float mx = muS[t];
            mx = fmaxf(mx, fmaxf(fmaxf(pmaxS[t * 4], pmaxS[t * 4 + 1]),
                                 fmaxf(pmaxS[t * 4 + 2], pmaxS[t * 4 + 3])));
            alphaS[t] = __expf(muS[t] - mx);
            muS[t] = mx;
        }
        __syncthreads();   // S2
        {
            float mxn = muS[lcol];
            float e[16], rs = 0.f;
#pragma unroll
            for (int r = 0; r < 16; ++r) { e[r] = __expf(st[r] - mxn); rs += e[r]; }
            rs += __shfl_xor(rs, 32);
            if (l < 32) psumS[l * 4 + w] = rs;
#pragma unroll
            for (int rg = 0; rg < 4; ++rg) {
                ushort4 pk;
                pk.x = f2b(e[rg * 4 + 0]); pk.y = f2b(e[rg * 4 + 1]);
                pk.z = f2b(e[rg * 4 + 2]); pk.w = f2b(e[rg * 4 + 3]);
                *(ushort4*)(Pb + lcol * 136 + w * 32 + 8 * rg + 4 * lhalf) = pk;
            }
        }
        __syncthreads();   // S3
        if (t < 32)
            ssumS[t] = ssumS[t] * alphaS[t] +
                       psumS[t * 4] + psumS[t * 4 + 1] + psumS[t * 4 + 2] + psumS[t * 4 + 3];

        // ---- PV: D[n = regmap][c = lcol], P from LDS (reg-cached), V frags global
        float ar[16];
#pragma unroll
        for (int r = 0; r < 16; ++r)
            ar[r] = alphaS[(r & 3) + 8 * (r >> 2) + 4 * lhalf];
#pragma unroll
        for (int ti = 0; ti < 4; ++ti)
#pragma unroll
            for (int r = 0; r < 16; ++r) o_acc[ti][r] *= ar[r];

        s8v pA[8];
#pragma unroll
        for (int kb = 0; kb < 8; ++kb)
            pA[kb] = *(const s8v*)(Pb + lcol * 136 + kb * 16 + lhalf * 8);

#pragma unroll
        for (int ti = 0; ti < 4; ++ti) {
            // ct = ti*4 + w ; mb = m0/16 + kb ; unit step = 512 elems
            const unsigned short* vc = Vfb + (size_t)((ti * 4 + w) * 64 + (m0 >> 4)) * 512;
            uint4 vb8[8];
#pragma unroll
            for (int kb = 0; kb < 8; ++kb) vb8[kb] = *(const uint4*)(vc + (size_t)kb * 512);
#pragma unroll
            for (int kb = 0; kb < 8; ++kb) {
                union { uint4 u; s8v s; } bv; bv.u = vb8[kb];
                o_acc[ti] = mfma32(pA[kb], bv.s, o_acc[ti]);
            }
        }
        __syncthreads();   // protect Pb/pmax/psum for next chunk
    }

    // ---- epilogue: out[b][c][n0..n0+31] += O / l ----
    float inv[16];
#pragma unroll
    for (int r = 0; r < 16; ++r)
        inv[r] = 1.0f / ssumS[(r & 3) + 8 * (r >> 2) + 4 * lhalf];

    float* OtW = OtA + w * 32 * 36;
#pragma unroll
    for (int ti = 0; ti < 4; ++ti) {
#pragma unroll
        for (int r = 0; r < 16; ++r)
            OtW[lcol * 36 + (r & 3) + 8 * (r >> 2) + 4 * lhalf] = o_acc[ti][r] * inv[r];
        __syncthreads();
        {
            int cloc = l >> 1, half = l & 1;
            int cabs = ti * 128 + w * 32 + cloc;
            const float* src = OtW + cloc * 36 + half * 16;
            float* op = out + ((size_t)b * Cd + cabs) * Nn + n0 + half * 16;
#pragma unroll
            for (int j = 0; j < 4; ++j) {
                float4 a = *(const float4*)(src + j * 4);
                float4 g = *(const float4*)(op + j * 4);
                g.x += a.x; g.y += a.y; g.z += a.z; g.w += a.w;
                *(float4*)(op + j * 4) = g;
            }
        }
        __syncthreads();
    }
}

// ---------------------------------------------------------------------------
// Fallback VALU attention (round-3 proven) for small ws_size.
// ---------------------------------------------------------------------------
__device__ __forceinline__ float u2lo(unsigned int u) {
    union { unsigned int i; float f; } v; v.i = u << 16; return v.f;
}
__device__ __forceinline__ float u2hi(unsigned int u) {
    union { unsigned int i; float f; } v; v.i = u & 0xFFFF0000u; return v.f;
}

__global__ __launch_bounds__(256) void attn_k(const float* __restrict__ up,
                                              const float* __restrict__ Wq,
                                              const unsigned short* __restrict__ Ktb,
                                              const unsigned short* __restrict__ Vtb,
                                              float* __restrict__ out) {
    __shared__ float Qs[16][516];
    __shared__ __align__(16) unsigned char Sraw[24576];
    unsigned short (*Us)[16]  = reinterpret_cast<unsigned short(*)[16]>(Sraw);
    unsigned short (*Wt)[512] = reinterpret_cast<unsigned short(*)[512]>(Sraw + 16384);
    float (*Ps)[65] = reinterpret_cast<float(*)[65]>(Sraw);
    float* mu_s     = reinterpret_cast<float*>(Sraw + 4160);
    float* ssum_s   = reinterpret_cast<float*>(Sraw + 4224);
    float* alpha_s  = reinterpret_cast<float*>(Sraw + 4288);

    const int t = threadIdx.x;
    const int b = blockIdx.y;
    const int n0 = blockIdx.x * 16;
    const int row = t & 15;
    const int grp = t >> 4;

    for (int i = t; i < Cd * 16; i += 256) {
        int c = i >> 4, r = i & 15;
        Us[c][r] = f2b(up[((size_t)b * Cd + c) * Nn + n0 + r]);
    }
    __syncthreads();

    float acc[32];
#pragma unroll
    for (int j = 0; j < 32; ++j) acc[j] = 0.f;

    for (int k0 = 0; k0 < Cd; k0 += 8) {
        for (int i = t; i < 1024; i += 256) {
            int oc = i >> 1;
            int kc = (i & 1) * 4;
            float4 wv = *(const float4*)(Wq + (size_t)oc * Cd + k0 + kc);
            Wt[kc + 0][oc] = f2b(wv.x); Wt[kc + 1][oc] = f2b(wv.y);
            Wt[kc + 2][oc] = f2b(wv.z); Wt[kc + 3][oc] = f2b(wv.w);
        }
        __syncthreads();
#pragma unroll
        for (int k = 0; k < 8; ++k) {
            float u = b2f(Us[k0 + k][row]);
            const ushort4* wr = (const ushort4*)(&Wt[k][grp * 32]);
#pragma unroll
            for (int j4 = 0; j4 < 8; ++j4) {
                ushort4 wv = wr[j4];
                acc[j4 * 4 + 0] += u * b2f(wv.x);
                acc[j4 * 4 + 1] += u * b2f(wv.y);
                acc[j4 * 4 + 2] += u * b2f(wv.z);
                acc[j4 * 4 + 3] += u * b2f(wv.w);
            }
        }
        __syncthreads();
    }

    const float scale = 0.04419417382415922f;
#pragma unroll
    for (int j = 0; j < 32; ++j) Qs[row][grp * 32 + j] = acc[j] * scale;
    if (t < 16) { mu_s[t] = -1e30f; ssum_s[t] = 0.f; }
#pragma unroll
    for (int j = 0; j < 32; ++j) acc[j] = 0.f;
    __syncthreads();

    const float4* qr = (const float4*)(&Qs[row][0]);

    for (int m0 = 0; m0 < Mm; m0 += 64) {
        {
            int mb = m0 + grp * 4;
            const uint4* K0 = (const uint4*)(Ktb + ((size_t)b * Mm + mb + 0) * Cd);
            const uint4* K1 = (const uint4*)(Ktb + ((size_t)b * Mm + mb + 1) * Cd);
            const uint4* K2 = (const uint4*)(Ktb + ((size_t)b * Mm + mb + 2) * Cd);
            const uint4* K3 = (const uint4*)(Ktb + ((size_t)b * Mm + mb + 3) * Cd);
            float a0 = 0.f, a1 = 0.f, a2 = 0.f, a3 = 0.f;
#pragma unroll 4
            for (int c8 = 0; c8 < Cd / 8; ++c8) {
                float4 qa = qr[2 * c8], qb = qr[2 * c8 + 1];
                uint4 k0v = K0[c8], k1v = K1[c8], k2v = K2[c8], k3v = K3[c8];
                a0 += qa.x * u2lo(k0v.x) + qa.y * u2hi(k0v.x) + qa.z * u2lo(k0v.y) + qa.w * u2hi(k0v.y)
                    + qb.x * u2lo(k0v.z) + qb.y * u2hi(k0v.z) + qb.z * u2lo(k0v.w) + qb.w * u2hi(k0v.w);
                a1 += qa.x * u2lo(k1v.x) + qa.y * u2hi(k1v.x) + qa.z * u2lo(k1v.y) + qa.w * u2hi(k1v.y)
                    + qb.x * u2lo(k1v.z) + qb.y * u2hi(k1v.z) + qb.z * u2lo(k1v.w) + qb.w * u2hi(k1v.w);
                a2 += qa.x * u2lo(k2v.x) + qa.y * u2hi(k2v.x) + qa.z * u2lo(k2v.y) + qa.w * u2hi(k2v.y)
                    + qb.x * u2lo(k2v.z) + qb.y * u2hi(k2v.z) + qb.z * u2lo(k2v.w) + qb.w * u2hi(k2v.w);
                a3 += qa.x * u2lo(k3v.x) + qa.y * u2hi(k3v.x) + qa.z * u2lo(k3v.y) + qa.w * u2hi(k3v.y)
                    + qb.x * u2lo(k3v.z) + qb.y * u2hi(k3v.z) + qb.z * u2lo(k3v.w) + qb.w * u2hi(k3v.w);
            }
            Ps[row][grp * 4 + 0] = a0;
            Ps[row][grp * 4 + 1] = a1;
            Ps[row][grp * 4 + 2] = a2;
            Ps[row][grp * 4 + 3] = a3;
        }
        __syncthreads();
        if (t < 16) {
            float mold = mu_s[t];
            float mx = mold;
            for (int m = 0; m < 64; ++m) mx = fmaxf(mx, Ps[t][m]);
            float al = __expf(mold - mx);
            float s = ssum_s[t] * al;
            for (int m = 0; m < 64; ++m) {
                float p = __expf(Ps[t][m] - mx);
                Ps[t][m] = p;
                s += p;
            }
            mu_s[t] = mx; ssum_s[t] = s; alpha_s[t] = al;
        }
        __syncthreads();
        {
            float arr = alpha_s[row];
#pragma unroll
            for (int j = 0; j < 32; ++j) acc[j] *= arr;
            const unsigned short* Vbase = Vtb + (size_t)b * Mm * Cd + (size_t)grp * 32;
            for (int m = 0; m < 64; ++m) {
                float p = Ps[row][m];
                const uint4* vr = (const uint4*)(Vbase + (size_t)(m0 + m) * Cd);
#pragma unroll
                for (int j4 = 0; j4 < 4; ++j4) {
                    uint4 v = vr[j4];
                    acc[j4 * 8 + 0] += p * u2lo(v.x); acc[j4 * 8 + 1] += p * u2hi(v.x);
                    acc[j4 * 8 + 2] += p * u2lo(v.y); acc[j4 * 8 + 3] += p * u2hi(v.y);
                    acc[j4 * 8 + 4] += p * u2lo(v.z); acc[j4 * 8 + 5] += p * u2hi(v.z);
                    acc[j4 * 8 + 6] += p * u2lo(v.w); acc[j4 * 8 + 7] += p * u2hi(v.w);
                }
            }
        }
        __syncthreads();
    }

    float invv = 1.0f / ssum_s[row];
#pragma unroll
    for (int j = 0; j < 32; ++j) {
        int c = grp * 32 + j;
        size_t idx = ((size_t)b * Cd + c) * Nn + n0 + row;
        out[idx] = out[idx] + acc[j] * invv;
    }
}

// ---------------------------------------------------------------------------
extern "C" void kernel_launch(void* const* d_in, const int* in_sizes, int n_in,
                              void* d_out, int out_size, void* d_ws, size_t ws_size,
                              hipStream_t stream) {
    const float* up   = (const float*)d_in[0];
    const float* down = (const float*)d_in[1];
    const float* Wq   = (const float*)d_in[2];
    const float* Wk   = (const float*)d_in[3];
    const float* Wv   = (const float*)d_in[4];
    const float* Wsk  = (const float*)d_in[5];
    float* out = (float*)d_out;

    const size_t szK = (size_t)Bn * Mm * Cd;   // bf16 elems: 4M (8 MiB)
    const size_t szQ = (size_t)Bn * Nn * Cd;   // bf16 elems: 16M (32 MiB)

    if (ws_size >= 2 * szK * 2 + szQ * 2) {
        // Fast path: Kf (frag) | Vf (frag) | Qt[n][c], all bf16. 48 MiB.
        unsigned short* Kf = (unsigned short*)d_ws;
        unsigned short* Vf = Kf + szK;
        unsigned short* Qt = Vf + szK;
        gemm_mfma<3><<<dim3(Mm / 64, Cd / 64, Bn), 256, 0, stream>>>(Wk, down, nullptr, Kf, Mm);
        gemm_mfma<4><<<dim3(Mm / 64, Cd / 64, Bn), 256, 0, stream>>>(Wv, down, nullptr, Vf, Mm);
        gemm_mfma<2><<<dim3(Nn / 64, Cd / 64, Bn), 256, 0, stream>>>(Wq, up, nullptr, Qt, Nn);
        gemm_mfma<0><<<dim3(Nn / 64, Cd / 64, Bn), 256, 0, stream>>>(Wsk, up, out, nullptr, Nn);
        attn_v2<<<dim3((Nn / 32) * Bn), 256, 0, stream>>>(Qt, Kf, Vf, out);
    } else {
        // Fallback (16 MiB ws): round-3 proven VALU attention.
        unsigned short* Ktb = (unsigned short*)d_ws;
        unsigned short* Vtb = Ktb + szK;
        gemm_mfma<2><<<dim3(Mm / 64, Cd / 64, Bn), 256, 0, stream>>>(Wk, down, nullptr, Ktb, Mm);
        gemm_mfma<2><<<dim3(Mm / 64, Cd / 64, Bn), 256, 0, stream>>>(Wv, down, nullptr, Vtb, Mm);
        gemm_mfma<0><<<dim3(Nn / 64, Cd / 64, Bn), 256, 0, stream>>>(Wsk, up, out, nullptr, Nn);
        attn_k<<<dim3(Nn / 16, Bn), 256, 0, stream>>>(up, Wq, Ktb, Vtb, out);
    }
}

// Round 3
// 399.854 us; speedup vs baseline: 1.4899x; 1.2408x over previous
//
#include <hip/hip_runtime.h>
#include <cstddef>

// Problem constants: B=8, C=512, N=4096, M=1024. Inputs f32, output f32.
#define Bn 8
#define Cd 512
#define Nn 4096
#define Mm 1024

typedef __attribute__((ext_vector_type(8))) short s8v;
typedef __attribute__((ext_vector_type(4))) float v4f;
typedef __attribute__((ext_vector_type(16))) float v16f;

__device__ __forceinline__ float b2f(unsigned short u) {
    union { unsigned int i; float f; } v; v.i = ((unsigned int)u) << 16; return v.f;
}
__device__ __forceinline__ unsigned short f2b(float f) {
    union { float f; unsigned int i; } v; v.f = f;
    unsigned int x = v.i;
    unsigned int r = (x + 0x7FFFu + ((x >> 16) & 1u)) >> 16;  // RNE
    return (unsigned short)r;
}
__device__ __forceinline__ v4f mfma16(s8v a, s8v b, v4f c) {
    return __builtin_amdgcn_mfma_f32_16x16x32_bf16(a, b, c, 0, 0, 0);
}
__device__ __forceinline__ v16f mfma32(s8v a, s8v b, v16f c) {
    return __builtin_amdgcn_mfma_f32_32x32x16_bf16(a, b, c, 0, 0, 0);
}

// ---------------------------------------------------------------------------
// convw: W f32[512][512] -> bf16, 4 weights into Wb[4][512][512].
// Removes per-K-step W f2b from the GEMM inner loop and halves W read traffic.
// ---------------------------------------------------------------------------
__global__ __launch_bounds__(256) void convw(const float* __restrict__ Wq, const float* __restrict__ Wk,
                                             const float* __restrict__ Wv, const float* __restrict__ Ws,
                                             unsigned short* __restrict__ Wb) {
    const float* S = (blockIdx.y == 0) ? Wq : (blockIdx.y == 1) ? Wk : (blockIdx.y == 2) ? Wv : Ws;
    int i = (blockIdx.x * 256 + threadIdx.x) * 4;
    float4 v = *(const float4*)(S + i);
    ushort4 u; u.x = f2b(v.x); u.y = f2b(v.y); u.z = f2b(v.z); u.w = f2b(v.w);
    *(ushort4*)(Wb + (size_t)blockIdx.y * 262144 + i) = u;
}

// ---------------------------------------------------------------------------
// gemm2: dual-output fused GEMM, 128n x 128o tile, 256 thr / 4 waves.
// D1[o][n] = W1[o][:]*X[:][n], D2[o][n] = W2[o][:]*X[:][n]  (X staged once).
// PAIRB=0: X=down (Nx=1024), W1=Wk->Kf (MFMA A-frags), W2=Wv->Vf (B-frags).
// PAIRB=1: X=up   (Nx=4096), W1=Wq->Qt[n][c] bf16,      W2=Wskip->out f32.
// Wave w owns o-rows [w*32, w*32+32) (2 ot subtiles), all 128 n (8 nt).
// 32 mfma16 / wave / 32-c K-step (vs 4 in the old 64x64 single-output GEMM).
// Grid 1D: b = bid&7 (one batch per XCD); the 4 o-panels of a (b, n-tile)
// are consecutive on that XCD -> X tile read from HBM once, then L2-hit.
// Fragment layouts (match attn_v2 reader):
//   Kf[((mt*32+kb)*64 + (m&31)+32*((c>>3)&1))*8 + (c&7)]
//   Vf[((ct*64+mb)*64 + (c&31)+32*((m>>3)&1))*8 + (m&7)]
// ---------------------------------------------------------------------------
template <int PAIRB>
__global__ __launch_bounds__(256, 2) void gemm2(const unsigned short* __restrict__ Wb,
                                                const float* __restrict__ X,
                                                float* __restrict__ outF,
                                                unsigned short* __restrict__ Y1,
                                                unsigned short* __restrict__ Y2) {
    constexpr int Nx = PAIRB ? Nn : Mm;
    __shared__ __align__(16) unsigned char raw[PAIRB ? 36864 : 18432];
    short (*Xs)[40] = reinterpret_cast<short(*)[40]>(raw);     // [128][40] bf16 staging

    const int t = threadIdx.x;
    const int w = t >> 6, lq = t & 15, quad = (t >> 4) & 3;
    const int bid = blockIdx.x;
    const int b = bid & 7, rest = bid >> 3;
    const int n0 = (rest >> 2) * 128, o0 = (rest & 3) * 128;
    const float* Xb = X + (size_t)b * Cd * Nx;
    const unsigned short* W1r = Wb + (size_t)(PAIRB ? 0 : 1) * 262144 + (size_t)(o0 + w * 32 + lq) * Cd;
    const unsigned short* W2r = Wb + (size_t)(PAIRB ? 3 : 2) * 262144 + (size_t)(o0 + w * 32 + lq) * Cd;

    v4f acc1[2][8], acc2[2][8];
#pragma unroll
    for (int ot = 0; ot < 2; ++ot)
#pragma unroll
        for (int nt = 0; nt < 8; ++nt) {
            acc1[ot][nt] = (v4f){0.f, 0.f, 0.f, 0.f};
            acc2[ot][nt] = (v4f){0.f, 0.f, 0.f, 0.f};
        }

    for (int c0 = 0; c0 < Cd; c0 += 32) {
        // X slice loads (coalesced: wave reads whole 512B n-rows)
        float4 xv[4];
#pragma unroll
        for (int p4 = 0; p4 < 4; ++p4) {
            int i = t + p4 * 256;
            xv[p4] = *(const float4*)(Xb + (size_t)(c0 + (i >> 5)) * Nx + n0 + (i & 31) * 4);
        }
        // W fragments (bf16, single 16B load each; issued early to hide latency)
        s8v af1[2], af2[2];
#pragma unroll
        for (int ot = 0; ot < 2; ++ot) {
            af1[ot] = *(const s8v*)(W1r + (size_t)ot * 16 * Cd + c0 + quad * 8);
            af2[ot] = *(const s8v*)(W2r + (size_t)ot * 16 * Cd + c0 + quad * 8);
        }
#pragma unroll
        for (int p4 = 0; p4 < 4; ++p4) {
            int i = t + p4 * 256;
            int c = i >> 5, n4 = (i & 31) * 4;
            Xs[n4 + 0][c] = (short)f2b(xv[p4].x); Xs[n4 + 1][c] = (short)f2b(xv[p4].y);
            Xs[n4 + 2][c] = (short)f2b(xv[p4].z); Xs[n4 + 3][c] = (short)f2b(xv[p4].w);
        }
        __syncthreads();
#pragma unroll
        for (int nt = 0; nt < 8; ++nt) {
            s8v bf = *(const s8v*)(&Xs[nt * 16 + lq][quad * 8]);
            acc1[0][nt] = mfma16(af1[0], bf, acc1[0][nt]);
            acc1[1][nt] = mfma16(af1[1], bf, acc1[1][nt]);
            acc2[0][nt] = mfma16(af2[0], bf, acc2[0][nt]);
            acc2[1][nt] = mfma16(af2[1], bf, acc2[1][nt]);
        }
        __syncthreads();
    }

    if (PAIRB) {
        // ---- acc2 (skip) -> out f32 [b][o][n]
#pragma unroll
        for (int ot = 0; ot < 2; ++ot)
#pragma unroll
            for (int nt = 0; nt < 8; ++nt)
#pragma unroll
                for (int r = 0; r < 4; ++r) {
                    int o = o0 + w * 32 + ot * 16 + quad * 4 + r;
                    int n = n0 + nt * 16 + lq;
                    outF[((size_t)b * Cd + o) * Nx + n] = acc2[ot][nt][r];
                }
        // ---- acc1 (Q) -> Qt[n][c] bf16 via full-tile LDS transpose
        short (*T2)[144] = reinterpret_cast<short(*)[144]>(raw);   // [128][144]
#pragma unroll
        for (int ot = 0; ot < 2; ++ot)
#pragma unroll
            for (int nt = 0; nt < 8; ++nt)
#pragma unroll
                for (int r = 0; r < 4; ++r)
                    T2[nt * 16 + lq][w * 32 + ot * 16 + quad * 4 + r] = (short)f2b(acc1[ot][nt][r]);
        __syncthreads();
        {
            int row = t >> 1, ob = (t & 1) * 64;
            unsigned short* qp = Y1 + ((size_t)b * Nx + n0 + row) * Cd + o0 + ob;
#pragma unroll
            for (int j = 0; j < 8; ++j)
                *(uint4*)(qp + j * 8) = *(const uint4*)(&T2[row][ob + j * 8]);
        }
    } else {
        // ---- acc1 (K) -> Kf fragments, direct from acc
        const int half = quad >> 1, ebase = (quad & 1) * 4;
        unsigned short* Kb = Y1 + (size_t)b * Mm * Cd;
#pragma unroll
        for (int ot = 0; ot < 2; ++ot) {
            int kb = (o0 + w * 32 + ot * 16) >> 4;
#pragma unroll
            for (int nt = 0; nt < 8; ++nt) {
                int m = n0 + nt * 16 + lq;
                int mt = m >> 5, lf = (m & 31) + 32 * half;
                ushort4 v;
                v.x = f2b(acc1[ot][nt][0]); v.y = f2b(acc1[ot][nt][1]);
                v.z = f2b(acc1[ot][nt][2]); v.w = f2b(acc1[ot][nt][3]);
                *(ushort4*)(Kb + ((size_t)(mt * 32 + kb) * 64 + lf) * 8 + ebase) = v;
            }
        }
        // ---- acc2 (V) -> Vf fragments via per-wave LDS transpose (no barriers:
        // wave w only touches Vst[w]; same-wave ds ordering via lgkmcnt)
        short (*Vst)[16][144] = reinterpret_cast<short(*)[16][144]>(raw);  // [4][16][144]
        unsigned short* Vbp = Y2 + (size_t)b * Cd * Mm;
        const int lane = t & 63;
#pragma unroll
        for (int ot = 0; ot < 2; ++ot) {
#pragma unroll
            for (int nt = 0; nt < 8; ++nt)
#pragma unroll
                for (int r = 0; r < 4; ++r)
                    Vst[w][quad * 4 + r][nt * 16 + lq] = (short)f2b(acc2[ot][nt][r]);
#pragma unroll
            for (int k = 0; k < 4; ++k) {
                int u = lane + k * 64;                 // 0..255: 16 c x 16 m-units
                int c_loc = u >> 4, m8 = u & 15;
                int c = o0 + w * 32 + ot * 16 + c_loc;
                int m = n0 + m8 * 8;
                int ct = c >> 5, mb = m >> 4;
                int lf = (c & 31) + 32 * (m8 & 1);
                uint4 v = *(const uint4*)(&Vst[w][c_loc][m8 * 8]);
                *(uint4*)(Vbp + ((size_t)(ct * 64 + mb) * 64 + lf) * 8) = v;
            }
        }
    }
}

// ---------------------------------------------------------------------------
// MFMA GEMM (legacy, kept for fallback paths): D[o][n] = sum_c W[o][c]*X[c][n].
// MODE 0: f32 store  MODE 2: bf16 store D^T  MODE 3: Kf frags  MODE 4: Vf frags
// ---------------------------------------------------------------------------
template <int MODE>
__global__ __launch_bounds__(256) void gemm_mfma(const float* __restrict__ W,
                                                 const float* __restrict__ X,
                                                 float* __restrict__ Yf,
                                                 unsigned short* __restrict__ Yb,
                                                 int Nx) {
    __shared__ short Xs[64][40];
    __shared__ short Tt[16][72];
    __shared__ __align__(16) short Vst[4][16][80];
    const int t = threadIdx.x;
    const int w = t >> 6, lq = t & 15, quad = (t >> 4) & 3;
    const int b = blockIdx.z, o0 = blockIdx.y * 64, n0 = blockIdx.x * 64;
    const float* Xb = X + (size_t)b * Cd * Nx;
    const float* Wrow = W + (size_t)(o0 + w * 16 + lq) * Cd;

    v4f acc[4];
#pragma unroll
    for (int i = 0; i < 4; ++i) acc[i] = (v4f){0.f, 0.f, 0.f, 0.f};

    for (int c0 = 0; c0 < Cd; c0 += 32) {
#pragma unroll
        for (int p = 0; p < 2; ++p) {
            int i = t + p * 256;
            int c = i >> 4;
            int n4 = (i & 15) * 4;
            float4 x = *(const float4*)(Xb + (size_t)(c0 + c) * Nx + n0 + n4);
            Xs[n4 + 0][c] = (short)f2b(x.x); Xs[n4 + 1][c] = (short)f2b(x.y);
            Xs[n4 + 2][c] = (short)f2b(x.z); Xs[n4 + 3][c] = (short)f2b(x.w);
        }
        union { unsigned short h[8]; s8v s; } af;
        {
            float4 wa = *(const float4*)(Wrow + c0 + quad * 8);
            float4 wb = *(const float4*)(Wrow + c0 + quad * 8 + 4);
            af.h[0] = f2b(wa.x); af.h[1] = f2b(wa.y); af.h[2] = f2b(wa.z); af.h[3] = f2b(wa.w);
            af.h[4] = f2b(wb.x); af.h[5] = f2b(wb.y); af.h[6] = f2b(wb.z); af.h[7] = f2b(wb.w);
        }
        __syncthreads();
#pragma unroll
        for (int nt = 0; nt < 4; ++nt) {
            s8v bf = *(const s8v*)(&Xs[nt * 16 + lq][quad * 8]);
            acc[nt] = mfma16(af.s, bf, acc[nt]);
        }
        __syncthreads();
    }

    if (MODE == 0 || MODE == 1) {
#pragma unroll
        for (int nt = 0; nt < 4; ++nt)
#pragma unroll
            for (int r = 0; r < 4; ++r) {
                int o = o0 + w * 16 + quad * 4 + r;
                int n = n0 + nt * 16 + lq;
                size_t idx = ((size_t)b * Cd + o) * Nx + n;
                if (MODE == 0) Yf[idx] = acc[nt][r];
                else           Yb[idx] = f2b(acc[nt][r]);
            }
    } else if (MODE == 2) {
#pragma unroll
        for (int nt = 0; nt < 4; ++nt) {
#pragma unroll
            for (int r = 0; r < 4; ++r)
                Tt[lq][w * 16 + quad * 4 + r] = (short)f2b(acc[nt][r]);
            __syncthreads();
            int nrow = t >> 4, o4 = (t & 15) * 4;
            ushort4 val = *(const ushort4*)(&Tt[nrow][o4]);
            *(ushort4*)(Yb + ((size_t)b * Nx + n0 + nt * 16 + nrow) * Cd + o0 + o4) = val;
            __syncthreads();
        }
    } else if (MODE == 3) {
        const int kb = (o0 + w * 16) >> 4;
        const int half = quad >> 1;
        const int ebase = (quad & 1) * 4;
        unsigned short* Kb = Yb + (size_t)b * Nx * Cd;
#pragma unroll
        for (int nt = 0; nt < 4; ++nt) {
            int m = n0 + nt * 16 + lq;
            int mt = m >> 5;
            int lf = (m & 31) + 32 * half;
            ushort4 v;
            v.x = f2b(acc[nt][0]); v.y = f2b(acc[nt][1]);
            v.z = f2b(acc[nt][2]); v.w = f2b(acc[nt][3]);
            *(ushort4*)(Kb + ((size_t)(mt * 32 + kb) * 64 + lf) * 8 + ebase) = v;
        }
    } else {
#pragma unroll
        for (int nt = 0; nt < 4; ++nt)
#pragma unroll
            for (int r = 0; r < 4; ++r)
                Vst[w][quad * 4 + r][nt * 16 + lq] = (short)f2b(acc[nt][r]);
        __syncthreads();
        unsigned short* Vbp = Yb + (size_t)b * Nx * Cd;
        const int lane = t & 63;
#pragma unroll
        for (int k = 0; k < 2; ++k) {
            int u = lane + k * 64;
            int c_loc = u >> 3, m8 = u & 7;
            int c = o0 + w * 16 + c_loc;
            int m = n0 + m8 * 8;
            int ct = c >> 5, mb = m >> 4;
            int lf = (c & 31) + 32 * (m8 & 1);
            uint4 v = *(const uint4*)(&Vst[w][c_loc][m8 * 8]);
            *(uint4*)(Vbp + ((size_t)(ct * 64 + mb) * 64 + lf) * 8) = v;
        }
    }
}

// ---------------------------------------------------------------------------
// attn_v2: flash attention, 32x32x16 MFMAs. K/V read directly from global in
// MFMA-fragment-tiled layout (wave-uniform base + lane*16B, fully coalesced).
// Q staged once in LDS (shared by 4 waves), P through LDS.
// Block = 256 thr / 4 waves handles (b, 32 q-rows). m-chunk = 128.
// Grid: 1024 linear; b = bid&7 (XCD affinity: batch's K+V frags fit XCD L2).
// ---------------------------------------------------------------------------
__global__ __launch_bounds__(256, 2) void attn_v2(const unsigned short* __restrict__ Qt,
                                                  const unsigned short* __restrict__ Kf,
                                                  const unsigned short* __restrict__ Vf,
                                                  float* __restrict__ out) {
    __shared__ __align__(16) unsigned char Ls[42880];
    unsigned char* Lq = Ls;                                   // Qs: 32x512 bf16 swizzled (32768 B)
    unsigned short* Pb = (unsigned short*)(Ls + 32768);       // Pb[32][136] bf16 (8704 B)
    float* pmaxS  = (float*)(Ls + 41472);                     // [32][4]
    float* psumS  = (float*)(Ls + 41984);                     // [32][4]
    float* muS    = (float*)(Ls + 42496);                     // [32]
    float* ssumS  = (float*)(Ls + 42624);                     // [32]
    float* alphaS = (float*)(Ls + 42752);                     // [32]
    float* OtA    = (float*)Ls;                               // epilogue alias: [4][32][36] f32

    const int t = threadIdx.x;
    const int l = t & 63, w = t >> 6;
    const int lcol = l & 31, lhalf = l >> 5;
    const int bid = blockIdx.x;
    const int b = bid & 7, n0 = (bid >> 3) * 32;

    {
        const unsigned short* qb = Qt + ((size_t)b * Nn + n0) * Cd;
#pragma unroll
        for (int i = 0; i < 8; ++i) {
            int s = i * 256 + t;           // unit id 0..2047
            int n = s >> 6, u = s & 63;
            uint4 v = *(const uint4*)(qb + (size_t)n * Cd + u * 8);
            *(uint4*)(Lq + ((n * 64 + (u ^ (n & 15))) << 4)) = v;
        }
    }
    if (t < 32) { muS[t] = -1e30f; ssumS[t] = 0.f; }

    v16f o_acc[4];
#pragma unroll
    for (int i = 0; i < 4; ++i)
#pragma unroll
        for (int r = 0; r < 16; ++r) o_acc[i][r] = 0.f;
    __syncthreads();

    const unsigned short* Kfb = Kf + (size_t)b * Mm * Cd + (size_t)l * 8;
    const unsigned short* Vfb = Vf + (size_t)b * Cd * Mm + (size_t)l * 8;
    const int qrow = lcol * 64;
    const int swz = lcol & 15;
    const float sc = 0.04419417382415922f;   // 1/sqrt(512)

    for (int m0 = 0; m0 < Mm; m0 += 128) {
        v16f st;
#pragma unroll
        for (int r = 0; r < 16; ++r) st[r] = 0.f;
        const unsigned short* kp = Kfb + (size_t)(((m0 >> 5) + w) * 32) * 512;
#pragma unroll
        for (int kb8 = 0; kb8 < 4; ++kb8) {
            uint4 ka[8];
#pragma unroll
            for (int j = 0; j < 8; ++j) ka[j] = *(const uint4*)(kp + (size_t)(kb8 * 8 + j) * 512);
#pragma unroll
            for (int j = 0; j < 8; ++j) {
                int kb = kb8 * 8 + j;
                s8v qf = *(const s8v*)(Lq + ((qrow + ((kb * 2 + lhalf) ^ swz)) << 4));
                union { uint4 u; s8v s; } av; av.u = ka[j];
                st = mfma32(av.s, qf, st);
            }
        }
#pragma unroll
        for (int r = 0; r < 16; ++r) st[r] *= sc;
        float tm = st[0];
#pragma unroll
        for (int r = 1; r < 16; ++r) tm = fmaxf(tm, st[r]);
        tm = fmaxf(tm, __shfl_xor(tm, 32));
        if (l < 32) pmaxS[l * 4 + w] = tm;
        __syncthreads();   // S1
        if (t < 32) {
            float mx = muS[t];
            mx = fmaxf(mx, fmaxf(fmaxf(pmaxS[t * 4], pmaxS[t * 4 + 1]),
                                 fmaxf(pmaxS[t * 4 + 2], pmaxS[t * 4 + 3])));
            alphaS[t] = __expf(muS[t] - mx);
            muS[t] = mx;
        }
        __syncthreads();   // S2
        {
            float mxn = muS[lcol];
            float e[16], rs = 0.f;
#pragma unroll
            for (int r = 0; r < 16; ++r) { e[r] = __expf(st[r] - mxn); rs += e[r]; }
            rs += __shfl_xor(rs, 32);
            if (l < 32) psumS[l * 4 + w] = rs;
#pragma unroll
            for (int rg = 0; rg < 4; ++rg) {
                ushort4 pk;
                pk.x = f2b(e[rg * 4 + 0]); pk.y = f2b(e[rg * 4 + 1]);
                pk.z = f2b(e[rg * 4 + 2]); pk.w = f2b(e[rg * 4 + 3]);
                *(ushort4*)(Pb + lcol * 136 + w * 32 + 8 * rg + 4 * lhalf) = pk;
            }
        }
        __syncthreads();   // S3
        if (t < 32)
            ssumS[t] = ssumS[t] * alphaS[t] +
                       psumS[t * 4] + psumS[t * 4 + 1] + psumS[t * 4 + 2] + psumS[t * 4 + 3];

        float ar[16];
#pragma unroll
        for (int r = 0; r < 16; ++r)
            ar[r] = alphaS[(r & 3) + 8 * (r >> 2) + 4 * lhalf];
#pragma unroll
        for (int ti = 0; ti < 4; ++ti)
#pragma unroll
            for (int r = 0; r < 16; ++r) o_acc[ti][r] *= ar[r];

        s8v pA[8];
#pragma unroll
        for (int kb = 0; kb < 8; ++kb)
            pA[kb] = *(const s8v*)(Pb + lcol * 136 + kb * 16 + lhalf * 8);

#pragma unroll
        for (int ti = 0; ti < 4; ++ti) {
            const unsigned short* vc = Vfb + (size_t)((ti * 4 + w) * 64 + (m0 >> 4)) * 512;
            uint4 vb8[8];
#pragma unroll
            for (int kb = 0; kb < 8; ++kb) vb8[kb] = *(const uint4*)(vc + (size_t)kb * 512);
#pragma unroll
            for (int kb = 0; kb < 8; ++kb) {
                union { uint4 u; s8v s; } bv; bv.u = vb8[kb];
                o_acc[ti] = mfma32(pA[kb], bv.s, o_acc[ti]);
            }
        }
        __syncthreads();
    }

    float inv[16];
#pragma unroll
    for (int r = 0; r < 16; ++r)
        inv[r] = 1.0f / ssumS[(r & 3) + 8 * (r >> 2) + 4 * lhalf];

    float* OtW = OtA + w * 32 * 36;
#pragma unroll
    for (int ti = 0; ti < 4; ++ti) {
#pragma unroll
        for (int r = 0; r < 16; ++r)
            OtW[lcol * 36 + (r & 3) + 8 * (r >> 2) + 4 * lhalf] = o_acc[ti][r] * inv[r];
        __syncthreads();
        {
            int cloc = l >> 1, half = l & 1;
            int cabs = ti * 128 + w * 32 + cloc;
            const float* src = OtW + cloc * 36 + half * 16;
            float* op = out + ((size_t)b * Cd + cabs) * Nn + n0 + half * 16;
#pragma unroll
            for (int j = 0; j < 4; ++j) {
                float4 a = *(const float4*)(src + j * 4);
                float4 g = *(const float4*)(op + j * 4);
                g.x += a.x; g.y += a.y; g.z += a.z; g.w += a.w;
                *(float4*)(op + j * 4) = g;
            }
        }
        __syncthreads();
    }
}

// ---------------------------------------------------------------------------
// Fallback VALU attention (round-3 proven) for small ws_size.
// ---------------------------------------------------------------------------
__device__ __forceinline__ float u2lo(unsigned int u) {
    union { unsigned int i; float f; } v; v.i = u << 16; return v.f;
}
__device__ __forceinline__ float u2hi(unsigned int u) {
    union { unsigned int i; float f; } v; v.i = u & 0xFFFF0000u; return v.f;
}

__global__ __launch_bounds__(256) void attn_k(const float* __restrict__ up,
                                              const float* __restrict__ Wq,
                                              const unsigned short* __restrict__ Ktb,
                                              const unsigned short* __restrict__ Vtb,
                                              float* __restrict__ out) {
    __shared__ float Qs[16][516];
    __shared__ __align__(16) unsigned char Sraw[24576];
    unsigned short (*Us)[16]  = reinterpret_cast<unsigned short(*)[16]>(Sraw);
    unsigned short (*Wt)[512] = reinterpret_cast<unsigned short(*)[512]>(Sraw + 16384);
    float (*Ps)[65] = reinterpret_cast<float(*)[65]>(Sraw);
    float* mu_s     = reinterpret_cast<float*>(Sraw + 4160);
    float* ssum_s   = reinterpret_cast<float*>(Sraw + 4224);
    float* alpha_s  = reinterpret_cast<float*>(Sraw + 4288);

    const int t = threadIdx.x;
    const int b = blockIdx.y;
    const int n0 = blockIdx.x * 16;
    const int row = t & 15;
    const int grp = t >> 4;

    for (int i = t; i < Cd * 16; i += 256) {
        int c = i >> 4, r = i & 15;
        Us[c][r] = f2b(up[((size_t)b * Cd + c) * Nn + n0 + r]);
    }
    __syncthreads();

    float acc[32];
#pragma unroll
    for (int j = 0; j < 32; ++j) acc[j] = 0.f;

    for (int k0 = 0; k0 < Cd; k0 += 8) {
        for (int i = t; i < 1024; i += 256) {
            int oc = i >> 1;
            int kc = (i & 1) * 4;
            float4 wv = *(const float4*)(Wq + (size_t)oc * Cd + k0 + kc);
            Wt[kc + 0][oc] = f2b(wv.x); Wt[kc + 1][oc] = f2b(wv.y);
            Wt[kc + 2][oc] = f2b(wv.z); Wt[kc + 3][oc] = f2b(wv.w);
        }
        __syncthreads();
#pragma unroll
        for (int k = 0; k < 8; ++k) {
            float u = b2f(Us[k0 + k][row]);
            const ushort4* wr = (const ushort4*)(&Wt[k][grp * 32]);
#pragma unroll
            for (int j4 = 0; j4 < 8; ++j4) {
                ushort4 wv = wr[j4];
                acc[j4 * 4 + 0] += u * b2f(wv.x);
                acc[j4 * 4 + 1] += u * b2f(wv.y);
                acc[j4 * 4 + 2] += u * b2f(wv.z);
                acc[j4 * 4 + 3] += u * b2f(wv.w);
            }
        }
        __syncthreads();
    }

    const float scale = 0.04419417382415922f;
#pragma unroll
    for (int j = 0; j < 32; ++j) Qs[row][grp * 32 + j] = acc[j] * scale;
    if (t < 16) { mu_s[t] = -1e30f; ssum_s[t] = 0.f; }
#pragma unroll
    for (int j = 0; j < 32; ++j) acc[j] = 0.f;
    __syncthreads();

    const float4* qr = (const float4*)(&Qs[row][0]);

    for (int m0 = 0; m0 < Mm; m0 += 64) {
        {
            int mb = m0 + grp * 4;
            const uint4* K0 = (const uint4*)(Ktb + ((size_t)b * Mm + mb + 0) * Cd);
            const uint4* K1 = (const uint4*)(Ktb + ((size_t)b * Mm + mb + 1) * Cd);
            const uint4* K2 = (const uint4*)(Ktb + ((size_t)b * Mm + mb + 2) * Cd);
            const uint4* K3 = (const uint4*)(Ktb + ((size_t)b * Mm + mb + 3) * Cd);
            float a0 = 0.f, a1 = 0.f, a2 = 0.f, a3 = 0.f;
#pragma unroll 4
            for (int c8 = 0; c8 < Cd / 8; ++c8) {
                float4 qa = qr[2 * c8], qb = qr[2 * c8 + 1];
                uint4 k0v = K0[c8], k1v = K1[c8], k2v = K2[c8], k3v = K3[c8];
                a0 += qa.x * u2lo(k0v.x) + qa.y * u2hi(k0v.x) + qa.z * u2lo(k0v.y) + qa.w * u2hi(k0v.y)
                    + qb.x * u2lo(k0v.z) + qb.y * u2hi(k0v.z) + qb.z * u2lo(k0v.w) + qb.w * u2hi(k0v.w);
                a1 += qa.x * u2lo(k1v.x) + qa.y * u2hi(k1v.x) + qa.z * u2lo(k1v.y) + qa.w * u2hi(k1v.y)
                    + qb.x * u2lo(k1v.z) + qb.y * u2hi(k1v.z) + qb.z * u2lo(k1v.w) + qb.w * u2hi(k1v.w);
                a2 += qa.x * u2lo(k2v.x) + qa.y * u2hi(k2v.x) + qa.z * u2lo(k2v.y) + qa.w * u2hi(k2v.y)
                    + qb.x * u2lo(k2v.z) + qb.y * u2hi(k2v.z) + qb.z * u2lo(k2v.w) + qb.w * u2hi(k2v.w);
                a3 += qa.x * u2lo(k3v.x) + qa.y * u2hi(k3v.x) + qa.z * u2lo(k3v.y) + qa.w * u2hi(k3v.y)
                    + qb.x * u2lo(k3v.z) + qb.y * u2hi(k3v.z) + qb.z * u2lo(k3v.w) + qb.w * u2hi(k3v.w);
            }
            Ps[row][grp * 4 + 0] = a0;
            Ps[row][grp * 4 + 1] = a1;
            Ps[row][grp * 4 + 2] = a2;
            Ps[row][grp * 4 + 3] = a3;
        }
        __syncthreads();
        if (t < 16) {
            float mold = mu_s[t];
            float mx = mold;
            for (int m = 0; m < 64; ++m) mx = fmaxf(mx, Ps[t][m]);
            float al = __expf(mold - mx);
            float s = ssum_s[t] * al;
            for (int m = 0; m < 64; ++m) {
                float p = __expf(Ps[t][m] - mx);
                Ps[t][m] = p;
                s += p;
            }
            mu_s[t] = mx; ssum_s[t] = s; alpha_s[t] = al;
        }
        __syncthreads();
        {
            float arr = alpha_s[row];
#pragma unroll
            for (int j = 0; j < 32; ++j) acc[j] *= arr;
            const unsigned short* Vbase = Vtb + (size_t)b * Mm * Cd + (size_t)grp * 32;
            for (int m = 0; m < 64; ++m) {
                float p = Ps[row][m];
                const uint4* vr = (const uint4*)(Vbase + (size_t)(m0 + m) * Cd);
#pragma unroll
                for (int j4 = 0; j4 < 4; ++j4) {
                    uint4 v = vr[j4];
                    acc[j4 * 8 + 0] += p * u2lo(v.x); acc[j4 * 8 + 1] += p * u2hi(v.x);
                    acc[j4 * 8 + 2] += p * u2lo(v.y); acc[j4 * 8 + 3] += p * u2hi(v.y);
                    acc[j4 * 8 + 4] += p * u2lo(v.z); acc[j4 * 8 + 5] += p * u2hi(v.z);
                    acc[j4 * 8 + 6] += p * u2lo(v.w); acc[j4 * 8 + 7] += p * u2hi(v.w);
                }
            }
        }
        __syncthreads();
    }

    float invv = 1.0f / ssum_s[row];
#pragma unroll
    for (int j = 0; j < 32; ++j) {
        int c = grp * 32 + j;
        size_t idx = ((size_t)b * Cd + c) * Nn + n0 + row;
        out[idx] = out[idx] + acc[j] * invv;
    }
}

// ---------------------------------------------------------------------------
extern "C" void kernel_launch(void* const* d_in, const int* in_sizes, int n_in,
                              void* d_out, int out_size, void* d_ws, size_t ws_size,
                              hipStream_t stream) {
    const float* up   = (const float*)d_in[0];
    const float* down = (const float*)d_in[1];
    const float* Wq   = (const float*)d_in[2];
    const float* Wk   = (const float*)d_in[3];
    const float* Wv   = (const float*)d_in[4];
    const float* Wsk  = (const float*)d_in[5];
    float* out = (float*)d_out;

    const size_t szK = (size_t)Bn * Mm * Cd;   // bf16 elems: 4M (8 MiB)
    const size_t szQ = (size_t)Bn * Nn * Cd;   // bf16 elems: 16M (32 MiB)
    const size_t szW = (size_t)4 * Cd * Cd;    // bf16 elems: 1M (2 MiB)

    if (ws_size >= (2 * szK + szQ + szW) * 2) {
        // Fast path v2: fused dual-output 128x128 GEMMs + pre-converted W.
        unsigned short* Kf = (unsigned short*)d_ws;
        unsigned short* Vf = Kf + szK;
        unsigned short* Qt = Vf + szK;
        unsigned short* Wb = Qt + szQ;
        convw<<<dim3(256, 4), 256, 0, stream>>>(Wq, Wk, Wv, Wsk, Wb);
        gemm2<0><<<dim3(256), 256, 0, stream>>>(Wb, down, nullptr, Kf, Vf);
        gemm2<1><<<dim3(1024), 256, 0, stream>>>(Wb, up, out, Qt, nullptr);
        attn_v2<<<dim3((Nn / 32) * Bn), 256, 0, stream>>>(Qt, Kf, Vf, out);
    } else if (ws_size >= (2 * szK + szQ) * 2) {
        // Previous fast path (48 MiB ws).
        unsigned short* Kf = (unsigned short*)d_ws;
        unsigned short* Vf = Kf + szK;
        unsigned short* Qt = Vf + szK;
        gemm_mfma<3><<<dim3(Mm / 64, Cd / 64, Bn), 256, 0, stream>>>(Wk, down, nullptr, Kf, Mm);
        gemm_mfma<4><<<dim3(Mm / 64, Cd / 64, Bn), 256, 0, stream>>>(Wv, down, nullptr, Vf, Mm);
        gemm_mfma<2><<<dim3(Nn / 64, Cd / 64, Bn), 256, 0, stream>>>(Wq, up, nullptr, Qt, Nn);
        gemm_mfma<0><<<dim3(Nn / 64, Cd / 64, Bn), 256, 0, stream>>>(Wsk, up, out, nullptr, Nn);
        attn_v2<<<dim3((Nn / 32) * Bn), 256, 0, stream>>>(Qt, Kf, Vf, out);
    } else {
        // Fallback (16 MiB ws): round-3 proven VALU attention.
        unsigned short* Ktb = (unsigned short*)d_ws;
        unsigned short* Vtb = Ktb + szK;
        gemm_mfma<2><<<dim3(Mm / 64, Cd / 64, Bn), 256, 0, stream>>>(Wk, down, nullptr, Ktb, Mm);
        gemm_mfma<2><<<dim3(Mm / 64, Cd / 64, Bn), 256, 0, stream>>>(Wv, down, nullptr, Vtb, Mm);
        gemm_mfma<0><<<dim3(Nn / 64, Cd / 64, Bn), 256, 0, stream>>>(Wsk, up, out, nullptr, Nn);
        attn_k<<<dim3(Nn / 16, Bn), 256, 0, stream>>>(up, Wq, Ktb, Vtb, out);
    }
}

// Round 4
// 375.757 us; speedup vs baseline: 1.5854x; 1.0641x over previous
//
#include <hip/hip_runtime.h>
#include <cstddef>

// Problem constants: B=8, C=512, N=4096, M=1024. Inputs f32, output f32.
#define Bn 8
#define Cd 512
#define Nn 4096
#define Mm 1024

typedef __attribute__((ext_vector_type(8))) short s8v;
typedef __attribute__((ext_vector_type(4))) float v4f;
typedef __attribute__((ext_vector_type(16))) float v16f;

__device__ __forceinline__ float b2f(unsigned short u) {
    union { unsigned int i; float f; } v; v.i = ((unsigned int)u) << 16; return v.f;
}
__device__ __forceinline__ unsigned short f2b(float f) {
    union { float f; unsigned int i; } v; v.f = f;
    unsigned int x = v.i;
    unsigned int r = (x + 0x7FFFu + ((x >> 16) & 1u)) >> 16;  // RNE
    return (unsigned short)r;
}
__device__ __forceinline__ v4f mfma16(s8v a, s8v b, v4f c) {
    return __builtin_amdgcn_mfma_f32_16x16x32_bf16(a, b, c, 0, 0, 0);
}
__device__ __forceinline__ v16f mfma32(s8v a, s8v b, v16f c) {
    return __builtin_amdgcn_mfma_f32_32x32x16_bf16(a, b, c, 0, 0, 0);
}
__device__ __forceinline__ void gload_lds16(const unsigned short* gsrc, unsigned char* lds) {
    __builtin_amdgcn_global_load_lds(
        (const __attribute__((address_space(1))) unsigned int*)gsrc,
        (__attribute__((address_space(3))) unsigned int*)lds, 16, 0, 0);
}

// ---------------------------------------------------------------------------
// convw: W f32[512][512] -> bf16, 4 weights into Wb[4][512][512].
// ---------------------------------------------------------------------------
__global__ __launch_bounds__(256) void convw(const float* __restrict__ Wq, const float* __restrict__ Wk,
                                             const float* __restrict__ Wv, const float* __restrict__ Ws,
                                             unsigned short* __restrict__ Wb) {
    const float* S = (blockIdx.y == 0) ? Wq : (blockIdx.y == 1) ? Wk : (blockIdx.y == 2) ? Wv : Ws;
    int i = (blockIdx.x * 256 + threadIdx.x) * 4;
    float4 v = *(const float4*)(S + i);
    ushort4 u; u.x = f2b(v.x); u.y = f2b(v.y); u.z = f2b(v.z); u.w = f2b(v.w);
    *(ushort4*)(Wb + (size_t)blockIdx.y * 262144 + i) = u;
}

// ---------------------------------------------------------------------------
// convx: transpose+convert X f32[b][C][Nx] -> Xt bf16[b][Nc][C] (chunk-local n).
// Removes f2b + 16-way-conflicted scalar ds_write staging from the GEMM loop
// (that staging was ~70% of GEMM time). 64n x 64c tiles; LDS pad 65 floats
// makes write banks (4k+j+c)%32 (2-way, free) and reads conflict-free.
// ---------------------------------------------------------------------------
__global__ __launch_bounds__(256) void convx(const float* __restrict__ X,
                                             unsigned short* __restrict__ Xt,
                                             int Nx, int Nc, int n_base) {
    __shared__ float Lf[64][65];
    const int t = threadIdx.x;
    const int b = blockIdx.z, c0 = blockIdx.y * 64;
    const int nl0 = blockIdx.x * 64;
    const int cl = t >> 4, n4 = (t & 15) * 4;
    const float* Xb = X + (size_t)b * Cd * Nx + n_base + nl0;
#pragma unroll
    for (int cc = 0; cc < 4; ++cc) {
        int c = cc * 16 + cl;
        float4 v = *(const float4*)(Xb + (size_t)(c0 + c) * Nx + n4);
        Lf[n4 + 0][c] = v.x; Lf[n4 + 1][c] = v.y;
        Lf[n4 + 2][c] = v.z; Lf[n4 + 3][c] = v.w;
    }
    __syncthreads();
    unsigned short* Xtb = Xt + ((size_t)b * Nc + nl0) * Cd + c0;
#pragma unroll
    for (int rep = 0; rep < 2; ++rep) {
        int u = t + rep * 256;
        int n = u >> 3, c8 = (u & 7) * 8;
        union { ushort4 h[2]; uint4 q; } pk;
        pk.h[0].x = f2b(Lf[n][c8 + 0]); pk.h[0].y = f2b(Lf[n][c8 + 1]);
        pk.h[0].z = f2b(Lf[n][c8 + 2]); pk.h[0].w = f2b(Lf[n][c8 + 3]);
        pk.h[1].x = f2b(Lf[n][c8 + 4]); pk.h[1].y = f2b(Lf[n][c8 + 5]);
        pk.h[1].z = f2b(Lf[n][c8 + 6]); pk.h[1].w = f2b(Lf[n][c8 + 7]);
        *(uint4*)(Xtb + (size_t)n * Cd + c8) = pk.q;
    }
}

// ---------------------------------------------------------------------------
// gemm3: dual-output fused GEMM from pre-transposed bf16 Xt[b][n][c].
// 128n x 128o tile, 256 thr / 4 waves, 32 mfma16 / wave / 32-c K-step.
// X staged via global_load_lds 16B into a LINEAR [128][32] bf16 tile,
// double-buffered, ONE barrier per step, zero staging VALU / conflicts.
// W fragments direct from global bf16 (issued before STAGE so their waitcnt
// doesn't drain the in-flight staging).
// PAIRB=0: X=down-chunk, W1=Wk->Kf (A-frags), W2=Wv->Vf (B-frags).
// PAIRB=1: X=up-chunk,   W1=Wq->Qt[n][c],     W2=Wskip->out f32.
// Fragment layouts (match attn_v2 reader):
//   Kf[((mt*32+kb)*64 + (m&31)+32*((c>>3)&1))*8 + (c&7)]
//   Vf[((ct*64+mb)*64 + (c&31)+32*((m>>3)&1))*8 + (m&7)]
// ---------------------------------------------------------------------------
template <int PAIRB>
__global__ __launch_bounds__(256, 2) void gemm3(const unsigned short* __restrict__ Wb,
                                                const unsigned short* __restrict__ Xt,
                                                float* __restrict__ outF,
                                                unsigned short* __restrict__ Y1,
                                                unsigned short* __restrict__ Y2,
                                                int Nc, int n_base) {
    __shared__ __align__(16) unsigned char raw[PAIRB ? 36864 : 18432];
    const int t = threadIdx.x;
    const int w = t >> 6, lq = t & 15, quad = (t >> 4) & 3;
    const int bid = blockIdx.x;
    const int b = bid & 7, rest = bid >> 3;
    const int nl0 = (rest >> 2) * 128, o0 = (rest & 3) * 128;
    const unsigned short* Xb = Xt + ((size_t)b * Nc + nl0) * Cd;
    const unsigned short* W1r = Wb + (size_t)(PAIRB ? 0 : 1) * 262144 + (size_t)(o0 + w * 32 + lq) * Cd;
    const unsigned short* W2r = Wb + (size_t)(PAIRB ? 3 : 2) * 262144 + (size_t)(o0 + w * 32 + lq) * Cd;

    v4f acc1[2][8], acc2[2][8];
#pragma unroll
    for (int ot = 0; ot < 2; ++ot)
#pragma unroll
        for (int nt = 0; nt < 8; ++nt) {
            acc1[ot][nt] = (v4f){0.f, 0.f, 0.f, 0.f};
            acc2[ot][nt] = (v4f){0.f, 0.f, 0.f, 0.f};
        }

    // STAGE(buf s, K-offset c0): 512 16B units, linear LDS (wave-uniform+lane*16)
#define STAGE(s, c0)                                                            \
    {                                                                           \
        _Pragma("unroll")                                                       \
        for (int rep = 0; rep < 2; ++rep) {                                     \
            int u = t + rep * 256;                                              \
            gload_lds16(Xb + (size_t)(u >> 2) * Cd + (c0) + (u & 3) * 8,        \
                        raw + (s) * 8192 + u * 16);                             \
        }                                                                       \
    }

    STAGE(0, 0);
    for (int step = 0; step < 16; ++step) {
        const int c0 = step * 32, cur = step & 1;
        __syncthreads();   // buf[cur] staged (vmcnt drain) + prev reads of buf[cur^1] done
        // W fragments first (their waitcnt then leaves next STAGE in flight)
        s8v af1[2], af2[2];
#pragma unroll
        for (int ot = 0; ot < 2; ++ot) {
            af1[ot] = *(const s8v*)(W1r + (size_t)ot * 16 * Cd + c0 + quad * 8);
            af2[ot] = *(const s8v*)(W2r + (size_t)ot * 16 * Cd + c0 + quad * 8);
        }
        if (step < 15) STAGE(cur ^ 1, c0 + 32);
        const short* Xs = (const short*)(raw + cur * 8192);
#pragma unroll
        for (int nt = 0; nt < 8; ++nt) {
            s8v bf = *(const s8v*)(Xs + (nt * 16 + lq) * 32 + quad * 8);
            acc1[0][nt] = mfma16(af1[0], bf, acc1[0][nt]);
            acc1[1][nt] = mfma16(af1[1], bf, acc1[1][nt]);
            acc2[0][nt] = mfma16(af2[0], bf, acc2[0][nt]);
            acc2[1][nt] = mfma16(af2[1], bf, acc2[1][nt]);
        }
    }
#undef STAGE
    __syncthreads();   // before reusing raw for epilogue transposes

    if (PAIRB) {
        // ---- acc2 (skip) -> out f32 [b][o][n_global]
#pragma unroll
        for (int ot = 0; ot < 2; ++ot)
#pragma unroll
            for (int nt = 0; nt < 8; ++nt)
#pragma unroll
                for (int r = 0; r < 4; ++r) {
                    int o = o0 + w * 32 + ot * 16 + quad * 4 + r;
                    int n = n_base + nl0 + nt * 16 + lq;
                    outF[((size_t)b * Cd + o) * Nn + n] = acc2[ot][nt][r];
                }
        // ---- acc1 (Q) -> Qt[n][c] bf16 via full-tile LDS transpose
        short (*T2)[144] = reinterpret_cast<short(*)[144]>(raw);   // [128][144]
#pragma unroll
        for (int ot = 0; ot < 2; ++ot)
#pragma unroll
            for (int nt = 0; nt < 8; ++nt)
#pragma unroll
                for (int r = 0; r < 4; ++r)
                    T2[nt * 16 + lq][w * 32 + ot * 16 + quad * 4 + r] = (short)f2b(acc1[ot][nt][r]);
        __syncthreads();
        {
            int row = t >> 1, ob = (t & 1) * 64;
            unsigned short* qp = Y1 + ((size_t)b * Nn + n_base + nl0 + row) * Cd + o0 + ob;
#pragma unroll
            for (int j = 0; j < 8; ++j)
                *(uint4*)(qp + j * 8) = *(const uint4*)(&T2[row][ob + j * 8]);
        }
    } else {
        // ---- acc1 (K) -> Kf fragments, direct from acc
        const int half = quad >> 1, ebase = (quad & 1) * 4;
        unsigned short* Kb = Y1 + (size_t)b * Mm * Cd;
#pragma unroll
        for (int ot = 0; ot < 2; ++ot) {
            int kb = (o0 + w * 32 + ot * 16) >> 4;
#pragma unroll
            for (int nt = 0; nt < 8; ++nt) {
                int m = nl0 + nt * 16 + lq;
                int mt = m >> 5, lf = (m & 31) + 32 * half;
                ushort4 v;
                v.x = f2b(acc1[ot][nt][0]); v.y = f2b(acc1[ot][nt][1]);
                v.z = f2b(acc1[ot][nt][2]); v.w = f2b(acc1[ot][nt][3]);
                *(ushort4*)(Kb + ((size_t)(mt * 32 + kb) * 64 + lf) * 8 + ebase) = v;
            }
        }
        // ---- acc2 (V) -> Vf fragments via per-wave LDS transpose
        short (*Vst)[16][144] = reinterpret_cast<short(*)[16][144]>(raw);  // [4][16][144]
        unsigned short* Vbp = Y2 + (size_t)b * Cd * Mm;
        const int lane = t & 63;
#pragma unroll
        for (int ot = 0; ot < 2; ++ot) {
#pragma unroll
            for (int nt = 0; nt < 8; ++nt)
#pragma unroll
                for (int r = 0; r < 4; ++r)
                    Vst[w][quad * 4 + r][nt * 16 + lq] = (short)f2b(acc2[ot][nt][r]);
#pragma unroll
            for (int k = 0; k < 4; ++k) {
                int u = lane + k * 64;                 // 0..255: 16 c x 16 m-units
                int c_loc = u >> 4, m8 = u & 15;
                int c = o0 + w * 32 + ot * 16 + c_loc;
                int m = nl0 + m8 * 8;
                int ct = c >> 5, mb = m >> 4;
                int lf = (c & 31) + 32 * (m8 & 1);
                uint4 v = *(const uint4*)(&Vst[w][c_loc][m8 * 8]);
                *(uint4*)(Vbp + ((size_t)(ct * 64 + mb) * 64 + lf) * 8) = v;
            }
        }
    }
}

// ---------------------------------------------------------------------------
// gemm2 (round-3 proven, kept for the 50 MiB workspace path).
// ---------------------------------------------------------------------------
template <int PAIRB>
__global__ __launch_bounds__(256, 2) void gemm2(const unsigned short* __restrict__ Wb,
                                                const float* __restrict__ X,
                                                float* __restrict__ outF,
                                                unsigned short* __restrict__ Y1,
                                                unsigned short* __restrict__ Y2) {
    constexpr int Nx = PAIRB ? Nn : Mm;
    __shared__ __align__(16) unsigned char raw[PAIRB ? 36864 : 18432];
    short (*Xs)[40] = reinterpret_cast<short(*)[40]>(raw);

    const int t = threadIdx.x;
    const int w = t >> 6, lq = t & 15, quad = (t >> 4) & 3;
    const int bid = blockIdx.x;
    const int b = bid & 7, rest = bid >> 3;
    const int n0 = (rest >> 2) * 128, o0 = (rest & 3) * 128;
    const float* Xb = X + (size_t)b * Cd * Nx;
    const unsigned short* W1r = Wb + (size_t)(PAIRB ? 0 : 1) * 262144 + (size_t)(o0 + w * 32 + lq) * Cd;
    const unsigned short* W2r = Wb + (size_t)(PAIRB ? 3 : 2) * 262144 + (size_t)(o0 + w * 32 + lq) * Cd;

    v4f acc1[2][8], acc2[2][8];
#pragma unroll
    for (int ot = 0; ot < 2; ++ot)
#pragma unroll
        for (int nt = 0; nt < 8; ++nt) {
            acc1[ot][nt] = (v4f){0.f, 0.f, 0.f, 0.f};
            acc2[ot][nt] = (v4f){0.f, 0.f, 0.f, 0.f};
        }

    for (int c0 = 0; c0 < Cd; c0 += 32) {
        float4 xv[4];
#pragma unroll
        for (int p4 = 0; p4 < 4; ++p4) {
            int i = t + p4 * 256;
            xv[p4] = *(const float4*)(Xb + (size_t)(c0 + (i >> 5)) * Nx + n0 + (i & 31) * 4);
        }
        s8v af1[2], af2[2];
#pragma unroll
        for (int ot = 0; ot < 2; ++ot) {
            af1[ot] = *(const s8v*)(W1r + (size_t)ot * 16 * Cd + c0 + quad * 8);
            af2[ot] = *(const s8v*)(W2r + (size_t)ot * 16 * Cd + c0 + quad * 8);
        }
#pragma unroll
        for (int p4 = 0; p4 < 4; ++p4) {
            int i = t + p4 * 256;
            int c = i >> 5, n4 = (i & 31) * 4;
            Xs[n4 + 0][c] = (short)f2b(xv[p4].x); Xs[n4 + 1][c] = (short)f2b(xv[p4].y);
            Xs[n4 + 2][c] = (short)f2b(xv[p4].z); Xs[n4 + 3][c] = (short)f2b(xv[p4].w);
        }
        __syncthreads();
#pragma unroll
        for (int nt = 0; nt < 8; ++nt) {
            s8v bf = *(const s8v*)(&Xs[nt * 16 + lq][quad * 8]);
            acc1[0][nt] = mfma16(af1[0], bf, acc1[0][nt]);
            acc1[1][nt] = mfma16(af1[1], bf, acc1[1][nt]);
            acc2[0][nt] = mfma16(af2[0], bf, acc2[0][nt]);
            acc2[1][nt] = mfma16(af2[1], bf, acc2[1][nt]);
        }
        __syncthreads();
    }

    if (PAIRB) {
#pragma unroll
        for (int ot = 0; ot < 2; ++ot)
#pragma unroll
            for (int nt = 0; nt < 8; ++nt)
#pragma unroll
                for (int r = 0; r < 4; ++r) {
                    int o = o0 + w * 32 + ot * 16 + quad * 4 + r;
                    int n = n0 + nt * 16 + lq;
                    outF[((size_t)b * Cd + o) * Nx + n] = acc2[ot][nt][r];
                }
        short (*T2)[144] = reinterpret_cast<short(*)[144]>(raw);
#pragma unroll
        for (int ot = 0; ot < 2; ++ot)
#pragma unroll
            for (int nt = 0; nt < 8; ++nt)
#pragma unroll
                for (int r = 0; r < 4; ++r)
                    T2[nt * 16 + lq][w * 32 + ot * 16 + quad * 4 + r] = (short)f2b(acc1[ot][nt][r]);
        __syncthreads();
        {
            int row = t >> 1, ob = (t & 1) * 64;
            unsigned short* qp = Y1 + ((size_t)b * Nx + n0 + row) * Cd + o0 + ob;
#pragma unroll
            for (int j = 0; j < 8; ++j)
                *(uint4*)(qp + j * 8) = *(const uint4*)(&T2[row][ob + j * 8]);
        }
    } else {
        const int half = quad >> 1, ebase = (quad & 1) * 4;
        unsigned short* Kb = Y1 + (size_t)b * Mm * Cd;
#pragma unroll
        for (int ot = 0; ot < 2; ++ot) {
            int kb = (o0 + w * 32 + ot * 16) >> 4;
#pragma unroll
            for (int nt = 0; nt < 8; ++nt) {
                int m = n0 + nt * 16 + lq;
                int mt = m >> 5, lf = (m & 31) + 32 * half;
                ushort4 v;
                v.x = f2b(acc1[ot][nt][0]); v.y = f2b(acc1[ot][nt][1]);
                v.z = f2b(acc1[ot][nt][2]); v.w = f2b(acc1[ot][nt][3]);
                *(ushort4*)(Kb + ((size_t)(mt * 32 + kb) * 64 + lf) * 8 + ebase) = v;
            }
        }
        short (*Vst)[16][144] = reinterpret_cast<short(*)[16][144]>(raw);
        unsigned short* Vbp = Y2 + (size_t)b * Cd * Mm;
        const int lane = t & 63;
#pragma unroll
        for (int ot = 0; ot < 2; ++ot) {
#pragma unroll
            for (int nt = 0; nt < 8; ++nt)
#pragma unroll
                for (int r = 0; r < 4; ++r)
                    Vst[w][quad * 4 + r][nt * 16 + lq] = (short)f2b(acc2[ot][nt][r]);
#pragma unroll
            for (int k = 0; k < 4; ++k) {
                int u = lane + k * 64;
                int c_loc = u >> 4, m8 = u & 15;
                int c = o0 + w * 32 + ot * 16 + c_loc;
                int m = n0 + m8 * 8;
                int ct = c >> 5, mb = m >> 4;
                int lf = (c & 31) + 32 * (m8 & 1);
                uint4 v = *(const uint4*)(&Vst[w][c_loc][m8 * 8]);
                *(uint4*)(Vbp + ((size_t)(ct * 64 + mb) * 64 + lf) * 8) = v;
            }
        }
    }
}

// ---------------------------------------------------------------------------
// MFMA GEMM (legacy; MODE 0 f32 store / MODE 2 bf16 D^T for the VALU path).
// ---------------------------------------------------------------------------
template <int MODE>
__global__ __launch_bounds__(256) void gemm_mfma(const float* __restrict__ W,
                                                 const float* __restrict__ X,
                                                 float* __restrict__ Yf,
                                                 unsigned short* __restrict__ Yb,
                                                 int Nx) {
    __shared__ short Xs[64][40];
    __shared__ short Tt[16][72];
    const int t = threadIdx.x;
    const int w = t >> 6, lq = t & 15, quad = (t >> 4) & 3;
    const int b = blockIdx.z, o0 = blockIdx.y * 64, n0 = blockIdx.x * 64;
    const float* Xb = X + (size_t)b * Cd * Nx;
    const float* Wrow = W + (size_t)(o0 + w * 16 + lq) * Cd;

    v4f acc[4];
#pragma unroll
    for (int i = 0; i < 4; ++i) acc[i] = (v4f){0.f, 0.f, 0.f, 0.f};

    for (int c0 = 0; c0 < Cd; c0 += 32) {
#pragma unroll
        for (int p = 0; p < 2; ++p) {
            int i = t + p * 256;
            int c = i >> 4;
            int n4 = (i & 15) * 4;
            float4 x = *(const float4*)(Xb + (size_t)(c0 + c) * Nx + n0 + n4);
            Xs[n4 + 0][c] = (short)f2b(x.x); Xs[n4 + 1][c] = (short)f2b(x.y);
            Xs[n4 + 2][c] = (short)f2b(x.z); Xs[n4 + 3][c] = (short)f2b(x.w);
        }
        union { unsigned short h[8]; s8v s; } af;
        {
            float4 wa = *(const float4*)(Wrow + c0 + quad * 8);
            float4 wb = *(const float4*)(Wrow + c0 + quad * 8 + 4);
            af.h[0] = f2b(wa.x); af.h[1] = f2b(wa.y); af.h[2] = f2b(wa.z); af.h[3] = f2b(wa.w);
            af.h[4] = f2b(wb.x); af.h[5] = f2b(wb.y); af.h[6] = f2b(wb.z); af.h[7] = f2b(wb.w);
        }
        __syncthreads();
#pragma unroll
        for (int nt = 0; nt < 4; ++nt) {
            s8v bf = *(const s8v*)(&Xs[nt * 16 + lq][quad * 8]);
            acc[nt] = mfma16(af.s, bf, acc[nt]);
        }
        __syncthreads();
    }

    if (MODE == 0 || MODE == 1) {
#pragma unroll
        for (int nt = 0; nt < 4; ++nt)
#pragma unroll
            for (int r = 0; r < 4; ++r) {
                int o = o0 + w * 16 + quad * 4 + r;
                int n = n0 + nt * 16 + lq;
                size_t idx = ((size_t)b * Cd + o) * Nx + n;
                if (MODE == 0) Yf[idx] = acc[nt][r];
                else           Yb[idx] = f2b(acc[nt][r]);
            }
    } else {
#pragma unroll
        for (int nt = 0; nt < 4; ++nt) {
#pragma unroll
            for (int r = 0; r < 4; ++r)
                Tt[lq][w * 16 + quad * 4 + r] = (short)f2b(acc[nt][r]);
            __syncthreads();
            int nrow = t >> 4, o4 = (t & 15) * 4;
            ushort4 val = *(const ushort4*)(&Tt[nrow][o4]);
            *(ushort4*)(Yb + ((size_t)b * Nx + n0 + nt * 16 + nrow) * Cd + o0 + o4) = val;
            __syncthreads();
        }
    }
}

// ---------------------------------------------------------------------------
// attn_v2: flash attention, 32x32x16 MFMAs. K/V read directly from global in
// MFMA-fragment-tiled layout (wave-uniform base + lane*16B, fully coalesced).
// ---------------------------------------------------------------------------
__global__ __launch_bounds__(256, 2) void attn_v2(const unsigned short* __restrict__ Qt,
                                                  const unsigned short* __restrict__ Kf,
                                                  const unsigned short* __restrict__ Vf,
                                                  float* __restrict__ out) {
    __shared__ __align__(16) unsigned char Ls[42880];
    unsigned char* Lq = Ls;                                   // Qs: 32x512 bf16 swizzled (32768 B)
    unsigned short* Pb = (unsigned short*)(Ls + 32768);       // Pb[32][136] bf16 (8704 B)
    float* pmaxS  = (float*)(Ls + 41472);                     // [32][4]
    float* psumS  = (float*)(Ls + 41984);                     // [32][4]
    float* muS    = (float*)(Ls + 42496);                     // [32]
    float* ssumS  = (float*)(Ls + 42624);                     // [32]
    float* alphaS = (float*)(Ls + 42752);                     // [32]
    float* OtA    = (float*)Ls;                               // epilogue alias: [4][32][36] f32

    const int t = threadIdx.x;
    const int l = t & 63, w = t >> 6;
    const int lcol = l & 31, lhalf = l >> 5;
    const int bid = blockIdx.x;
    const int b = bid & 7, n0 = (bid >> 3) * 32;

    {
        const unsigned short* qb = Qt + ((size_t)b * Nn + n0) * Cd;
#pragma unroll
        for (int i = 0; i < 8; ++i) {
            int s = i * 256 + t;           // unit id 0..2047
            int n = s >> 6, u = s & 63;
            uint4 v = *(const uint4*)(qb + (size_t)n * Cd + u * 8);
            *(uint4*)(Lq + ((n * 64 + (u ^ (n & 15))) << 4)) = v;
        }
    }
    if (t < 32) { muS[t] = -1e30f; ssumS[t] = 0.f; }

    v16f o_acc[4];
#pragma unroll
    for (int i = 0; i < 4; ++i)
#pragma unroll
        for (int r = 0; r < 16; ++r) o_acc[i][r] = 0.f;
    __syncthreads();

    const unsigned short* Kfb = Kf + (size_t)b * Mm * Cd + (size_t)l * 8;
    const unsigned short* Vfb = Vf + (size_t)b * Cd * Mm + (size_t)l * 8;
    const int qrow = lcol * 64;
    const int swz = lcol & 15;
    const float sc = 0.04419417382415922f;   // 1/sqrt(512)

    for (int m0 = 0; m0 < Mm; m0 += 128) {
        v16f st;
#pragma unroll
        for (int r = 0; r < 16; ++r) st[r] = 0.f;
        const unsigned short* kp = Kfb + (size_t)(((m0 >> 5) + w) * 32) * 512;
#pragma unroll
        for (int kb8 = 0; kb8 < 4; ++kb8) {
            uint4 ka[8];
#pragma unroll
            for (int j = 0; j < 8; ++j) ka[j] = *(const uint4*)(kp + (size_t)(kb8 * 8 + j) * 512);
#pragma unroll
            for (int j = 0; j < 8; ++j) {
                int kb = kb8 * 8 + j;
                s8v qf = *(const s8v*)(Lq + ((qrow + ((kb * 2 + lhalf) ^ swz)) << 4));
                union { uint4 u; s8v s; } av; av.u = ka[j];
                st = mfma32(av.s, qf, st);
            }
        }
#pragma unroll
        for (int r = 0; r < 16; ++r) st[r] *= sc;
        float tm = st[0];
#pragma unroll
        for (int r = 1; r < 16; ++r) tm = fmaxf(tm, st[r]);
        tm = fmaxf(tm, __shfl_xor(tm, 32));
        if (l < 32) pmaxS[l * 4 + w] = tm;
        __syncthreads();   // S1
        if (t < 32) {
            float mx = muS[t];
            mx = fmaxf(mx, fmaxf(fmaxf(pmaxS[t * 4], pmaxS[t * 4 + 1]),
                                 fmaxf(pmaxS[t * 4 + 2], pmaxS[t * 4 + 3])));
            alphaS[t] = __expf(muS[t] - mx);
            muS[t] = mx;
        }
        __syncthreads();   // S2
        {
            float mxn = muS[lcol];
            float e[16], rs = 0.f;
#pragma unroll
            for (int r = 0; r < 16; ++r) { e[r] = __expf(st[r] - mxn); rs += e[r]; }
            rs += __shfl_xor(rs, 32);
            if (l < 32) psumS[l * 4 + w] = rs;
#pragma unroll
            for (int rg = 0; rg < 4; ++rg) {
                ushort4 pk;
                pk.x = f2b(e[rg * 4 + 0]); pk.y = f2b(e[rg * 4 + 1]);
                pk.z = f2b(e[rg * 4 + 2]); pk.w = f2b(e[rg * 4 + 3]);
                *(ushort4*)(Pb + lcol * 136 + w * 32 + 8 * rg + 4 * lhalf) = pk;
            }
        }
        __syncthreads();   // S3
        if (t < 32)
            ssumS[t] = ssumS[t] * alphaS[t] +
                       psumS[t * 4] + psumS[t * 4 + 1] + psumS[t * 4 + 2] + psumS[t * 4 + 3];

        float ar[16];
#pragma unroll
        for (int r = 0; r < 16; ++r)
            ar[r] = alphaS[(r & 3) + 8 * (r >> 2) + 4 * lhalf];
#pragma unroll
        for (int ti = 0; ti < 4; ++ti)
#pragma unroll
            for (int r = 0; r < 16; ++r) o_acc[ti][r] *= ar[r];

        s8v pA[8];
#pragma unroll
        for (int kb = 0; kb < 8; ++kb)
            pA[kb] = *(const s8v*)(Pb + lcol * 136 + kb * 16 + lhalf * 8);

#pragma unroll
        for (int ti = 0; ti < 4; ++ti) {
            const unsigned short* vc = Vfb + (size_t)((ti * 4 + w) * 64 + (m0 >> 4)) * 512;
            uint4 vb8[8];
#pragma unroll
            for (int kb = 0; kb < 8; ++kb) vb8[kb] = *(const uint4*)(vc + (size_t)kb * 512);
#pragma unroll
            for (int kb = 0; kb < 8; ++kb) {
                union { uint4 u; s8v s; } bv; bv.u = vb8[kb];
                o_acc[ti] = mfma32(pA[kb], bv.s, o_acc[ti]);
            }
        }
        __syncthreads();
    }

    float inv[16];
#pragma unroll
    for (int r = 0; r < 16; ++r)
        inv[r] = 1.0f / ssumS[(r & 3) + 8 * (r >> 2) + 4 * lhalf];

    float* OtW = OtA + w * 32 * 36;
#pragma unroll
    for (int ti = 0; ti < 4; ++ti) {
#pragma unroll
        for (int r = 0; r < 16; ++r)
            OtW[lcol * 36 + (r & 3) + 8 * (r >> 2) + 4 * lhalf] = o_acc[ti][r] * inv[r];
        __syncthreads();
        {
            int cloc = l >> 1, half = l & 1;
            int cabs = ti * 128 + w * 32 + cloc;
            const float* src = OtW + cloc * 36 + half * 16;
            float* op = out + ((size_t)b * Cd + cabs) * Nn + n0 + half * 16;
#pragma unroll
            for (int j = 0; j < 4; ++j) {
                float4 a = *(const float4*)(src + j * 4);
                float4 g = *(const float4*)(op + j * 4);
                g.x += a.x; g.y += a.y; g.z += a.z; g.w += a.w;
                *(float4*)(op + j * 4) = g;
            }
        }
        __syncthreads();
    }
}

// ---------------------------------------------------------------------------
// Fallback VALU attention (round-3 proven) for small ws_size.
// ---------------------------------------------------------------------------
__device__ __forceinline__ float u2lo(unsigned int u) {
    union { unsigned int i; float f; } v; v.i = u << 16; return v.f;
}
__device__ __forceinline__ float u2hi(unsigned int u) {
    union { unsigned int i; float f; } v; v.i = u & 0xFFFF0000u; return v.f;
}

__global__ __launch_bounds__(256) void attn_k(const float* __restrict__ up,
                                              const float* __restrict__ Wq,
                                              const unsigned short* __restrict__ Ktb,
                                              const unsigned short* __restrict__ Vtb,
                                              float* __restrict__ out) {
    __shared__ float Qs[16][516];
    __shared__ __align__(16) unsigned char Sraw[24576];
    unsigned short (*Us)[16]  = reinterpret_cast<unsigned short(*)[16]>(Sraw);
    unsigned short (*Wt)[512] = reinterpret_cast<unsigned short(*)[512]>(Sraw + 16384);
    float (*Ps)[65] = reinterpret_cast<float(*)[65]>(Sraw);
    float* mu_s     = reinterpret_cast<float*>(Sraw + 4160);
    float* ssum_s   = reinterpret_cast<float*>(Sraw + 4224);
    float* alpha_s  = reinterpret_cast<float*>(Sraw + 4288);

    const int t = threadIdx.x;
    const int b = blockIdx.y;
    const int n0 = blockIdx.x * 16;
    const int row = t & 15;
    const int grp = t >> 4;

    for (int i = t; i < Cd * 16; i += 256) {
        int c = i >> 4, r = i & 15;
        Us[c][r] = f2b(up[((size_t)b * Cd + c) * Nn + n0 + r]);
    }
    __syncthreads();

    float acc[32];
#pragma unroll
    for (int j = 0; j < 32; ++j) acc[j] = 0.f;

    for (int k0 = 0; k0 < Cd; k0 += 8) {
        for (int i = t; i < 1024; i += 256) {
            int oc = i >> 1;
            int kc = (i & 1) * 4;
            float4 wv = *(const float4*)(Wq + (size_t)oc * Cd + k0 + kc);
            Wt[kc + 0][oc] = f2b(wv.x); Wt[kc + 1][oc] = f2b(wv.y);
            Wt[kc + 2][oc] = f2b(wv.z); Wt[kc + 3][oc] = f2b(wv.w);
        }
        __syncthreads();
#pragma unroll
        for (int k = 0; k < 8; ++k) {
            float u = b2f(Us[k0 + k][row]);
            const ushort4* wr = (const ushort4*)(&Wt[k][grp * 32]);
#pragma unroll
            for (int j4 = 0; j4 < 8; ++j4) {
                ushort4 wv = wr[j4];
                acc[j4 * 4 + 0] += u * b2f(wv.x);
                acc[j4 * 4 + 1] += u * b2f(wv.y);
                acc[j4 * 4 + 2] += u * b2f(wv.z);
                acc[j4 * 4 + 3] += u * b2f(wv.w);
            }
        }
        __syncthreads();
    }

    const float scale = 0.04419417382415922f;
#pragma unroll
    for (int j = 0; j < 32; ++j) Qs[row][grp * 32 + j] = acc[j] * scale;
    if (t < 16) { mu_s[t] = -1e30f; ssum_s[t] = 0.f; }
#pragma unroll
    for (int j = 0; j < 32; ++j) acc[j] = 0.f;
    __syncthreads();

    const float4* qr = (const float4*)(&Qs[row][0]);

    for (int m0 = 0; m0 < Mm; m0 += 64) {
        {
            int mb = m0 + grp * 4;
            const uint4* K0 = (const uint4*)(Ktb + ((size_t)b * Mm + mb + 0) * Cd);
            const uint4* K1 = (const uint4*)(Ktb + ((size_t)b * Mm + mb + 1) * Cd);
            const uint4* K2 = (const uint4*)(Ktb + ((size_t)b * Mm + mb + 2) * Cd);
            const uint4* K3 = (const uint4*)(Ktb + ((size_t)b * Mm + mb + 3) * Cd);
            float a0 = 0.f, a1 = 0.f, a2 = 0.f, a3 = 0.f;
#pragma unroll 4
            for (int c8 = 0; c8 < Cd / 8; ++c8) {
                float4 qa = qr[2 * c8], qb = qr[2 * c8 + 1];
                uint4 k0v = K0[c8], k1v = K1[c8], k2v = K2[c8], k3v = K3[c8];
                a0 += qa.x * u2lo(k0v.x) + qa.y * u2hi(k0v.x) + qa.z * u2lo(k0v.y) + qa.w * u2hi(k0v.y)
                    + qb.x * u2lo(k0v.z) + qb.y * u2hi(k0v.z) + qb.z * u2lo(k0v.w) + qb.w * u2hi(k0v.w);
                a1 += qa.x * u2lo(k1v.x) + qa.y * u2hi(k1v.x) + qa.z * u2lo(k1v.y) + qa.w * u2hi(k1v.y)
                    + qb.x * u2lo(k1v.z) + qb.y * u2hi(k1v.z) + qb.z * u2lo(k1v.w) + qb.w * u2hi(k1v.w);
                a2 += qa.x * u2lo(k2v.x) + qa.y * u2hi(k2v.x) + qa.z * u2lo(k2v.y) + qa.w * u2hi(k2v.y)
                    + qb.x * u2lo(k2v.z) + qb.y * u2hi(k2v.z) + qb.z * u2lo(k2v.w) + qb.w * u2hi(k2v.w);
                a3 += qa.x * u2lo(k3v.x) + qa.y * u2hi(k3v.x) + qa.z * u2lo(k3v.y) + qa.w * u2hi(k3v.y)
                    + qb.x * u2lo(k3v.z) + qb.y * u2hi(k3v.z) + qb.z * u2lo(k3v.w) + qb.w * u2hi(k3v.w);
            }
            Ps[row][grp * 4 + 0] = a0;
            Ps[row][grp * 4 + 1] = a1;
            Ps[row][grp * 4 + 2] = a2;
            Ps[row][grp * 4 + 3] = a3;
        }
        __syncthreads();
        if (t < 16) {
            float mold = mu_s[t];
            float mx = mold;
            for (int m = 0; m < 64; ++m) mx = fmaxf(mx, Ps[t][m]);
            float al = __expf(mold - mx);
            float s = ssum_s[t] * al;
            for (int m = 0; m < 64; ++m) {
                float p = __expf(Ps[t][m] - mx);
                Ps[t][m] = p;
                s += p;
            }
            mu_s[t] = mx; ssum_s[t] = s; alpha_s[t] = al;
        }
        __syncthreads();
        {
            float arr = alpha_s[row];
#pragma unroll
            for (int j = 0; j < 32; ++j) acc[j] *= arr;
            const unsigned short* Vbase = Vtb + (size_t)b * Mm * Cd + (size_t)grp * 32;
            for (int m = 0; m < 64; ++m) {
                float p = Ps[row][m];
                const uint4* vr = (const uint4*)(Vbase + (size_t)(m0 + m) * Cd);
#pragma unroll
                for (int j4 = 0; j4 < 4; ++j4) {
                    uint4 v = vr[j4];
                    acc[j4 * 8 + 0] += p * u2lo(v.x); acc[j4 * 8 + 1] += p * u2hi(v.x);
                    acc[j4 * 8 + 2] += p * u2lo(v.y); acc[j4 * 8 + 3] += p * u2hi(v.y);
                    acc[j4 * 8 + 4] += p * u2lo(v.z); acc[j4 * 8 + 5] += p * u2hi(v.z);
                    acc[j4 * 8 + 6] += p * u2lo(v.w); acc[j4 * 8 + 7] += p * u2hi(v.w);
                }
            }
        }
        __syncthreads();
    }

    float invv = 1.0f / ssum_s[row];
#pragma unroll
    for (int j = 0; j < 32; ++j) {
        int c = grp * 32 + j;
        size_t idx = ((size_t)b * Cd + c) * Nn + n0 + row;
        out[idx] = out[idx] + acc[j] * invv;
    }
}

// ---------------------------------------------------------------------------
extern "C" void kernel_launch(void* const* d_in, const int* in_sizes, int n_in,
                              void* d_out, int out_size, void* d_ws, size_t ws_size,
                              hipStream_t stream) {
    const float* up   = (const float*)d_in[0];
    const float* down = (const float*)d_in[1];
    const float* Wq   = (const float*)d_in[2];
    const float* Wk   = (const float*)d_in[3];
    const float* Wv   = (const float*)d_in[4];
    const float* Wsk  = (const float*)d_in[5];
    float* out = (float*)d_out;

    const size_t szK = (size_t)Bn * Mm * Cd;   // 4M bf16 elems (8 MiB)
    const size_t szQ = (size_t)Bn * Nn * Cd;   // 16M elems (32 MiB)
    const size_t szW = (size_t)4 * Cd * Cd;    // 1M elems (2 MiB)

    if (ws_size >= (szK * 2 + szW + szQ * 2) * 2) {
        // Full pre-transposed path: 82 MiB. [Kf][Vf][Wb][Xtu][R=Qt/Xtd]
        unsigned short* Kf  = (unsigned short*)d_ws;
        unsigned short* Vf  = Kf + szK;
        unsigned short* Wb  = Vf + szK;
        unsigned short* Xtu = Wb + szW;
        unsigned short* R   = Xtu + szQ;       // Xtd first, then Qt (disjoint lifetimes)
        unsigned short* Xtd = R;
        unsigned short* Qt  = R;
        convw<<<dim3(256, 4), 256, 0, stream>>>(Wq, Wk, Wv, Wsk, Wb);
        convx<<<dim3(Mm / 64, Cd / 64, Bn), 256, 0, stream>>>(down, Xtd, Mm, Mm, 0);
        gemm3<0><<<dim3(8 * (Mm / 128) * 4), 256, 0, stream>>>(Wb, Xtd, nullptr, Kf, Vf, Mm, 0);
        convx<<<dim3(Nn / 64, Cd / 64, Bn), 256, 0, stream>>>(up, Xtu, Nn, Nn, 0);
        gemm3<1><<<dim3(8 * (Nn / 128) * 4), 256, 0, stream>>>(Wb, Xtu, out, Qt, nullptr, Nn, 0);
        attn_v2<<<dim3((Nn / 32) * Bn), 256, 0, stream>>>(Qt, Kf, Vf, out);
    } else if (ws_size >= (szK * 2 + szW + szQ + szK) * 2) {
        // Chunked pre-transposed path: 58 MiB. Shared 8 MiB Xc for down + up chunks.
        unsigned short* Kf = (unsigned short*)d_ws;
        unsigned short* Vf = Kf + szK;
        unsigned short* Wb = Vf + szK;
        unsigned short* Qt = Wb + szW;
        unsigned short* Xc = Qt + szQ;
        convw<<<dim3(256, 4), 256, 0, stream>>>(Wq, Wk, Wv, Wsk, Wb);
        convx<<<dim3(Mm / 64, Cd / 64, Bn), 256, 0, stream>>>(down, Xc, Mm, Mm, 0);
        gemm3<0><<<dim3(8 * (Mm / 128) * 4), 256, 0, stream>>>(Wb, Xc, nullptr, Kf, Vf, Mm, 0);
        for (int ch = 0; ch < 4; ++ch) {
            convx<<<dim3(1024 / 64, Cd / 64, Bn), 256, 0, stream>>>(up, Xc, Nn, 1024, ch * 1024);
            gemm3<1><<<dim3(8 * (1024 / 128) * 4), 256, 0, stream>>>(Wb, Xc, out, Qt, nullptr, 1024, ch * 1024);
        }
        attn_v2<<<dim3((Nn / 32) * Bn), 256, 0, stream>>>(Qt, Kf, Vf, out);
    } else if (ws_size >= (2 * szK + szQ + szW) * 2) {
        // Round-3 proven path (50 MiB): in-loop staging gemm2.
        unsigned short* Kf = (unsigned short*)d_ws;
        unsigned short* Vf = Kf + szK;
        unsigned short* Qt = Vf + szK;
        unsigned short* Wb = Qt + szQ;
        convw<<<dim3(256, 4), 256, 0, stream>>>(Wq, Wk, Wv, Wsk, Wb);
        gemm2<0><<<dim3(256), 256, 0, stream>>>(Wb, down, nullptr, Kf, Vf);
        gemm2<1><<<dim3(1024), 256, 0, stream>>>(Wb, up, out, Qt, nullptr);
        attn_v2<<<dim3((Nn / 32) * Bn), 256, 0, stream>>>(Qt, Kf, Vf, out);
    } else {
        // Fallback (16 MiB ws): VALU attention.
        unsigned short* Ktb = (unsigned short*)d_ws;
        unsigned short* Vtb = Ktb + szK;
        gemm_mfma<2><<<dim3(Mm / 64, Cd / 64, Bn), 256, 0, stream>>>(Wk, down, nullptr, Ktb, Mm);
        gemm_mfma<2><<<dim3(Mm / 64, Cd / 64, Bn), 256, 0, stream>>>(Wv, down, nullptr, Vtb, Mm);
        gemm_mfma<0><<<dim3(Nn / 64, Cd / 64, Bn), 256, 0, stream>>>(Wsk, up, out, nullptr, Nn);
        attn_k<<<dim3(Nn / 16, Bn), 256, 0, stream>>>(up, Wq, Ktb, Vtb, out);
    }
}

// Round 5
// 335.878 us; speedup vs baseline: 1.7737x; 1.1187x over previous
//
#include <hip/hip_runtime.h>
#include <cstddef>

// Problem constants: B=8, C=512, N=4096, M=1024. Inputs f32, output f32.
#define Bn 8
#define Cd 512
#define Nn 4096
#define Mm 1024

typedef __attribute__((ext_vector_type(8))) short s8v;
typedef __attribute__((ext_vector_type(4))) float v4f;
typedef __attribute__((ext_vector_type(16))) float v16f;

__device__ __forceinline__ float b2f(unsigned short u) {
    union { unsigned int i; float f; } v; v.i = ((unsigned int)u) << 16; return v.f;
}
__device__ __forceinline__ unsigned short f2b(float f) {
    union { float f; unsigned int i; } v; v.f = f;
    unsigned int x = v.i;
    unsigned int r = (x + 0x7FFFu + ((x >> 16) & 1u)) >> 16;  // RNE
    return (unsigned short)r;
}
__device__ __forceinline__ v4f mfma16(s8v a, s8v b, v4f c) {
    return __builtin_amdgcn_mfma_f32_16x16x32_bf16(a, b, c, 0, 0, 0);
}
__device__ __forceinline__ v16f mfma32(s8v a, s8v b, v16f c) {
    return __builtin_amdgcn_mfma_f32_32x32x16_bf16(a, b, c, 0, 0, 0);
}
__device__ __forceinline__ void gload_lds16(const unsigned short* gsrc, unsigned char* lds) {
    __builtin_amdgcn_global_load_lds(
        (const __attribute__((address_space(1))) unsigned int*)gsrc,
        (__attribute__((address_space(3))) unsigned int*)lds, 16, 0, 0);
}

// ---------------------------------------------------------------------------
// convwf: W f32[512][512] -> bf16 MFMA A-fragment tiles.
// Wf[wsel][((o16*16 + cstep)*64 + lane)*8 + e], lane=(lq=o&15, quad=(c>>3)&3),
// e=c&7. GEMM then reads af as wave-uniform-base + lane*16B (1 coalesced 1KiB
// transaction vs the previous 16-line gather per fragment).
// ---------------------------------------------------------------------------
__global__ __launch_bounds__(256) void convwf(const float* __restrict__ Wq, const float* __restrict__ Wk,
                                              const float* __restrict__ Wv, const float* __restrict__ Ws,
                                              unsigned short* __restrict__ Wf) {
    const float* S = (blockIdx.y == 0) ? Wq : (blockIdx.y == 1) ? Wk : (blockIdx.y == 2) ? Wv : Ws;
    const int o16 = blockIdx.x;            // 0..31
    const int t = threadIdx.x;
    const int l = t & 63, sub = t >> 6;
    const int lq = l & 15, quad = l >> 4;
    unsigned short* dst = Wf + (size_t)blockIdx.y * 262144;
#pragma unroll
    for (int rep = 0; rep < 4; ++rep) {
        int cstep = sub * 4 + rep;         // 0..15
        const float* src = S + (size_t)(o16 * 16 + lq) * Cd + cstep * 32 + quad * 8;
        float4 va = *(const float4*)(src);
        float4 vb = *(const float4*)(src + 4);
        union { ushort4 h[2]; uint4 q; } pk;
        pk.h[0].x = f2b(va.x); pk.h[0].y = f2b(va.y); pk.h[0].z = f2b(va.z); pk.h[0].w = f2b(va.w);
        pk.h[1].x = f2b(vb.x); pk.h[1].y = f2b(vb.y); pk.h[1].z = f2b(vb.z); pk.h[1].w = f2b(vb.w);
        *(uint4*)(dst + ((size_t)(o16 * 16 + cstep) * 64 + l) * 8) = pk.q;
    }
}

// ---------------------------------------------------------------------------
// convx: transpose+convert X f32[b][C][Nx] -> Xt bf16[b][N][C].
// 64n x 64c tiles; LDS pad 65 floats -> 2-way (free) banks both sides.
// ---------------------------------------------------------------------------
__global__ __launch_bounds__(256) void convx(const float* __restrict__ X,
                                             unsigned short* __restrict__ Xt,
                                             int Nx) {
    __shared__ float Lf[64][65];
    const int t = threadIdx.x;
    const int b = blockIdx.z, c0 = blockIdx.y * 64;
    const int nl0 = blockIdx.x * 64;
    const int cl = t >> 4, n4 = (t & 15) * 4;
    const float* Xb = X + (size_t)b * Cd * Nx + nl0;
#pragma unroll
    for (int cc = 0; cc < 4; ++cc) {
        int c = cc * 16 + cl;
        float4 v = *(const float4*)(Xb + (size_t)(c0 + c) * Nx + n4);
        Lf[n4 + 0][c] = v.x; Lf[n4 + 1][c] = v.y;
        Lf[n4 + 2][c] = v.z; Lf[n4 + 3][c] = v.w;
    }
    __syncthreads();
    unsigned short* Xtb = Xt + ((size_t)b * Nx + nl0) * Cd + c0;
#pragma unroll
    for (int rep = 0; rep < 2; ++rep) {
        int u = t + rep * 256;
        int n = u >> 3, c8 = (u & 7) * 8;
        union { ushort4 h[2]; uint4 q; } pk;
        pk.h[0].x = f2b(Lf[n][c8 + 0]); pk.h[0].y = f2b(Lf[n][c8 + 1]);
        pk.h[0].z = f2b(Lf[n][c8 + 2]); pk.h[0].w = f2b(Lf[n][c8 + 3]);
        pk.h[1].x = f2b(Lf[n][c8 + 4]); pk.h[1].y = f2b(Lf[n][c8 + 5]);
        pk.h[1].z = f2b(Lf[n][c8 + 6]); pk.h[1].w = f2b(Lf[n][c8 + 7]);
        *(uint4*)(Xtb + (size_t)n * Cd + c8) = pk.q;
    }
}

// ---------------------------------------------------------------------------
// gemm4: dual-output GEMM from pre-transposed bf16 Xt[b][n][c], fragment W.
// Block = 32 n-rows x ALL 1024 outputs (W1 512 + W2 512), 4 waves; wave w
// owns o16 tiles [w*8, w*8+8) of each weight. 32 mfma16/thread/32c-step.
// X staged via global_load_lds (linear 2KB tiles, double-buffered, 1 barrier
// per step). W-fragment loads coalesced (base + lane*16B), issued BEFORE the
// staging issue so their waitcnt doesn't drain the in-flight stage (vmcnt FIFO).
// Because a block covers all c_out for its rows, outputs are written IN-PLACE:
// PAIRB=0: XY=Xtd->Kf (A-frags), Y2=Vf (B-frags).  W1=Wk, W2=Wv.
// PAIRB=1: XY=Xtu->Qt[n][c],     outF=out (skip).   W1=Wq, W2=Wskip.
// Fragment layouts (match attn_v2 reader):
//   Kf[((mt*32+kb)*64 + (m&31)+32*((c>>3)&1))*8 + (c&7)]
//   Vf[((ct*64+mb)*64 + (c&31)+32*((m>>3)&1))*8 + (m&7)]
// ---------------------------------------------------------------------------
template <int PAIRB>
__global__ __launch_bounds__(256, 2) void gemm4(const unsigned short* __restrict__ Wf,
                                                unsigned short* XY,
                                                unsigned short* __restrict__ Y2,
                                                float* __restrict__ outF,
                                                int Nc) {
    __shared__ __align__(16) unsigned char raw[PAIRB ? 34816 : 8192];
    const int t = threadIdx.x;
    const int l = t & 63, w = t >> 6, lq = t & 15, quad = (t >> 4) & 3;
    const int bid = blockIdx.x;
    const int b = bid & 7, n0 = (bid >> 3) * 32;
    unsigned short* Xb = XY + ((size_t)b * Nc + n0) * Cd;
    const unsigned short* W1f = Wf + (size_t)(PAIRB ? 0 : 1) * 262144 + (size_t)l * 8;
    const unsigned short* W2f = Wf + (size_t)(PAIRB ? 3 : 2) * 262144 + (size_t)l * 8;

    v4f acc1[8][2], acc2[8][2];
#pragma unroll
    for (int i = 0; i < 8; ++i)
#pragma unroll
        for (int nt = 0; nt < 2; ++nt) {
            acc1[i][nt] = (v4f){0.f, 0.f, 0.f, 0.f};
            acc2[i][nt] = (v4f){0.f, 0.f, 0.f, 0.f};
        }

    // STAGE: 128 units of 16B (32 rows x 32 c bf16), linear LDS.
#define STAGE4(s, c0)                                                            \
    if (t < 128) gload_lds16(Xb + (size_t)(t >> 2) * Cd + (c0) + (t & 3) * 8,    \
                             raw + (s) * 2048 + t * 16);

    STAGE4(0, 0);
    for (int step = 0; step < 16; ++step) {
        const int c0 = step * 32, cur = step & 1;
        __syncthreads();   // buf[cur] staged + prev reads of buf[cur^1] done
        // W fragments first (oldest vmem; waits on them leave the stage in flight)
        s8v a1[8], a2[8];
#pragma unroll
        for (int i = 0; i < 8; ++i)
            a1[i] = *(const s8v*)(W1f + ((size_t)((w * 8 + i) * 16 + step) << 9));
#pragma unroll
        for (int i = 0; i < 8; ++i)
            a2[i] = *(const s8v*)(W2f + ((size_t)((w * 8 + i) * 16 + step) << 9));
        if (step < 15) { STAGE4(cur ^ 1, c0 + 32) }
        const short* Xs = (const short*)(raw + cur * 2048);
        s8v bf0 = *(const s8v*)(Xs + lq * 32 + quad * 8);
        s8v bf1 = *(const s8v*)(Xs + (lq + 16) * 32 + quad * 8);
#pragma unroll
        for (int i = 0; i < 8; ++i) {
            acc1[i][0] = mfma16(a1[i], bf0, acc1[i][0]);
            acc1[i][1] = mfma16(a1[i], bf1, acc1[i][1]);
        }
#pragma unroll
        for (int i = 0; i < 8; ++i) {
            acc2[i][0] = mfma16(a2[i], bf0, acc2[i][0]);
            acc2[i][1] = mfma16(a2[i], bf1, acc2[i][1]);
        }
    }
#undef STAGE4
    __syncthreads();   // all staging reads done before raw reuse / in-place writes

    if (PAIRB) {
        // ---- acc2 (skip) -> out f32 [b][o][n]
#pragma unroll
        for (int i = 0; i < 8; ++i)
#pragma unroll
            for (int nt = 0; nt < 2; ++nt)
#pragma unroll
                for (int r = 0; r < 4; ++r) {
                    int o = (w * 8 + i) * 16 + quad * 4 + r;
                    int n = n0 + nt * 16 + lq;
                    outF[((size_t)b * Cd + o) * Nn + n] = acc2[i][nt][r];
                }
        // ---- acc1 (Q) -> Qt[n][c] IN-PLACE over Xtu via LDS transpose
        short (*T2)[528] = reinterpret_cast<short(*)[528]>(raw);   // [32][528]
#pragma unroll
        for (int i = 0; i < 8; ++i)
#pragma unroll
            for (int nt = 0; nt < 2; ++nt)
#pragma unroll
                for (int r = 0; r < 4; ++r)
                    T2[nt * 16 + lq][(w * 8 + i) * 16 + quad * 4 + r] = (short)f2b(acc1[i][nt][r]);
        __syncthreads();
        {
            int row = t >> 3, cb = (t & 7) * 64;
            unsigned short* qp = Xb + (size_t)row * Cd + cb;   // same bytes this block read
#pragma unroll
            for (int j = 0; j < 8; ++j)
                *(uint4*)(qp + j * 8) = *(const uint4*)(&T2[row][cb + j * 8]);
        }
    } else {
        // ---- acc1 (K) -> Kf fragments IN-PLACE over Xtd (this block's rows)
        const int half = quad >> 1, ebase = (quad & 1) * 4;
        {
            unsigned short* Kb = XY + (size_t)b * Mm * Cd;
            const int mt = n0 >> 5;
#pragma unroll
            for (int i = 0; i < 8; ++i) {
                int kb = w * 8 + i;
#pragma unroll
                for (int nt = 0; nt < 2; ++nt) {
                    int lf = (nt * 16 + lq) + 32 * half;
                    ushort4 v;
                    v.x = f2b(acc1[i][nt][0]); v.y = f2b(acc1[i][nt][1]);
                    v.z = f2b(acc1[i][nt][2]); v.w = f2b(acc1[i][nt][3]);
                    *(ushort4*)(Kb + ((size_t)(mt * 32 + kb) * 64 + lf) * 8 + ebase) = v;
                }
            }
        }
        // ---- acc2 (V) -> Vf fragments via per-wave LDS transpose
        short (*Vst)[40] = reinterpret_cast<short(*)[40]>(raw + w * 1280);   // [16][40]
        unsigned short* Vb0 = Y2 + (size_t)b * Cd * Mm;
#pragma unroll
        for (int i = 0; i < 8; ++i) {
#pragma unroll
            for (int nt = 0; nt < 2; ++nt)
#pragma unroll
                for (int r = 0; r < 4; ++r)
                    Vst[quad * 4 + r][nt * 16 + lq] = (short)f2b(acc2[i][nt][r]);
            // same-wave ds ordering (lgkmcnt) -> no barrier needed
            int c_abs = (w * 8 + i) * 16 + (l >> 2);
            int m8 = l & 3;
            int ct = c_abs >> 5, mb = (n0 >> 4) + (m8 >> 1);
            int lf = (c_abs & 31) + 32 * (m8 & 1);
            uint4 v = *(const uint4*)(&Vst[l >> 2][m8 * 8]);
            *(uint4*)(Vb0 + ((size_t)(ct * 64 + mb) * 64 + lf) * 8) = v;
        }
    }
}

// ---------------------------------------------------------------------------
// MFMA GEMM (legacy, fallback path only). MODE 0: f32 store. MODE 2: bf16 D^T.
// ---------------------------------------------------------------------------
template <int MODE>
__global__ __launch_bounds__(256) void gemm_mfma(const float* __restrict__ W,
                                                 const float* __restrict__ X,
                                                 float* __restrict__ Yf,
                                                 unsigned short* __restrict__ Yb,
                                                 int Nx) {
    __shared__ short Xs[64][40];
    __shared__ short Tt[16][72];
    const int t = threadIdx.x;
    const int w = t >> 6, lq = t & 15, quad = (t >> 4) & 3;
    const int b = blockIdx.z, o0 = blockIdx.y * 64, n0 = blockIdx.x * 64;
    const float* Xb = X + (size_t)b * Cd * Nx;
    const float* Wrow = W + (size_t)(o0 + w * 16 + lq) * Cd;

    v4f acc[4];
#pragma unroll
    for (int i = 0; i < 4; ++i) acc[i] = (v4f){0.f, 0.f, 0.f, 0.f};

    for (int c0 = 0; c0 < Cd; c0 += 32) {
#pragma unroll
        for (int p = 0; p < 2; ++p) {
            int i = t + p * 256;
            int c = i >> 4;
            int n4 = (i & 15) * 4;
            float4 x = *(const float4*)(Xb + (size_t)(c0 + c) * Nx + n0 + n4);
            Xs[n4 + 0][c] = (short)f2b(x.x); Xs[n4 + 1][c] = (short)f2b(x.y);
            Xs[n4 + 2][c] = (short)f2b(x.z); Xs[n4 + 3][c] = (short)f2b(x.w);
        }
        union { unsigned short h[8]; s8v s; } af;
        {
            float4 wa = *(const float4*)(Wrow + c0 + quad * 8);
            float4 wb = *(const float4*)(Wrow + c0 + quad * 8 + 4);
            af.h[0] = f2b(wa.x); af.h[1] = f2b(wa.y); af.h[2] = f2b(wa.z); af.h[3] = f2b(wa.w);
            af.h[4] = f2b(wb.x); af.h[5] = f2b(wb.y); af.h[6] = f2b(wb.z); af.h[7] = f2b(wb.w);
        }
        __syncthreads();
#pragma unroll
        for (int nt = 0; nt < 4; ++nt) {
            s8v bf = *(const s8v*)(&Xs[nt * 16 + lq][quad * 8]);
            acc[nt] = mfma16(af.s, bf, acc[nt]);
        }
        __syncthreads();
    }

    if (MODE == 0) {
#pragma unroll
        for (int nt = 0; nt < 4; ++nt)
#pragma unroll
            for (int r = 0; r < 4; ++r) {
                int o = o0 + w * 16 + quad * 4 + r;
                int n = n0 + nt * 16 + lq;
                Yf[((size_t)b * Cd + o) * Nx + n] = acc[nt][r];
            }
    } else {
#pragma unroll
        for (int nt = 0; nt < 4; ++nt) {
#pragma unroll
            for (int r = 0; r < 4; ++r)
                Tt[lq][w * 16 + quad * 4 + r] = (short)f2b(acc[nt][r]);
            __syncthreads();
            int nrow = t >> 4, o4 = (t & 15) * 4;
            ushort4 val = *(const ushort4*)(&Tt[nrow][o4]);
            *(ushort4*)(Yb + ((size_t)b * Nx + n0 + nt * 16 + nrow) * Cd + o0 + o4) = val;
            __syncthreads();
        }
    }
}

// ---------------------------------------------------------------------------
// attn_v2: flash attention, 32x32x16 MFMAs. K/V read directly from global in
// MFMA-fragment-tiled layout (wave-uniform base + lane*16B, fully coalesced).
// This round: ti=0 V loads prefetched before the softmax barriers (hides L2
// latency under softmax), s_setprio(1) around MFMA bursts.
// ---------------------------------------------------------------------------
__global__ __launch_bounds__(256, 2) void attn_v2(const unsigned short* __restrict__ Qt,
                                                  const unsigned short* __restrict__ Kf,
                                                  const unsigned short* __restrict__ Vf,
                                                  float* __restrict__ out) {
    __shared__ __align__(16) unsigned char Ls[42880];
    unsigned char* Lq = Ls;                                   // Qs: 32x512 bf16 swizzled (32768 B)
    unsigned short* Pb = (unsigned short*)(Ls + 32768);       // Pb[32][136] bf16 (8704 B)
    float* pmaxS  = (float*)(Ls + 41472);                     // [32][4]
    float* psumS  = (float*)(Ls + 41984);                     // [32][4]
    float* muS    = (float*)(Ls + 42496);                     // [32]
    float* ssumS  = (float*)(Ls + 42624);                     // [32]
    float* alphaS = (float*)(Ls + 42752);                     // [32]
    float* OtA    = (float*)Ls;                               // epilogue alias: [4][32][36] f32

    const int t = threadIdx.x;
    const int l = t & 63, w = t >> 6;
    const int lcol = l & 31, lhalf = l >> 5;
    const int bid = blockIdx.x;
    const int b = bid & 7, n0 = (bid >> 3) * 32;

    {
        const unsigned short* qb = Qt + ((size_t)b * Nn + n0) * Cd;
#pragma unroll
        for (int i = 0; i < 8; ++i) {
            int s = i * 256 + t;           // unit id 0..2047
            int n = s >> 6, u = s & 63;
            uint4 v = *(const uint4*)(qb + (size_t)n * Cd + u * 8);
            *(uint4*)(Lq + ((n * 64 + (u ^ (n & 15))) << 4)) = v;
        }
    }
    if (t < 32) { muS[t] = -1e30f; ssumS[t] = 0.f; }

    v16f o_acc[4];
#pragma unroll
    for (int i = 0; i < 4; ++i)
#pragma unroll
        for (int r = 0; r < 16; ++r) o_acc[i][r] = 0.f;
    __syncthreads();

    const unsigned short* Kfb = Kf + (size_t)b * Mm * Cd + (size_t)l * 8;
    const unsigned short* Vfb = Vf + (size_t)b * Cd * Mm + (size_t)l * 8;
    const int qrow = lcol * 64;
    const int swz = lcol & 15;
    const float sc = 0.04419417382415922f;   // 1/sqrt(512)

    for (int m0 = 0; m0 < Mm; m0 += 128) {
        v16f st;
#pragma unroll
        for (int r = 0; r < 16; ++r) st[r] = 0.f;
        const unsigned short* kp = Kfb + (size_t)(((m0 >> 5) + w) * 32) * 512;
#pragma unroll
        for (int kb8 = 0; kb8 < 4; ++kb8) {
            uint4 ka[8];
#pragma unroll
            for (int j = 0; j < 8; ++j) ka[j] = *(const uint4*)(kp + (size_t)(kb8 * 8 + j) * 512);
            __builtin_amdgcn_s_setprio(1);
#pragma unroll
            for (int j = 0; j < 8; ++j) {
                int kb = kb8 * 8 + j;
                s8v qf = *(const s8v*)(Lq + ((qrow + ((kb * 2 + lhalf) ^ swz)) << 4));
                union { uint4 u; s8v s; } av; av.u = ka[j];
                st = mfma32(av.s, qf, st);
            }
            __builtin_amdgcn_s_setprio(0);
        }
        // ---- prefetch V for ti=0 (independent of softmax; hides L2 latency) ----
        uint4 v0p[8];
        {
            const unsigned short* vc = Vfb + (size_t)(w * 64 + (m0 >> 4)) * 512;
#pragma unroll
            for (int kb = 0; kb < 8; ++kb) v0p[kb] = *(const uint4*)(vc + (size_t)kb * 512);
        }
#pragma unroll
        for (int r = 0; r < 16; ++r) st[r] *= sc;
        float tm = st[0];
#pragma unroll
        for (int r = 1; r < 16; ++r) tm = fmaxf(tm, st[r]);
        tm = fmaxf(tm, __shfl_xor(tm, 32));
        if (l < 32) pmaxS[l * 4 + w] = tm;
        __syncthreads();   // S1
        if (t < 32) {
            float mx = muS[t];
            mx = fmaxf(mx, fmaxf(fmaxf(pmaxS[t * 4], pmaxS[t * 4 + 1]),
                                 fmaxf(pmaxS[t * 4 + 2], pmaxS[t * 4 + 3])));
            alphaS[t] = __expf(muS[t] - mx);
            muS[t] = mx;
        }
        __syncthreads();   // S2
        {
            float mxn = muS[lcol];
            float e[16], rs = 0.f;
#pragma unroll
            for (int r = 0; r < 16; ++r) { e[r] = __expf(st[r] - mxn); rs += e[r]; }
            rs += __shfl_xor(rs, 32);
            if (l < 32) psumS[l * 4 + w] = rs;
#pragma unroll
            for (int rg = 0; rg < 4; ++rg) {
                ushort4 pk;
                pk.x = f2b(e[rg * 4 + 0]); pk.y = f2b(e[rg * 4 + 1]);
                pk.z = f2b(e[rg * 4 + 2]); pk.w = f2b(e[rg * 4 + 3]);
                *(ushort4*)(Pb + lcol * 136 + w * 32 + 8 * rg + 4 * lhalf) = pk;
            }
        }
        __syncthreads();   // S3
        if (t < 32)
            ssumS[t] = ssumS[t] * alphaS[t] +
                       psumS[t * 4] + psumS[t * 4 + 1] + psumS[t * 4 + 2] + psumS[t * 4 + 3];

        float ar[16];
#pragma unroll
        for (int r = 0; r < 16; ++r)
            ar[r] = alphaS[(r & 3) + 8 * (r >> 2) + 4 * lhalf];
#pragma unroll
        for (int ti = 0; ti < 4; ++ti)
#pragma unroll
            for (int r = 0; r < 16; ++r) o_acc[ti][r] *= ar[r];

        s8v pA[8];
#pragma unroll
        for (int kb = 0; kb < 8; ++kb)
            pA[kb] = *(const s8v*)(Pb + lcol * 136 + kb * 16 + lhalf * 8);

#pragma unroll
        for (int ti = 0; ti < 4; ++ti) {
            uint4 vb8[8];
            if (ti == 0) {
#pragma unroll
                for (int kb = 0; kb < 8; ++kb) vb8[kb] = v0p[kb];
            } else {
                const unsigned short* vc = Vfb + (size_t)((ti * 4 + w) * 64 + (m0 >> 4)) * 512;
#pragma unroll
                for (int kb = 0; kb < 8; ++kb) vb8[kb] = *(const uint4*)(vc + (size_t)kb * 512);
            }
            __builtin_amdgcn_s_setprio(1);
#pragma unroll
            for (int kb = 0; kb < 8; ++kb) {
                union { uint4 u; s8v s; } bv; bv.u = vb8[kb];
                o_acc[ti] = mfma32(pA[kb], bv.s, o_acc[ti]);
            }
            __builtin_amdgcn_s_setprio(0);
        }
        __syncthreads();
    }

    float inv[16];
#pragma unroll
    for (int r = 0; r < 16; ++r)
        inv[r] = 1.0f / ssumS[(r & 3) + 8 * (r >> 2) + 4 * lhalf];

    float* OtW = OtA + w * 32 * 36;
#pragma unroll
    for (int ti = 0; ti < 4; ++ti) {
#pragma unroll
        for (int r = 0; r < 16; ++r)
            OtW[lcol * 36 + (r & 3) + 8 * (r >> 2) + 4 * lhalf] = o_acc[ti][r] * inv[r];
        __syncthreads();
        {
            int cloc = l >> 1, half = l & 1;
            int cabs = ti * 128 + w * 32 + cloc;
            const float* src = OtW + cloc * 36 + half * 16;
            float* op = out + ((size_t)b * Cd + cabs) * Nn + n0 + half * 16;
#pragma unroll
            for (int j = 0; j < 4; ++j) {
                float4 a = *(const float4*)(src + j * 4);
                float4 g = *(const float4*)(op + j * 4);
                g.x += a.x; g.y += a.y; g.z += a.z; g.w += a.w;
                *(float4*)(op + j * 4) = g;
            }
        }
        __syncthreads();
    }
}

// ---------------------------------------------------------------------------
// Fallback VALU attention (proven) for small ws_size.
// ---------------------------------------------------------------------------
__device__ __forceinline__ float u2lo(unsigned int u) {
    union { unsigned int i; float f; } v; v.i = u << 16; return v.f;
}
__device__ __forceinline__ float u2hi(unsigned int u) {
    union { unsigned int i; float f; } v; v.i = u & 0xFFFF0000u; return v.f;
}

__global__ __launch_bounds__(256) void attn_k(const float* __restrict__ up,
                                              const float* __restrict__ Wq,
                                              const unsigned short* __restrict__ Ktb,
                                              const unsigned short* __restrict__ Vtb,
                                              float* __restrict__ out) {
    __shared__ float Qs[16][516];
    __shared__ __align__(16) unsigned char Sraw[24576];
    unsigned short (*Us)[16]  = reinterpret_cast<unsigned short(*)[16]>(Sraw);
    unsigned short (*Wt)[512] = reinterpret_cast<unsigned short(*)[512]>(Sraw + 16384);
    float (*Ps)[65] = reinterpret_cast<float(*)[65]>(Sraw);
    float* mu_s     = reinterpret_cast<float*>(Sraw + 4160);
    float* ssum_s   = reinterpret_cast<float*>(Sraw + 4224);
    float* alpha_s  = reinterpret_cast<float*>(Sraw + 4288);

    const int t = threadIdx.x;
    const int b = blockIdx.y;
    const int n0 = blockIdx.x * 16;
    const int row = t & 15;
    const int grp = t >> 4;

    for (int i = t; i < Cd * 16; i += 256) {
        int c = i >> 4, r = i & 15;
        Us[c][r] = f2b(up[((size_t)b * Cd + c) * Nn + n0 + r]);
    }
    __syncthreads();

    float acc[32];
#pragma unroll
    for (int j = 0; j < 32; ++j) acc[j] = 0.f;

    for (int k0 = 0; k0 < Cd; k0 += 8) {
        for (int i = t; i < 1024; i += 256) {
            int oc = i >> 1;
            int kc = (i & 1) * 4;
            float4 wv = *(const float4*)(Wq + (size_t)oc * Cd + k0 + kc);
            Wt[kc + 0][oc] = f2b(wv.x); Wt[kc + 1][oc] = f2b(wv.y);
            Wt[kc + 2][oc] = f2b(wv.z); Wt[kc + 3][oc] = f2b(wv.w);
        }
        __syncthreads();
#pragma unroll
        for (int k = 0; k < 8; ++k) {
            float u = b2f(Us[k0 + k][row]);
            const ushort4* wr = (const ushort4*)(&Wt[k][grp * 32]);
#pragma unroll
            for (int j4 = 0; j4 < 8; ++j4) {
                ushort4 wv = wr[j4];
                acc[j4 * 4 + 0] += u * b2f(wv.x);
                acc[j4 * 4 + 1] += u * b2f(wv.y);
                acc[j4 * 4 + 2] += u * b2f(wv.z);
                acc[j4 * 4 + 3] += u * b2f(wv.w);
            }
        }
        __syncthreads();
    }

    const float scale = 0.04419417382415922f;
#pragma unroll
    for (int j = 0; j < 32; ++j) Qs[row][grp * 32 + j] = acc[j] * scale;
    if (t < 16) { mu_s[t] = -1e30f; ssum_s[t] = 0.f; }
#pragma unroll
    for (int j = 0; j < 32; ++j) acc[j] = 0.f;
    __syncthreads();

    const float4* qr = (const float4*)(&Qs[row][0]);

    for (int m0 = 0; m0 < Mm; m0 += 64) {
        {
            int mb = m0 + grp * 4;
            const uint4* K0 = (const uint4*)(Ktb + ((size_t)b * Mm + mb + 0) * Cd);
            const uint4* K1 = (const uint4*)(Ktb + ((size_t)b * Mm + mb + 1) * Cd);
            const uint4* K2 = (const uint4*)(Ktb + ((size_t)b * Mm + mb + 2) * Cd);
            const uint4* K3 = (const uint4*)(Ktb + ((size_t)b * Mm + mb + 3) * Cd);
            float a0 = 0.f, a1 = 0.f, a2 = 0.f, a3 = 0.f;
#pragma unroll 4
            for (int c8 = 0; c8 < Cd / 8; ++c8) {
                float4 qa = qr[2 * c8], qb = qr[2 * c8 + 1];
                uint4 k0v = K0[c8], k1v = K1[c8], k2v = K2[c8], k3v = K3[c8];
                a0 += qa.x * u2lo(k0v.x) + qa.y * u2hi(k0v.x) + qa.z * u2lo(k0v.y) + qa.w * u2hi(k0v.y)
                    + qb.x * u2lo(k0v.z) + qb.y * u2hi(k0v.z) + qb.z * u2lo(k0v.w) + qb.w * u2hi(k0v.w);
                a1 += qa.x * u2lo(k1v.x) + qa.y * u2hi(k1v.x) + qa.z * u2lo(k1v.y) + qa.w * u2hi(k1v.y)
                    + qb.x * u2lo(k1v.z) + qb.y * u2hi(k1v.z) + qb.z * u2lo(k1v.w) + qb.w * u2hi(k1v.w);
                a2 += qa.x * u2lo(k2v.x) + qa.y * u2hi(k2v.x) + qa.z * u2lo(k2v.y) + qa.w * u2hi(k2v.y)
                    + qb.x * u2lo(k2v.z) + qb.y * u2hi(k2v.z) + qb.z * u2lo(k2v.w) + qb.w * u2hi(k2v.w);
                a3 += qa.x * u2lo(k3v.x) + qa.y * u2hi(k3v.x) + qa.z * u2lo(k3v.y) + qa.w * u2hi(k3v.y)
                    + qb.x * u2lo(k3v.z) + qb.y * u2hi(k3v.z) + qb.z * u2lo(k3v.w) + qb.w * u2hi(k3v.w);
            }
            Ps[row][grp * 4 + 0] = a0;
            Ps[row][grp * 4 + 1] = a1;
            Ps[row][grp * 4 + 2] = a2;
            Ps[row][grp * 4 + 3] = a3;
        }
        __syncthreads();
        if (t < 16) {
            float mold = mu_s[t];
            float mx = mold;
            for (int m = 0; m < 64; ++m) mx = fmaxf(mx, Ps[t][m]);
            float al = __expf(mold - mx);
            float s = ssum_s[t] * al;
            for (int m = 0; m < 64; ++m) {
                float p = __expf(Ps[t][m] - mx);
                Ps[t][m] = p;
                s += p;
            }
            mu_s[t] = mx; ssum_s[t] = s; alpha_s[t] = al;
        }
        __syncthreads();
        {
            float arr = alpha_s[row];
#pragma unroll
            for (int j = 0; j < 32; ++j) acc[j] *= arr;
            const unsigned short* Vbase = Vtb + (size_t)b * Mm * Cd + (size_t)grp * 32;
            for (int m = 0; m < 64; ++m) {
                float p = Ps[row][m];
                const uint4* vr = (const uint4*)(Vbase + (size_t)(m0 + m) * Cd);
#pragma unroll
                for (int j4 = 0; j4 < 4; ++j4) {
                    uint4 v = vr[j4];
                    acc[j4 * 8 + 0] += p * u2lo(v.x); acc[j4 * 8 + 1] += p * u2hi(v.x);
                    acc[j4 * 8 + 2] += p * u2lo(v.y); acc[j4 * 8 + 3] += p * u2hi(v.y);
                    acc[j4 * 8 + 4] += p * u2lo(v.z); acc[j4 * 8 + 5] += p * u2hi(v.z);
                    acc[j4 * 8 + 6] += p * u2lo(v.w); acc[j4 * 8 + 7] += p * u2hi(v.w);
                }
            }
        }
        __syncthreads();
    }

    float invv = 1.0f / ssum_s[row];
#pragma unroll
    for (int j = 0; j < 32; ++j) {
        int c = grp * 32 + j;
        size_t idx = ((size_t)b * Cd + c) * Nn + n0 + row;
        out[idx] = out[idx] + acc[j] * invv;
    }
}

// ---------------------------------------------------------------------------
extern "C" void kernel_launch(void* const* d_in, const int* in_sizes, int n_in,
                              void* d_out, int out_size, void* d_ws, size_t ws_size,
                              hipStream_t stream) {
    const float* up   = (const float*)d_in[0];
    const float* down = (const float*)d_in[1];
    const float* Wq   = (const float*)d_in[2];
    const float* Wk   = (const float*)d_in[3];
    const float* Wv   = (const float*)d_in[4];
    const float* Wsk  = (const float*)d_in[5];
    float* out = (float*)d_out;

    const size_t szK = (size_t)Bn * Mm * Cd;   // 4M bf16 elems (8 MiB)
    const size_t szQ = (size_t)Bn * Nn * Cd;   // 16M elems (32 MiB)
    const size_t szW = (size_t)4 * Cd * Cd;    // 1M elems (2 MiB)

    if (ws_size >= (2 * szK + szQ + szW) * 2) {
        // 50 MiB path (same gate round 3 proved): in-place pre-transposed GEMMs.
        // [XK: Xtd->Kf 8MiB][Vf 8MiB][XQ: Xtu->Qt 32MiB][Wf 2MiB]
        unsigned short* XK = (unsigned short*)d_ws;
        unsigned short* Vf = XK + szK;
        unsigned short* XQ = Vf + szK;
        unsigned short* Wf = XQ + szQ;
        convwf<<<dim3(32, 4), 256, 0, stream>>>(Wq, Wk, Wv, Wsk, Wf);
        convx<<<dim3(Mm / 64, Cd / 64, Bn), 256, 0, stream>>>(down, XK, Mm);
        gemm4<0><<<dim3(Bn * (Mm / 32)), 256, 0, stream>>>(Wf, XK, Vf, nullptr, Mm);
        convx<<<dim3(Nn / 64, Cd / 64, Bn), 256, 0, stream>>>(up, XQ, Nn);
        gemm4<1><<<dim3(Bn * (Nn / 32)), 256, 0, stream>>>(Wf, XQ, nullptr, out, Nn);
        attn_v2<<<dim3((Nn / 32) * Bn), 256, 0, stream>>>(XQ, XK, Vf, out);
    } else {
        // Fallback (16 MiB ws): VALU attention.
        unsigned short* Ktb = (unsigned short*)d_ws;
        unsigned short* Vtb = Ktb + szK;
        gemm_mfma<2><<<dim3(Mm / 64, Cd / 64, Bn), 256, 0, stream>>>(Wk, down, nullptr, Ktb, Mm);
        gemm_mfma<2><<<dim3(Mm / 64, Cd / 64, Bn), 256, 0, stream>>>(Wv, down, nullptr, Vtb, Mm);
        gemm_mfma<0><<<dim3(Nn / 64, Cd / 64, Bn), 256, 0, stream>>>(Wsk, up, out, nullptr, Nn);
        attn_k<<<dim3(Nn / 16, Bn), 256, 0, stream>>>(up, Wq, Ktb, Vtb, out);
    }
}

// Round 6
// 324.190 us; speedup vs baseline: 1.8376x; 1.0361x over previous
//
#include <hip/hip_runtime.h>
#include <cstddef>

// Problem constants: B=8, C=512, N=4096, M=1024. Inputs f32, output f32.
#define Bn 8
#define Cd 512
#define Nn 4096
#define Mm 1024

typedef __attribute__((ext_vector_type(8))) short s8v;
typedef __attribute__((ext_vector_type(4))) float v4f;
typedef __attribute__((ext_vector_type(16))) float v16f;

__device__ __forceinline__ float b2f(unsigned short u) {
    union { unsigned int i; float f; } v; v.i = ((unsigned int)u) << 16; return v.f;
}
__device__ __forceinline__ unsigned short f2b(float f) {
    union { float f; unsigned int i; } v; v.f = f;
    unsigned int x = v.i;
    unsigned int r = (x + 0x7FFFu + ((x >> 16) & 1u)) >> 16;  // RNE
    return (unsigned short)r;
}
__device__ __forceinline__ v4f mfma16(s8v a, s8v b, v4f c) {
    return __builtin_amdgcn_mfma_f32_16x16x32_bf16(a, b, c, 0, 0, 0);
}
__device__ __forceinline__ v16f mfma32(s8v a, s8v b, v16f c) {
    return __builtin_amdgcn_mfma_f32_32x32x16_bf16(a, b, c, 0, 0, 0);
}
__device__ __forceinline__ void gload_lds16(const unsigned short* gsrc, unsigned char* lds) {
    __builtin_amdgcn_global_load_lds(
        (const __attribute__((address_space(1))) unsigned int*)gsrc,
        (__attribute__((address_space(3))) unsigned int*)lds, 16, 0, 0);
}

// ---------------------------------------------------------------------------
// convwf: W f32[512][512] -> bf16 MFMA A-fragment tiles.
// Wf[wsel][((o16*16 + cstep)*64 + lane)*8 + e], lane=(lq=o&15, quad=(c>>3)&3),
// e=c&7. GEMM reads af as wave-uniform-base + lane*16B (coalesced 1KiB).
// ---------------------------------------------------------------------------
__global__ __launch_bounds__(256) void convwf(const float* __restrict__ Wq, const float* __restrict__ Wk,
                                              const float* __restrict__ Wv, const float* __restrict__ Ws,
                                              unsigned short* __restrict__ Wf) {
    const float* S = (blockIdx.y == 0) ? Wq : (blockIdx.y == 1) ? Wk : (blockIdx.y == 2) ? Wv : Ws;
    const int o16 = blockIdx.x;            // 0..31
    const int t = threadIdx.x;
    const int l = t & 63, sub = t >> 6;
    const int lq = l & 15, quad = l >> 4;
    unsigned short* dst = Wf + (size_t)blockIdx.y * 262144;
#pragma unroll
    for (int rep = 0; rep < 4; ++rep) {
        int cstep = sub * 4 + rep;         // 0..15
        const float* src = S + (size_t)(o16 * 16 + lq) * Cd + cstep * 32 + quad * 8;
        float4 va = *(const float4*)(src);
        float4 vb = *(const float4*)(src + 4);
        union { ushort4 h[2]; uint4 q; } pk;
        pk.h[0].x = f2b(va.x); pk.h[0].y = f2b(va.y); pk.h[0].z = f2b(va.z); pk.h[0].w = f2b(va.w);
        pk.h[1].x = f2b(vb.x); pk.h[1].y = f2b(vb.y); pk.h[1].z = f2b(vb.z); pk.h[1].w = f2b(vb.w);
        *(uint4*)(dst + ((size_t)(o16 * 16 + cstep) * 64 + l) * 8) = pk.q;
    }
}

// ---------------------------------------------------------------------------
// convx: transpose+convert X f32[b][C][Nx] -> Xt bf16[b][N][C].
// 64n x 64c tiles; LDS pad 65 floats -> 2-way (free) banks both sides.
// ---------------------------------------------------------------------------
__global__ __launch_bounds__(256) void convx(const float* __restrict__ X,
                                             unsigned short* __restrict__ Xt,
                                             int Nx) {
    __shared__ float Lf[64][65];
    const int t = threadIdx.x;
    const int b = blockIdx.z, c0 = blockIdx.y * 64;
    const int nl0 = blockIdx.x * 64;
    const int cl = t >> 4, n4 = (t & 15) * 4;
    const float* Xb = X + (size_t)b * Cd * Nx + nl0;
#pragma unroll
    for (int cc = 0; cc < 4; ++cc) {
        int c = cc * 16 + cl;
        float4 v = *(const float4*)(Xb + (size_t)(c0 + c) * Nx + n4);
        Lf[n4 + 0][c] = v.x; Lf[n4 + 1][c] = v.y;
        Lf[n4 + 2][c] = v.z; Lf[n4 + 3][c] = v.w;
    }
    __syncthreads();
    unsigned short* Xtb = Xt + ((size_t)b * Nx + nl0) * Cd + c0;
#pragma unroll
    for (int rep = 0; rep < 2; ++rep) {
        int u = t + rep * 256;
        int n = u >> 3, c8 = (u & 7) * 8;
        union { ushort4 h[2]; uint4 q; } pk;
        pk.h[0].x = f2b(Lf[n][c8 + 0]); pk.h[0].y = f2b(Lf[n][c8 + 1]);
        pk.h[0].z = f2b(Lf[n][c8 + 2]); pk.h[0].w = f2b(Lf[n][c8 + 3]);
        pk.h[1].x = f2b(Lf[n][c8 + 4]); pk.h[1].y = f2b(Lf[n][c8 + 5]);
        pk.h[1].z = f2b(Lf[n][c8 + 6]); pk.h[1].w = f2b(Lf[n][c8 + 7]);
        *(uint4*)(Xtb + (size_t)n * Cd + c8) = pk.q;
    }
}

// ---------------------------------------------------------------------------
// gemm4: dual-output GEMM from pre-transposed bf16 Xt[b][n][c], fragment W.
// Block = 32 n-rows x ALL 1024 outputs, 4 waves. X staged via global_load_lds
// (linear, double-buffered, 1 barrier/step); W fragment loads coalesced.
// Outputs written IN-PLACE over the consumed X rows (block-local).
// PAIRB=0: XY=Xtd->Kf (A-frags), Y2=Vf (B-frags).  W1=Wk, W2=Wv.
// PAIRB=1: XY=Xtu->Qt[n][c],     outF=out (skip).   W1=Wq, W2=Wskip.
// ---------------------------------------------------------------------------
template <int PAIRB>
__global__ __launch_bounds__(256, 2) void gemm4(const unsigned short* __restrict__ Wf,
                                                unsigned short* XY,
                                                unsigned short* __restrict__ Y2,
                                                float* __restrict__ outF,
                                                int Nc) {
    __shared__ __align__(16) unsigned char raw[PAIRB ? 34816 : 8192];
    const int t = threadIdx.x;
    const int l = t & 63, w = t >> 6, lq = t & 15, quad = (t >> 4) & 3;
    const int bid = blockIdx.x;
    const int b = bid & 7, n0 = (bid >> 3) * 32;
    unsigned short* Xb = XY + ((size_t)b * Nc + n0) * Cd;
    const unsigned short* W1f = Wf + (size_t)(PAIRB ? 0 : 1) * 262144 + (size_t)l * 8;
    const unsigned short* W2f = Wf + (size_t)(PAIRB ? 3 : 2) * 262144 + (size_t)l * 8;

    v4f acc1[8][2], acc2[8][2];
#pragma unroll
    for (int i = 0; i < 8; ++i)
#pragma unroll
        for (int nt = 0; nt < 2; ++nt) {
            acc1[i][nt] = (v4f){0.f, 0.f, 0.f, 0.f};
            acc2[i][nt] = (v4f){0.f, 0.f, 0.f, 0.f};
        }

#define STAGE4(s, c0)                                                            \
    if (t < 128) gload_lds16(Xb + (size_t)(t >> 2) * Cd + (c0) + (t & 3) * 8,    \
                             raw + (s) * 2048 + t * 16);

    STAGE4(0, 0);
    for (int step = 0; step < 16; ++step) {
        const int c0 = step * 32, cur = step & 1;
        __syncthreads();
        s8v a1[8], a2[8];
#pragma unroll
        for (int i = 0; i < 8; ++i)
            a1[i] = *(const s8v*)(W1f + ((size_t)((w * 8 + i) * 16 + step) << 9));
#pragma unroll
        for (int i = 0; i < 8; ++i)
            a2[i] = *(const s8v*)(W2f + ((size_t)((w * 8 + i) * 16 + step) << 9));
        if (step < 15) { STAGE4(cur ^ 1, c0 + 32) }
        const short* Xs = (const short*)(raw + cur * 2048);
        s8v bf0 = *(const s8v*)(Xs + lq * 32 + quad * 8);
        s8v bf1 = *(const s8v*)(Xs + (lq + 16) * 32 + quad * 8);
#pragma unroll
        for (int i = 0; i < 8; ++i) {
            acc1[i][0] = mfma16(a1[i], bf0, acc1[i][0]);
            acc1[i][1] = mfma16(a1[i], bf1, acc1[i][1]);
        }
#pragma unroll
        for (int i = 0; i < 8; ++i) {
            acc2[i][0] = mfma16(a2[i], bf0, acc2[i][0]);
            acc2[i][1] = mfma16(a2[i], bf1, acc2[i][1]);
        }
    }
#undef STAGE4
    __syncthreads();

    if (PAIRB) {
#pragma unroll
        for (int i = 0; i < 8; ++i)
#pragma unroll
            for (int nt = 0; nt < 2; ++nt)
#pragma unroll
                for (int r = 0; r < 4; ++r) {
                    int o = (w * 8 + i) * 16 + quad * 4 + r;
                    int n = n0 + nt * 16 + lq;
                    outF[((size_t)b * Cd + o) * Nn + n] = acc2[i][nt][r];
                }
        short (*T2)[528] = reinterpret_cast<short(*)[528]>(raw);   // [32][528]
#pragma unroll
        for (int i = 0; i < 8; ++i)
#pragma unroll
            for (int nt = 0; nt < 2; ++nt)
#pragma unroll
                for (int r = 0; r < 4; ++r)
                    T2[nt * 16 + lq][(w * 8 + i) * 16 + quad * 4 + r] = (short)f2b(acc1[i][nt][r]);
        __syncthreads();
        {
            int row = t >> 3, cb = (t & 7) * 64;
            unsigned short* qp = Xb + (size_t)row * Cd + cb;
#pragma unroll
            for (int j = 0; j < 8; ++j)
                *(uint4*)(qp + j * 8) = *(const uint4*)(&T2[row][cb + j * 8]);
        }
    } else {
        const int half = quad >> 1, ebase = (quad & 1) * 4;
        {
            unsigned short* Kb = XY + (size_t)b * Mm * Cd;
            const int mt = n0 >> 5;
#pragma unroll
            for (int i = 0; i < 8; ++i) {
                int kb = w * 8 + i;
#pragma unroll
                for (int nt = 0; nt < 2; ++nt) {
                    int lf = (nt * 16 + lq) + 32 * half;
                    ushort4 v;
                    v.x = f2b(acc1[i][nt][0]); v.y = f2b(acc1[i][nt][1]);
                    v.z = f2b(acc1[i][nt][2]); v.w = f2b(acc1[i][nt][3]);
                    *(ushort4*)(Kb + ((size_t)(mt * 32 + kb) * 64 + lf) * 8 + ebase) = v;
                }
            }
        }
        short (*Vst)[40] = reinterpret_cast<short(*)[40]>(raw + w * 1280);   // [16][40]
        unsigned short* Vb0 = Y2 + (size_t)b * Cd * Mm;
#pragma unroll
        for (int i = 0; i < 8; ++i) {
#pragma unroll
            for (int nt = 0; nt < 2; ++nt)
#pragma unroll
                for (int r = 0; r < 4; ++r)
                    Vst[quad * 4 + r][nt * 16 + lq] = (short)f2b(acc2[i][nt][r]);
            int c_abs = (w * 8 + i) * 16 + (l >> 2);
            int m8 = l & 3;
            int ct = c_abs >> 5, mb = (n0 >> 4) + (m8 >> 1);
            int lf = (c_abs & 31) + 32 * (m8 & 1);
            uint4 v = *(const uint4*)(&Vst[l >> 2][m8 * 8]);
            *(uint4*)(Vb0 + ((size_t)(ct * 64 + mb) * 64 + lf) * 8) = v;
        }
    }
}

// ---------------------------------------------------------------------------
// MFMA GEMM (legacy, fallback path only). MODE 0: f32 store. MODE 2: bf16 D^T.
// ---------------------------------------------------------------------------
template <int MODE>
__global__ __launch_bounds__(256) void gemm_mfma(const float* __restrict__ W,
                                                 const float* __restrict__ X,
                                                 float* __restrict__ Yf,
                                                 unsigned short* __restrict__ Yb,
                                                 int Nx) {
    __shared__ short Xs[64][40];
    __shared__ short Tt[16][72];
    const int t = threadIdx.x;
    const int w = t >> 6, lq = t & 15, quad = (t >> 4) & 3;
    const int b = blockIdx.z, o0 = blockIdx.y * 64, n0 = blockIdx.x * 64;
    const float* Xb = X + (size_t)b * Cd * Nx;
    const float* Wrow = W + (size_t)(o0 + w * 16 + lq) * Cd;

    v4f acc[4];
#pragma unroll
    for (int i = 0; i < 4; ++i) acc[i] = (v4f){0.f, 0.f, 0.f, 0.f};

    for (int c0 = 0; c0 < Cd; c0 += 32) {
#pragma unroll
        for (int p = 0; p < 2; ++p) {
            int i = t + p * 256;
            int c = i >> 4;
            int n4 = (i & 15) * 4;
            float4 x = *(const float4*)(Xb + (size_t)(c0 + c) * Nx + n0 + n4);
            Xs[n4 + 0][c] = (short)f2b(x.x); Xs[n4 + 1][c] = (short)f2b(x.y);
            Xs[n4 + 2][c] = (short)f2b(x.z); Xs[n4 + 3][c] = (short)f2b(x.w);
        }
        union { unsigned short h[8]; s8v s; } af;
        {
            float4 wa = *(const float4*)(Wrow + c0 + quad * 8);
            float4 wb = *(const float4*)(Wrow + c0 + quad * 8 + 4);
            af.h[0] = f2b(wa.x); af.h[1] = f2b(wa.y); af.h[2] = f2b(wa.z); af.h[3] = f2b(wa.w);
            af.h[4] = f2b(wb.x); af.h[5] = f2b(wb.y); af.h[6] = f2b(wb.z); af.h[7] = f2b(wb.w);
        }
        __syncthreads();
#pragma unroll
        for (int nt = 0; nt < 4; ++nt) {
            s8v bf = *(const s8v*)(&Xs[nt * 16 + lq][quad * 8]);
            acc[nt] = mfma16(af.s, bf, acc[nt]);
        }
        __syncthreads();
    }

    if (MODE == 0) {
#pragma unroll
        for (int nt = 0; nt < 4; ++nt)
#pragma unroll
            for (int r = 0; r < 4; ++r) {
                int o = o0 + w * 16 + quad * 4 + r;
                int n = n0 + nt * 16 + lq;
                Yf[((size_t)b * Cd + o) * Nx + n] = acc[nt][r];
            }
    } else {
#pragma unroll
        for (int nt = 0; nt < 4; ++nt) {
#pragma unroll
            for (int r = 0; r < 4; ++r)
                Tt[lq][w * 16 + quad * 4 + r] = (short)f2b(acc[nt][r]);
            __syncthreads();
            int nrow = t >> 4, o4 = (t & 15) * 4;
            ushort4 val = *(const ushort4*)(&Tt[nrow][o4]);
            *(ushort4*)(Yb + ((size_t)b * Nx + n0 + nt * 16 + nrow) * Cd + o0 + o4) = val;
            __syncthreads();
        }
    }
}

// ---------------------------------------------------------------------------
// attn_v3: flash attention, 64 q-rows/block (2x attn_v2) to HALVE per-q K/V
// L2 traffic (attn_v2 was L2-BW-bound: 128 blocks/batch x 2MB K+V = 256MB/XCD
// ~= 60us at 4.3TB/s per-XCD L2). 512 thr / 8 waves, m-chunk 256 (wave w owns
// m-tile w). Q in 64KB LDS shared by all waves; Pb[64][264]. PV: wave w owns
// c-tiles {w*2, w*2+1} (o_acc[2][2]). LDS 104KB -> 1 block/CU, 2 waves/SIMD
// (same as v2). Cross-wave softmax reduce fully parallel (64 rows x 8
// partials, 8-lane shfl). Barrier rate halved vs v2.
// ---------------------------------------------------------------------------
__global__ __launch_bounds__(512, 2) void attn_v3(const unsigned short* __restrict__ Qt,
                                                  const unsigned short* __restrict__ Kf,
                                                  const unsigned short* __restrict__ Vf,
                                                  float* __restrict__ out) {
    __shared__ __align__(16) unsigned char Ls[104192];
    unsigned char* Lq = Ls;                                   // 64x512 bf16 swizzled (65536)
    unsigned short* Pb = (unsigned short*)(Ls + 65536);       // [64][264] bf16 (33792)
    float* pmaxS  = (float*)(Ls + 99328);                     // [64][8]
    float* psumS  = (float*)(Ls + 101376);                    // [64][8]
    float* muS    = (float*)(Ls + 103424);                    // [64]
    float* ssumS  = (float*)(Ls + 103680);                    // [64]
    float* alphaS = (float*)(Ls + 103936);                    // [64]
    float* OtA    = (float*)Ls;                               // epilogue alias [8][32][36] f32

    const int t = threadIdx.x;
    const int l = t & 63, w = t >> 6;          // 8 waves
    const int lcol = l & 31, lhalf = l >> 5;
    const int bid = blockIdx.x;
    const int b = bid & 7, n0 = (bid >> 3) * 64;

    // ---- stage Q (64 rows x 512 c bf16) swizzled: unit u of row n at u^(n&15)
    {
        const unsigned short* qb = Qt + ((size_t)b * Nn + n0) * Cd;
#pragma unroll
        for (int i = 0; i < 8; ++i) {
            int s = i * 512 + t;           // unit id 0..4095
            int n = s >> 6, u = s & 63;
            uint4 v = *(const uint4*)(qb + (size_t)n * Cd + u * 8);
            *(uint4*)(Lq + ((n * 64 + (u ^ (n & 15))) << 4)) = v;
        }
    }
    if (t < 64) { muS[t] = -1e30f; ssumS[t] = 0.f; }

    v16f o_acc[2][2];
#pragma unroll
    for (int nh = 0; nh < 2; ++nh)
#pragma unroll
        for (int ti = 0; ti < 2; ++ti)
#pragma unroll
            for (int r = 0; r < 16; ++r) o_acc[nh][ti][r] = 0.f;
    __syncthreads();

    const unsigned short* Kfb = Kf + (size_t)b * Mm * Cd + (size_t)l * 8;
    const unsigned short* Vfb = Vf + (size_t)b * Cd * Mm + (size_t)l * 8;
    const int q0 = lcol * 64, q1 = (lcol + 32) * 64;
    const int swz = lcol & 15;
    const float sc = 0.04419417382415922f;   // 1/sqrt(512)

    for (int m0 = 0; m0 < Mm; m0 += 256) {
        // ---- QK^T: wave w owns m-tile (m0/32 + w); S^T for n 0..63 (two halves)
        v16f st0, st1;
#pragma unroll
        for (int r = 0; r < 16; ++r) { st0[r] = 0.f; st1[r] = 0.f; }
        const unsigned short* kp = Kfb + (size_t)(((m0 >> 5) + w) * 32) * 512;
#pragma unroll
        for (int kb8 = 0; kb8 < 4; ++kb8) {
            uint4 ka[8];
#pragma unroll
            for (int j = 0; j < 8; ++j) ka[j] = *(const uint4*)(kp + (size_t)(kb8 * 8 + j) * 512);
            __builtin_amdgcn_s_setprio(1);
#pragma unroll
            for (int j = 0; j < 8; ++j) {
                int kb = kb8 * 8 + j;
                int uo = (kb * 2 + lhalf) ^ swz;
                s8v qf0 = *(const s8v*)(Lq + ((q0 + uo) << 4));
                s8v qf1 = *(const s8v*)(Lq + ((q1 + uo) << 4));
                union { uint4 u; s8v s; } av; av.u = ka[j];
                st0 = mfma32(av.s, qf0, st0);
                st1 = mfma32(av.s, qf1, st1);
            }
            __builtin_amdgcn_s_setprio(0);
        }
        // ---- prefetch V (ti=0, first 8 fragments): hides L2 latency under softmax
        uint4 v0p[8];
        {
            const unsigned short* vc = Vfb + (size_t)((w * 2) * 64 + (m0 >> 4)) * 512;
#pragma unroll
            for (int j = 0; j < 8; ++j) v0p[j] = *(const uint4*)(vc + (size_t)j * 512);
        }
        // ---- partial max per wave (16 regs = 16 of 32 m) ----
#pragma unroll
        for (int r = 0; r < 16; ++r) { st0[r] *= sc; st1[r] *= sc; }
        float tm0 = st0[0], tm1 = st1[0];
#pragma unroll
        for (int r = 1; r < 16; ++r) { tm0 = fmaxf(tm0, st0[r]); tm1 = fmaxf(tm1, st1[r]); }
        tm0 = fmaxf(tm0, __shfl_xor(tm0, 32));
        tm1 = fmaxf(tm1, __shfl_xor(tm1, 32));
        if (l < 32) {
            pmaxS[l * 8 + w] = tm0;
            pmaxS[(l + 32) * 8 + w] = tm1;
        }
        __syncthreads();   // S1
        {   // cross-wave max reduce: 64 rows x 8 partials, fully parallel
            int row = t >> 3, p = t & 7;
            float v = pmaxS[row * 8 + p];
            v = fmaxf(v, __shfl_xor(v, 1));
            v = fmaxf(v, __shfl_xor(v, 2));
            v = fmaxf(v, __shfl_xor(v, 4));
            if (p == 0) {
                float mold = muS[row];
                float mx = fmaxf(mold, v);
                alphaS[row] = __expf(mold - mx);
                muS[row] = mx;
            }
        }
        __syncthreads();   // S2
        {
            float mx0 = muS[lcol], mx1 = muS[lcol + 32];
            float e0[16], e1[16], rs0 = 0.f, rs1 = 0.f;
#pragma unroll
            for (int r = 0; r < 16; ++r) {
                e0[r] = __expf(st0[r] - mx0); rs0 += e0[r];
                e1[r] = __expf(st1[r] - mx1); rs1 += e1[r];
            }
            rs0 += __shfl_xor(rs0, 32);
            rs1 += __shfl_xor(rs1, 32);
            if (l < 32) {
                psumS[l * 8 + w] = rs0;
                psumS[(l + 32) * 8 + w] = rs1;
            }
#pragma unroll
            for (int rg = 0; rg < 4; ++rg) {
                ushort4 pk0, pk1;
                pk0.x = f2b(e0[rg * 4 + 0]); pk0.y = f2b(e0[rg * 4 + 1]);
                pk0.z = f2b(e0[rg * 4 + 2]); pk0.w = f2b(e0[rg * 4 + 3]);
                pk1.x = f2b(e1[rg * 4 + 0]); pk1.y = f2b(e1[rg * 4 + 1]);
                pk1.z = f2b(e1[rg * 4 + 2]); pk1.w = f2b(e1[rg * 4 + 3]);
                *(ushort4*)(Pb + lcol * 264 + w * 32 + 8 * rg + 4 * lhalf) = pk0;
                *(ushort4*)(Pb + (lcol + 32) * 264 + w * 32 + 8 * rg + 4 * lhalf) = pk1;
            }
        }
        __syncthreads();   // S3
        {   // cross-wave sum reduce + running denom
            int row = t >> 3, p = t & 7;
            float v = psumS[row * 8 + p];
            v += __shfl_xor(v, 1);
            v += __shfl_xor(v, 2);
            v += __shfl_xor(v, 4);
            if (p == 0) ssumS[row] = ssumS[row] * alphaS[row] + v;
        }

        // ---- rescale accumulators ----
        float ar0[16], ar1[16];
#pragma unroll
        for (int r = 0; r < 16; ++r) {
            int crow = (r & 3) + 8 * (r >> 2) + 4 * lhalf;
            ar0[r] = alphaS[crow];
            ar1[r] = alphaS[32 + crow];
        }
#pragma unroll
        for (int ti = 0; ti < 2; ++ti)
#pragma unroll
            for (int r = 0; r < 16; ++r) {
                o_acc[0][ti][r] *= ar0[r];
                o_acc[1][ti][r] *= ar1[r];
            }

        // ---- PV: wave w owns c-tiles {w*2, w*2+1}; 16 V fragments each ----
#pragma unroll
        for (int h = 0; h < 2; ++h) {
            s8v pA0[8], pA1[8];
#pragma unroll
            for (int j = 0; j < 8; ++j) {
                pA0[j] = *(const s8v*)(Pb + lcol * 264 + (h * 8 + j) * 16 + lhalf * 8);
                pA1[j] = *(const s8v*)(Pb + (lcol + 32) * 264 + (h * 8 + j) * 16 + lhalf * 8);
            }
#pragma unroll
            for (int ti = 0; ti < 2; ++ti) {
                uint4 vb[8];
                if (h == 0 && ti == 0) {
#pragma unroll
                    for (int j = 0; j < 8; ++j) vb[j] = v0p[j];
                } else {
                    const unsigned short* vc = Vfb + (size_t)((w * 2 + ti) * 64 + (m0 >> 4) + h * 8) * 512;
#pragma unroll
                    for (int j = 0; j < 8; ++j) vb[j] = *(const uint4*)(vc + (size_t)j * 512);
                }
                __builtin_amdgcn_s_setprio(1);
#pragma unroll
                for (int j = 0; j < 8; ++j) {
                    union { uint4 u; s8v s; } bv; bv.u = vb[j];
                    o_acc[0][ti] = mfma32(pA0[j], bv.s, o_acc[0][ti]);
                    o_acc[1][ti] = mfma32(pA1[j], bv.s, o_acc[1][ti]);
                }
                __builtin_amdgcn_s_setprio(0);
            }
        }
        __syncthreads();   // protect Pb/pmax/psum/alphaS for next chunk
    }

    // ---- epilogue: out[b][c][n0..n0+63] += O / l (per-wave LDS transpose) ----
    float inv0[16], inv1[16];
#pragma unroll
    for (int r = 0; r < 16; ++r) {
        int crow = (r & 3) + 8 * (r >> 2) + 4 * lhalf;
        inv0[r] = 1.0f / ssumS[crow];
        inv1[r] = 1.0f / ssumS[32 + crow];
    }
    float* OtW = OtA + w * 32 * 36;     // per-wave region; Lq is dead
#pragma unroll
    for (int nh = 0; nh < 2; ++nh)
#pragma unroll
        for (int ti = 0; ti < 2; ++ti) {
#pragma unroll
            for (int r = 0; r < 16; ++r) {
                int crow = (r & 3) + 8 * (r >> 2) + 4 * lhalf;
                OtW[lcol * 36 + crow] = o_acc[nh][ti][r] * (nh ? inv1[r] : inv0[r]);
            }
            // same-wave LDS ordering (in-order DS pipe) -> no barrier needed
            int cloc = l >> 1, half = l & 1;
            int cabs = (w * 2 + ti) * 32 + cloc;
            const float* src = OtW + cloc * 36 + half * 16;
            float* op = out + ((size_t)b * Cd + cabs) * Nn + n0 + nh * 32 + half * 16;
#pragma unroll
            for (int j = 0; j < 4; ++j) {
                float4 a = *(const float4*)(src + j * 4);
                float4 g = *(const float4*)(op + j * 4);
                g.x += a.x; g.y += a.y; g.z += a.z; g.w += a.w;
                *(float4*)(op + j * 4) = g;
            }
        }
}

// ---------------------------------------------------------------------------
// Fallback VALU attention (proven) for small ws_size.
// ---------------------------------------------------------------------------
__device__ __forceinline__ float u2lo(unsigned int u) {
    union { unsigned int i; float f; } v; v.i = u << 16; return v.f;
}
__device__ __forceinline__ float u2hi(unsigned int u) {
    union { unsigned int i; float f; } v; v.i = u & 0xFFFF0000u; return v.f;
}

__global__ __launch_bounds__(256) void attn_k(const float* __restrict__ up,
                                              const float* __restrict__ Wq,
                                              const unsigned short* __restrict__ Ktb,
                                              const unsigned short* __restrict__ Vtb,
                                              float* __restrict__ out) {
    __shared__ float Qs[16][516];
    __shared__ __align__(16) unsigned char Sraw[24576];
    unsigned short (*Us)[16]  = reinterpret_cast<unsigned short(*)[16]>(Sraw);
    unsigned short (*Wt)[512] = reinterpret_cast<unsigned short(*)[512]>(Sraw + 16384);
    float (*Ps)[65] = reinterpret_cast<float(*)[65]>(Sraw);
    float* mu_s     = reinterpret_cast<float*>(Sraw + 4160);
    float* ssum_s   = reinterpret_cast<float*>(Sraw + 4224);
    float* alpha_s  = reinterpret_cast<float*>(Sraw + 4288);

    const int t = threadIdx.x;
    const int b = blockIdx.y;
    const int n0 = blockIdx.x * 16;
    const int row = t & 15;
    const int grp = t >> 4;

    for (int i = t; i < Cd * 16; i += 256) {
        int c = i >> 4, r = i & 15;
        Us[c][r] = f2b(up[((size_t)b * Cd + c) * Nn + n0 + r]);
    }
    __syncthreads();

    float acc[32];
#pragma unroll
    for (int j = 0; j < 32; ++j) acc[j] = 0.f;

    for (int k0 = 0; k0 < Cd; k0 += 8) {
        for (int i = t; i < 1024; i += 256) {
            int oc = i >> 1;
            int kc = (i & 1) * 4;
            float4 wv = *(const float4*)(Wq + (size_t)oc * Cd + k0 + kc);
            Wt[kc + 0][oc] = f2b(wv.x); Wt[kc + 1][oc] = f2b(wv.y);
            Wt[kc + 2][oc] = f2b(wv.z); Wt[kc + 3][oc] = f2b(wv.w);
        }
        __syncthreads();
#pragma unroll
        for (int k = 0; k < 8; ++k) {
            float u = b2f(Us[k0 + k][row]);
            const ushort4* wr = (const ushort4*)(&Wt[k][grp * 32]);
#pragma unroll
            for (int j4 = 0; j4 < 8; ++j4) {
                ushort4 wv = wr[j4];
                acc[j4 * 4 + 0] += u * b2f(wv.x);
                acc[j4 * 4 + 1] += u * b2f(wv.y);
                acc[j4 * 4 + 2] += u * b2f(wv.z);
                acc[j4 * 4 + 3] += u * b2f(wv.w);
            }
        }
        __syncthreads();
    }

    const float scale = 0.04419417382415922f;
#pragma unroll
    for (int j = 0; j < 32; ++j) Qs[row][grp * 32 + j] = acc[j] * scale;
    if (t < 16) { mu_s[t] = -1e30f; ssum_s[t] = 0.f; }
#pragma unroll
    for (int j = 0; j < 32; ++j) acc[j] = 0.f;
    __syncthreads();

    const float4* qr = (const float4*)(&Qs[row][0]);

    for (int m0 = 0; m0 < Mm; m0 += 64) {
        {
            int mb = m0 + grp * 4;
            const uint4* K0 = (const uint4*)(Ktb + ((size_t)b * Mm + mb + 0) * Cd);
            const uint4* K1 = (const uint4*)(Ktb + ((size_t)b * Mm + mb + 1) * Cd);
            const uint4* K2 = (const uint4*)(Ktb + ((size_t)b * Mm + mb + 2) * Cd);
            const uint4* K3 = (const uint4*)(Ktb + ((size_t)b * Mm + mb + 3) * Cd);
            float a0 = 0.f, a1 = 0.f, a2 = 0.f, a3 = 0.f;
#pragma unroll 4
            for (int c8 = 0; c8 < Cd / 8; ++c8) {
                float4 qa = qr[2 * c8], qb = qr[2 * c8 + 1];
                uint4 k0v = K0[c8], k1v = K1[c8], k2v = K2[c8], k3v = K3[c8];
                a0 += qa.x * u2lo(k0v.x) + qa.y * u2hi(k0v.x) + qa.z * u2lo(k0v.y) + qa.w * u2hi(k0v.y)
                    + qb.x * u2lo(k0v.z) + qb.y * u2hi(k0v.z) + qb.z * u2lo(k0v.w) + qb.w * u2hi(k0v.w);
                a1 += qa.x * u2lo(k1v.x) + qa.y * u2hi(k1v.x) + qa.z * u2lo(k1v.y) + qa.w * u2hi(k1v.y)
                    + qb.x * u2lo(k1v.z) + qb.y * u2hi(k1v.z) + qb.z * u2lo(k1v.w) + qb.w * u2hi(k1v.w);
                a2 += qa.x * u2lo(k2v.x) + qa.y * u2hi(k2v.x) + qa.z * u2lo(k2v.y) + qa.w * u2hi(k2v.y)
                    + qb.x * u2lo(k2v.z) + qb.y * u2hi(k2v.z) + qb.z * u2lo(k2v.w) + qb.w * u2hi(k2v.w);
                a3 += qa.x * u2lo(k3v.x) + qa.y * u2hi(k3v.x) + qa.z * u2lo(k3v.y) + qa.w * u2hi(k3v.y)
                    + qb.x * u2lo(k3v.z) + qb.y * u2hi(k3v.z) + qb.z * u2lo(k3v.w) + qb.w * u2hi(k3v.w);
            }
            Ps[row][grp * 4 + 0] = a0;
            Ps[row][grp * 4 + 1] = a1;
            Ps[row][grp * 4 + 2] = a2;
            Ps[row][grp * 4 + 3] = a3;
        }
        __syncthreads();
        if (t < 16) {
            float mold = mu_s[t];
            float mx = mold;
            for (int m = 0; m < 64; ++m) mx = fmaxf(mx, Ps[t][m]);
            float al = __expf(mold - mx);
            float s = ssum_s[t] * al;
            for (int m = 0; m < 64; ++m) {
                float p = __expf(Ps[t][m] - mx);
                Ps[t][m] = p;
                s += p;
            }
            mu_s[t] = mx; ssum_s[t] = s; alpha_s[t] = al;
        }
        __syncthreads();
        {
            float arr = alpha_s[row];
#pragma unroll
            for (int j = 0; j < 32; ++j) acc[j] *= arr;
            const unsigned short* Vbase = Vtb + (size_t)b * Mm * Cd + (size_t)grp * 32;
            for (int m = 0; m < 64; ++m) {
                float p = Ps[row][m];
                const uint4* vr = (const uint4*)(Vbase + (size_t)(m0 + m) * Cd);
#pragma unroll
                for (int j4 = 0; j4 < 4; ++j4) {
                    uint4 v = vr[j4];
                    acc[j4 * 8 + 0] += p * u2lo(v.x); acc[j4 * 8 + 1] += p * u2hi(v.x);
                    acc[j4 * 8 + 2] += p * u2lo(v.y); acc[j4 * 8 + 3] += p * u2hi(v.y);
                    acc[j4 * 8 + 4] += p * u2lo(v.z); acc[j4 * 8 + 5] += p * u2hi(v.z);
                    acc[j4 * 8 + 6] += p * u2lo(v.w); acc[j4 * 8 + 7] += p * u2hi(v.w);
                }
            }
        }
        __syncthreads();
    }

    float invv = 1.0f / ssum_s[row];
#pragma unroll
    for (int j = 0; j < 32; ++j) {
        int c = grp * 32 + j;
        size_t idx = ((size_t)b * Cd + c) * Nn + n0 + row;
        out[idx] = out[idx] + acc[j] * invv;
    }
}

// ---------------------------------------------------------------------------
extern "C" void kernel_launch(void* const* d_in, const int* in_sizes, int n_in,
                              void* d_out, int out_size, void* d_ws, size_t ws_size,
                              hipStream_t stream) {
    const float* up   = (const float*)d_in[0];
    const float* down = (const float*)d_in[1];
    const float* Wq   = (const float*)d_in[2];
    const float* Wk   = (const float*)d_in[3];
    const float* Wv   = (const float*)d_in[4];
    const float* Wsk  = (const float*)d_in[5];
    float* out = (float*)d_out;

    const size_t szK = (size_t)Bn * Mm * Cd;   // 4M bf16 elems (8 MiB)
    const size_t szQ = (size_t)Bn * Nn * Cd;   // 16M elems (32 MiB)
    const size_t szW = (size_t)4 * Cd * Cd;    // 1M elems (2 MiB)

    if (ws_size >= (2 * szK + szQ + szW) * 2) {
        // 50 MiB path: in-place pre-transposed GEMMs + 64-row-tile attention.
        // [XK: Xtd->Kf 8MiB][Vf 8MiB][XQ: Xtu->Qt 32MiB][Wf 2MiB]
        unsigned short* XK = (unsigned short*)d_ws;
        unsigned short* Vf = XK + szK;
        unsigned short* XQ = Vf + szK;
        unsigned short* Wf = XQ + szQ;
        convwf<<<dim3(32, 4), 256, 0, stream>>>(Wq, Wk, Wv, Wsk, Wf);
        convx<<<dim3(Mm / 64, Cd / 64, Bn), 256, 0, stream>>>(down, XK, Mm);
        gemm4<0><<<dim3(Bn * (Mm / 32)), 256, 0, stream>>>(Wf, XK, Vf, nullptr, Mm);
        convx<<<dim3(Nn / 64, Cd / 64, Bn), 256, 0, stream>>>(up, XQ, Nn);
        gemm4<1><<<dim3(Bn * (Nn / 32)), 256, 0, stream>>>(Wf, XQ, nullptr, out, Nn);
        attn_v3<<<dim3((Nn / 64) * Bn), 512, 0, stream>>>(XQ, XK, Vf, out);
    } else {
        // Fallback (16 MiB ws): VALU attention.
        unsigned short* Ktb = (unsigned short*)d_ws;
        unsigned short* Vtb = Ktb + szK;
        gemm_mfma<2><<<dim3(Mm / 64, Cd / 64, Bn), 256, 0, stream>>>(Wk, down, nullptr, Ktb, Mm);
        gemm_mfma<2><<<dim3(Mm / 64, Cd / 64, Bn), 256, 0, stream>>>(Wv, down, nullptr, Vtb, Mm);
        gemm_mfma<0><<<dim3(Nn / 64, Cd / 64, Bn), 256, 0, stream>>>(Wsk, up, out, nullptr, Nn);
        attn_k<<<dim3(Nn / 16, Bn), 256, 0, stream>>>(up, Wq, Ktb, Vtb, out);
    }
}

// Round 7
// 281.369 us; speedup vs baseline: 2.1173x; 1.1522x over previous
//
#include <hip/hip_runtime.h>
#include <cstddef>

// Problem constants: B=8, C=512, N=4096, M=1024. Inputs f32, output f32.
#define Bn 8
#define Cd 512
#define Nn 4096
#define Mm 1024

typedef __attribute__((ext_vector_type(8))) short s8v;
typedef __attribute__((ext_vector_type(4))) float v4f;
typedef __attribute__((ext_vector_type(16))) float v16f;

__device__ __forceinline__ float b2f(unsigned short u) {
    union { unsigned int i; float f; } v; v.i = ((unsigned int)u) << 16; return v.f;
}
__device__ __forceinline__ unsigned short f2b(float f) {
    union { float f; unsigned int i; } v; v.f = f;
    unsigned int x = v.i;
    unsigned int r = (x + 0x7FFFu + ((x >> 16) & 1u)) >> 16;  // RNE
    return (unsigned short)r;
}
__device__ __forceinline__ v4f mfma16(s8v a, s8v b, v4f c) {
    return __builtin_amdgcn_mfma_f32_16x16x32_bf16(a, b, c, 0, 0, 0);
}
__device__ __forceinline__ v16f mfma32(s8v a, s8v b, v16f c) {
    return __builtin_amdgcn_mfma_f32_32x32x16_bf16(a, b, c, 0, 0, 0);
}
__device__ __forceinline__ void gload_lds16(const unsigned short* gsrc, unsigned char* lds) {
    __builtin_amdgcn_global_load_lds(
        (const __attribute__((address_space(1))) unsigned int*)gsrc,
        (__attribute__((address_space(3))) unsigned int*)lds, 16, 0, 0);
}

// ---------------------------------------------------------------------------
// convwf: W f32[512][512] -> bf16 MFMA A-fragment tiles.
// Wf[wsel][((o16*16 + cstep)*64 + lane)*8 + e]; lane holds W[o16*16+(l&15)]
// [cstep*32+(l>>4)*8 ..+8]. Readers get wave-uniform-base + lane*16B.
// ---------------------------------------------------------------------------
__global__ __launch_bounds__(256) void convwf(const float* __restrict__ Wq, const float* __restrict__ Wk,
                                              const float* __restrict__ Wv, const float* __restrict__ Ws,
                                              unsigned short* __restrict__ Wf) {
    const float* S = (blockIdx.y == 0) ? Wq : (blockIdx.y == 1) ? Wk : (blockIdx.y == 2) ? Wv : Ws;
    const int o16 = blockIdx.x;            // 0..31
    const int t = threadIdx.x;
    const int l = t & 63, sub = t >> 6;
    const int lq = l & 15, quad = l >> 4;
    unsigned short* dst = Wf + (size_t)blockIdx.y * 262144;
#pragma unroll
    for (int rep = 0; rep < 4; ++rep) {
        int cstep = sub * 4 + rep;         // 0..15
        const float* src = S + (size_t)(o16 * 16 + lq) * Cd + cstep * 32 + quad * 8;
        float4 va = *(const float4*)(src);
        float4 vb = *(const float4*)(src + 4);
        union { ushort4 h[2]; uint4 q; } pk;
        pk.h[0].x = f2b(va.x); pk.h[0].y = f2b(va.y); pk.h[0].z = f2b(va.z); pk.h[0].w = f2b(va.w);
        pk.h[1].x = f2b(vb.x); pk.h[1].y = f2b(vb.y); pk.h[1].z = f2b(vb.z); pk.h[1].w = f2b(vb.w);
        *(uint4*)(dst + ((size_t)(o16 * 16 + cstep) * 64 + l) * 8) = pk.q;
    }
}

// ---------------------------------------------------------------------------
// convx: transpose+convert X f32[b][C][Nx] -> Xt bf16[b][N][C]. (down only now)
// ---------------------------------------------------------------------------
__global__ __launch_bounds__(256) void convx(const float* __restrict__ X,
                                             unsigned short* __restrict__ Xt,
                                             int Nx) {
    __shared__ float Lf[64][65];
    const int t = threadIdx.x;
    const int b = blockIdx.z, c0 = blockIdx.y * 64;
    const int nl0 = blockIdx.x * 64;
    const int cl = t >> 4, n4 = (t & 15) * 4;
    const float* Xb = X + (size_t)b * Cd * Nx + nl0;
#pragma unroll
    for (int cc = 0; cc < 4; ++cc) {
        int c = cc * 16 + cl;
        float4 v = *(const float4*)(Xb + (size_t)(c0 + c) * Nx + n4);
        Lf[n4 + 0][c] = v.x; Lf[n4 + 1][c] = v.y;
        Lf[n4 + 2][c] = v.z; Lf[n4 + 3][c] = v.w;
    }
    __syncthreads();
    unsigned short* Xtb = Xt + ((size_t)b * Nx + nl0) * Cd + c0;
#pragma unroll
    for (int rep = 0; rep < 2; ++rep) {
        int u = t + rep * 256;
        int n = u >> 3, c8 = (u & 7) * 8;
        union { ushort4 h[2]; uint4 q; } pk;
        pk.h[0].x = f2b(Lf[n][c8 + 0]); pk.h[0].y = f2b(Lf[n][c8 + 1]);
        pk.h[0].z = f2b(Lf[n][c8 + 2]); pk.h[0].w = f2b(Lf[n][c8 + 3]);
        pk.h[1].x = f2b(Lf[n][c8 + 4]); pk.h[1].y = f2b(Lf[n][c8 + 5]);
        pk.h[1].z = f2b(Lf[n][c8 + 6]); pk.h[1].w = f2b(Lf[n][c8 + 7]);
        *(uint4*)(Xtb + (size_t)n * Cd + c8) = pk.q;
    }
}

// ---------------------------------------------------------------------------
// gemm4<0> (proven round 5/6): K/V GEMM from Xtd bf16[b][m][c], fragment W.
// Block = 32 m-rows x all 1024 outputs (Wk 512 + Wv 512), in-place Kf over Xtd.
// ---------------------------------------------------------------------------
template <int PAIRB>
__global__ __launch_bounds__(256, 2) void gemm4(const unsigned short* __restrict__ Wf,
                                                unsigned short* XY,
                                                unsigned short* __restrict__ Y2,
                                                float* __restrict__ outF,
                                                int Nc) {
    __shared__ __align__(16) unsigned char raw[8192];
    const int t = threadIdx.x;
    const int l = t & 63, w = t >> 6, lq = t & 15, quad = (t >> 4) & 3;
    const int bid = blockIdx.x;
    const int b = bid & 7, n0 = (bid >> 3) * 32;
    unsigned short* Xb = XY + ((size_t)b * Nc + n0) * Cd;
    const unsigned short* W1f = Wf + (size_t)1 * 262144 + (size_t)l * 8;
    const unsigned short* W2f = Wf + (size_t)2 * 262144 + (size_t)l * 8;

    v4f acc1[8][2], acc2[8][2];
#pragma unroll
    for (int i = 0; i < 8; ++i)
#pragma unroll
        for (int nt = 0; nt < 2; ++nt) {
            acc1[i][nt] = (v4f){0.f, 0.f, 0.f, 0.f};
            acc2[i][nt] = (v4f){0.f, 0.f, 0.f, 0.f};
        }

#define STAGE4(s, c0)                                                            \
    if (t < 128) gload_lds16(Xb + (size_t)(t >> 2) * Cd + (c0) + (t & 3) * 8,    \
                             raw + (s) * 2048 + t * 16);

    STAGE4(0, 0);
    for (int step = 0; step < 16; ++step) {
        const int c0 = step * 32, cur = step & 1;
        __syncthreads();
        s8v a1[8], a2[8];
#pragma unroll
        for (int i = 0; i < 8; ++i)
            a1[i] = *(const s8v*)(W1f + ((size_t)((w * 8 + i) * 16 + step) << 9));
#pragma unroll
        for (int i = 0; i < 8; ++i)
            a2[i] = *(const s8v*)(W2f + ((size_t)((w * 8 + i) * 16 + step) << 9));
        if (step < 15) { STAGE4(cur ^ 1, c0 + 32) }
        const short* Xs = (const short*)(raw + cur * 2048);
        s8v bf0 = *(const s8v*)(Xs + lq * 32 + quad * 8);
        s8v bf1 = *(const s8v*)(Xs + (lq + 16) * 32 + quad * 8);
#pragma unroll
        for (int i = 0; i < 8; ++i) {
            acc1[i][0] = mfma16(a1[i], bf0, acc1[i][0]);
            acc1[i][1] = mfma16(a1[i], bf1, acc1[i][1]);
        }
#pragma unroll
        for (int i = 0; i < 8; ++i) {
            acc2[i][0] = mfma16(a2[i], bf0, acc2[i][0]);
            acc2[i][1] = mfma16(a2[i], bf1, acc2[i][1]);
        }
    }
#undef STAGE4
    __syncthreads();

    // ---- acc1 (K) -> Kf fragments IN-PLACE over Xtd rows
    const int half = quad >> 1, ebase = (quad & 1) * 4;
    {
        unsigned short* Kb = XY + (size_t)b * Mm * Cd;
        const int mt = n0 >> 5;
#pragma unroll
        for (int i = 0; i < 8; ++i) {
            int kb = w * 8 + i;
#pragma unroll
            for (int nt = 0; nt < 2; ++nt) {
                int lf = (nt * 16 + lq) + 32 * half;
                ushort4 v;
                v.x = f2b(acc1[i][nt][0]); v.y = f2b(acc1[i][nt][1]);
                v.z = f2b(acc1[i][nt][2]); v.w = f2b(acc1[i][nt][3]);
                *(ushort4*)(Kb + ((size_t)(mt * 32 + kb) * 64 + lf) * 8 + ebase) = v;
            }
        }
    }
    // ---- acc2 (V) -> Vf fragments via per-wave LDS transpose
    short (*Vst)[40] = reinterpret_cast<short(*)[40]>(raw + w * 1280);   // [16][40]
    unsigned short* Vb0 = Y2 + (size_t)b * Cd * Mm;
#pragma unroll
    for (int i = 0; i < 8; ++i) {
#pragma unroll
        for (int nt = 0; nt < 2; ++nt)
#pragma unroll
            for (int r = 0; r < 4; ++r)
                Vst[quad * 4 + r][nt * 16 + lq] = (short)f2b(acc2[i][nt][r]);
        int c_abs = (w * 8 + i) * 16 + (l >> 2);
        int m8 = l & 3;
        int ct = c_abs >> 5, mb = (n0 >> 4) + (m8 >> 1);
        int lf = (c_abs & 31) + 32 * (m8 & 1);
        uint4 v = *(const uint4*)(&Vst[l >> 2][m8 * 8]);
        *(uint4*)(Vb0 + ((size_t)(ct * 64 + mb) * 64 + lf) * 8) = v;
    }
}

// ---------------------------------------------------------------------------
// MFMA GEMM (legacy, fallback path only). MODE 0: f32 store. MODE 2: bf16 D^T.
// ---------------------------------------------------------------------------
template <int MODE>
__global__ __launch_bounds__(256) void gemm_mfma(const float* __restrict__ W,
                                                 const float* __restrict__ X,
                                                 float* __restrict__ Yf,
                                                 unsigned short* __restrict__ Yb,
                                                 int Nx) {
    __shared__ short Xs[64][40];
    __shared__ short Tt[16][72];
    const int t = threadIdx.x;
    const int w = t >> 6, lq = t & 15, quad = (t >> 4) & 3;
    const int b = blockIdx.z, o0 = blockIdx.y * 64, n0 = blockIdx.x * 64;
    const float* Xb = X + (size_t)b * Cd * Nx;
    const float* Wrow = W + (size_t)(o0 + w * 16 + lq) * Cd;

    v4f acc[4];
#pragma unroll
    for (int i = 0; i < 4; ++i) acc[i] = (v4f){0.f, 0.f, 0.f, 0.f};

    for (int c0 = 0; c0 < Cd; c0 += 32) {
#pragma unroll
        for (int p = 0; p < 2; ++p) {
            int i = t + p * 256;
            int c = i >> 4;
            int n4 = (i & 15) * 4;
            float4 x = *(const float4*)(Xb + (size_t)(c0 + c) * Nx + n0 + n4);
            Xs[n4 + 0][c] = (short)f2b(x.x); Xs[n4 + 1][c] = (short)f2b(x.y);
            Xs[n4 + 2][c] = (short)f2b(x.z); Xs[n4 + 3][c] = (short)f2b(x.w);
        }
        union { unsigned short h[8]; s8v s; } af;
        {
            float4 wa = *(const float4*)(Wrow + c0 + quad * 8);
            float4 wb = *(const float4*)(Wrow + c0 + quad * 8 + 4);
            af.h[0] = f2b(wa.x); af.h[1] = f2b(wa.y); af.h[2] = f2b(wa.z); af.h[3] = f2b(wa.w);
            af.h[4] = f2b(wb.x); af.h[5] = f2b(wb.y); af.h[6] = f2b(wb.z); af.h[7] = f2b(wb.w);
        }
        __syncthreads();
#pragma unroll
        for (int nt = 0; nt < 4; ++nt) {
            s8v bf = *(const s8v*)(&Xs[nt * 16 + lq][quad * 8]);
            acc[nt] = mfma16(af.s, bf, acc[nt]);
        }
        __syncthreads();
    }

    if (MODE == 0) {
#pragma unroll
        for (int nt = 0; nt < 4; ++nt)
#pragma unroll
            for (int r = 0; r < 4; ++r) {
                int o = o0 + w * 16 + quad * 4 + r;
                int n = n0 + nt * 16 + lq;
                Yf[((size_t)b * Cd + o) * Nx + n] = acc[nt][r];
            }
    } else {
#pragma unroll
        for (int nt = 0; nt < 4; ++nt) {
#pragma unroll
            for (int r = 0; r < 4; ++r)
                Tt[lq][w * 16 + quad * 4 + r] = (short)f2b(acc[nt][r]);
            __syncthreads();
            int nrow = t >> 4, o4 = (t & 15) * 4;
            ushort4 val = *(const ushort4*)(&Tt[nrow][o4]);
            *(ushort4*)(Yb + ((size_t)b * Nx + n0 + nt * 16 + nrow) * Cd + o0 + o4) = val;
            __syncthreads();
        }
    }
}

// ---------------------------------------------------------------------------
// attn_f: fused Q-projection + skip-projection + flash attention.
// Block = 64 q-rows (b, n0), 512 thr / 8 waves. Prologue:
//  (1) stage up[b][:, n0:n0+64] f32 -> Xu bf16 swizzled in Lq (in-kernel
//      transpose; kills convx(up));
//  (2) wave w computes Q[o=w*64..+63][64n] and skip[same] via the PROVEN
//      gemm4 MFMA mapping (A=Wf frags coalesced, B=Xu from LDS, 2-way-free
//      banks via the ^(n&15) swizzle); skip stored straight to out (pure
//      store; epilogue RMW-add unchanged); Q written over Xu in Lq, swizzled.
//  Kills gemm4<1> + Qt round-trip entirely. Main loop/epilogue = attn_v3
//  (proven): m-chunk 256, wave w owns m-tile w; PV c-tiles {w*2,w*2+1};
//  V-prefetch + setprio.
// ---------------------------------------------------------------------------
__global__ __launch_bounds__(512, 2) void attn_f(const float* __restrict__ up,
                                                 const unsigned short* __restrict__ Wf,
                                                 const unsigned short* __restrict__ Kf,
                                                 const unsigned short* __restrict__ Vf,
                                                 float* __restrict__ out) {
    __shared__ __align__(16) unsigned char Ls[104192];
    unsigned char* Lq = Ls;                                   // Xu then Q: 64x512 bf16 swizzled (65536)
    unsigned short* Pb = (unsigned short*)(Ls + 65536);       // [64][264] bf16 (33792)
    float* pmaxS  = (float*)(Ls + 99328);                     // [64][8]
    float* psumS  = (float*)(Ls + 101376);                    // [64][8]
    float* muS    = (float*)(Ls + 103424);                    // [64]
    float* ssumS  = (float*)(Ls + 103680);                    // [64]
    float* alphaS = (float*)(Ls + 103936);                    // [64]
    float* OtA    = (float*)Ls;                               // epilogue alias [8][32][36] f32

    const int t = threadIdx.x;
    const int l = t & 63, w = t >> 6;          // 8 waves
    const int lcol = l & 31, lhalf = l >> 5;
    const int lq = l & 15, quad = (l >> 4) & 3;
    const int bid = blockIdx.x;
    const int b = bid & 7, n0 = (bid >> 3) * 64;

    // ---- (1) stage up rows -> Xu bf16 swizzled: unit u of row n at u^(n&15)
    {
        const float* ub = up + (size_t)b * Cd * Nn + n0;
#pragma unroll
        for (int it = 0; it < 16; ++it) {
            int i = it * 512 + t;              // 8192 float4 units: 512c x 16 n-groups
            int c = i >> 4, n4 = (i & 15) * 4;
            float4 v = *(const float4*)(ub + (size_t)c * Nn + n4);
            int cu = c >> 3, ce = (c & 7) * 2;
            float vv[4] = {v.x, v.y, v.z, v.w};
#pragma unroll
            for (int j = 0; j < 4; ++j) {
                int n = n4 + j;
                *(unsigned short*)(Lq + ((n * 64 + (cu ^ (n & 15))) << 4) + ce) = f2b(vv[j]);
            }
        }
    }
    __syncthreads();

    // ---- (2) Q + skip prologue: wave w owns o = w*64 .. w*64+63 ----
    {
        v4f aq[4][4], ask[4][4];
#pragma unroll
        for (int oi = 0; oi < 4; ++oi)
#pragma unroll
            for (int ni = 0; ni < 4; ++ni) {
                aq[oi][ni] = (v4f){0.f, 0.f, 0.f, 0.f};
                ask[oi][ni] = (v4f){0.f, 0.f, 0.f, 0.f};
            }
        const unsigned short* WqF = Wf + (size_t)l * 8;                    // Wf[0] = Wq
        const unsigned short* WsF = Wf + (size_t)3 * 262144 + (size_t)l * 8;  // Wf[3] = Wskip
        for (int step = 0; step < 16; ++step) {
            s8v a1[4], a2[4];
#pragma unroll
            for (int oi = 0; oi < 4; ++oi)
                a1[oi] = *(const s8v*)(WqF + ((size_t)((w * 4 + oi) * 16 + step) << 9));
#pragma unroll
            for (int oi = 0; oi < 4; ++oi)
                a2[oi] = *(const s8v*)(WsF + ((size_t)((w * 4 + oi) * 16 + step) << 9));
#pragma unroll
            for (int ni = 0; ni < 4; ++ni) {
                int n = ni * 16 + lq;          // n&15 == lq
                s8v bf = *(const s8v*)(Lq + ((n * 64 + ((step * 4 + quad) ^ lq)) << 4));
#pragma unroll
                for (int oi = 0; oi < 4; ++oi) {
                    aq[oi][ni] = mfma16(a1[oi], bf, aq[oi][ni]);
                    ask[oi][ni] = mfma16(a2[oi], bf, ask[oi][ni]);
                }
            }
        }
        // skip -> out (pure store; epilogue adds x on top)
#pragma unroll
        for (int oi = 0; oi < 4; ++oi)
#pragma unroll
            for (int ni = 0; ni < 4; ++ni)
#pragma unroll
                for (int r = 0; r < 4; ++r) {
                    int o = w * 64 + oi * 16 + quad * 4 + r;
                    int n = n0 + ni * 16 + lq;
                    out[((size_t)b * Cd + o) * Nn + n] = ask[oi][ni][r];
                }
        __syncthreads();   // all Xu reads complete before overwrite
        // Q -> Lq (overwrite Xu), swizzled bf16, 8B per (oi,ni)
#pragma unroll
        for (int oi = 0; oi < 4; ++oi)
#pragma unroll
            for (int ni = 0; ni < 4; ++ni) {
                int n = ni * 16 + lq;
                int cu = w * 8 + oi * 2 + (quad >> 1);
                ushort4 pk;
                pk.x = f2b(aq[oi][ni][0]); pk.y = f2b(aq[oi][ni][1]);
                pk.z = f2b(aq[oi][ni][2]); pk.w = f2b(aq[oi][ni][3]);
                *(ushort4*)(Lq + ((n * 64 + (cu ^ lq)) << 4) + (quad & 1) * 8) = pk;
            }
    }
    if (t < 64) { muS[t] = -1e30f; ssumS[t] = 0.f; }

    v16f o_acc[2][2];
#pragma unroll
    for (int nh = 0; nh < 2; ++nh)
#pragma unroll
        for (int ti = 0; ti < 2; ++ti)
#pragma unroll
            for (int r = 0; r < 16; ++r) o_acc[nh][ti][r] = 0.f;
    __syncthreads();

    const unsigned short* Kfb = Kf + (size_t)b * Mm * Cd + (size_t)l * 8;
    const unsigned short* Vfb = Vf + (size_t)b * Cd * Mm + (size_t)l * 8;
    const int q0 = lcol * 64, q1 = (lcol + 32) * 64;
    const int swz = lcol & 15;
    const float sc = 0.04419417382415922f;   // 1/sqrt(512)

    for (int m0 = 0; m0 < Mm; m0 += 256) {
        v16f st0, st1;
#pragma unroll
        for (int r = 0; r < 16; ++r) { st0[r] = 0.f; st1[r] = 0.f; }
        const unsigned short* kp = Kfb + (size_t)(((m0 >> 5) + w) * 32) * 512;
#pragma unroll
        for (int kb8 = 0; kb8 < 4; ++kb8) {
            uint4 ka[8];
#pragma unroll
            for (int j = 0; j < 8; ++j) ka[j] = *(const uint4*)(kp + (size_t)(kb8 * 8 + j) * 512);
            __builtin_amdgcn_s_setprio(1);
#pragma unroll
            for (int j = 0; j < 8; ++j) {
                int kb = kb8 * 8 + j;
                int uo = (kb * 2 + lhalf) ^ swz;
                s8v qf0 = *(const s8v*)(Lq + ((q0 + uo) << 4));
                s8v qf1 = *(const s8v*)(Lq + ((q1 + uo) << 4));
                union { uint4 u; s8v s; } av; av.u = ka[j];
                st0 = mfma32(av.s, qf0, st0);
                st1 = mfma32(av.s, qf1, st1);
            }
            __builtin_amdgcn_s_setprio(0);
        }
        uint4 v0p[8];
        {
            const unsigned short* vc = Vfb + (size_t)((w * 2) * 64 + (m0 >> 4)) * 512;
#pragma unroll
            for (int j = 0; j < 8; ++j) v0p[j] = *(const uint4*)(vc + (size_t)j * 512);
        }
#pragma unroll
        for (int r = 0; r < 16; ++r) { st0[r] *= sc; st1[r] *= sc; }
        float tm0 = st0[0], tm1 = st1[0];
#pragma unroll
        for (int r = 1; r < 16; ++r) { tm0 = fmaxf(tm0, st0[r]); tm1 = fmaxf(tm1, st1[r]); }
        tm0 = fmaxf(tm0, __shfl_xor(tm0, 32));
        tm1 = fmaxf(tm1, __shfl_xor(tm1, 32));
        if (l < 32) {
            pmaxS[l * 8 + w] = tm0;
            pmaxS[(l + 32) * 8 + w] = tm1;
        }
        __syncthreads();   // S1
        {
            int row = t >> 3, p = t & 7;
            float v = pmaxS[row * 8 + p];
            v = fmaxf(v, __shfl_xor(v, 1));
            v = fmaxf(v, __shfl_xor(v, 2));
            v = fmaxf(v, __shfl_xor(v, 4));
            if (p == 0) {
                float mold = muS[row];
                float mx = fmaxf(mold, v);
                alphaS[row] = __expf(mold - mx);
                muS[row] = mx;
            }
        }
        __syncthreads();   // S2
        {
            float mx0 = muS[lcol], mx1 = muS[lcol + 32];
            float e0[16], e1[16], rs0 = 0.f, rs1 = 0.f;
#pragma unroll
            for (int r = 0; r < 16; ++r) {
                e0[r] = __expf(st0[r] - mx0); rs0 += e0[r];
                e1[r] = __expf(st1[r] - mx1); rs1 += e1[r];
            }
            rs0 += __shfl_xor(rs0, 32);
            rs1 += __shfl_xor(rs1, 32);
            if (l < 32) {
                psumS[l * 8 + w] = rs0;
                psumS[(l + 32) * 8 + w] = rs1;
            }
#pragma unroll
            for (int rg = 0; rg < 4; ++rg) {
                ushort4 pk0, pk1;
                pk0.x = f2b(e0[rg * 4 + 0]); pk0.y = f2b(e0[rg * 4 + 1]);
                pk0.z = f2b(e0[rg * 4 + 2]); pk0.w = f2b(e0[rg * 4 + 3]);
                pk1.x = f2b(e1[rg * 4 + 0]); pk1.y = f2b(e1[rg * 4 + 1]);
                pk1.z = f2b(e1[rg * 4 + 2]); pk1.w = f2b(e1[rg * 4 + 3]);
                *(ushort4*)(Pb + lcol * 264 + w * 32 + 8 * rg + 4 * lhalf) = pk0;
                *(ushort4*)(Pb + (lcol + 32) * 264 + w * 32 + 8 * rg + 4 * lhalf) = pk1;
            }
        }
        __syncthreads();   // S3
        {
            int row = t >> 3, p = t & 7;
            float v = psumS[row * 8 + p];
            v += __shfl_xor(v, 1);
            v += __shfl_xor(v, 2);
            v += __shfl_xor(v, 4);
            if (p == 0) ssumS[row] = ssumS[row] * alphaS[row] + v;
        }

        float ar0[16], ar1[16];
#pragma unroll
        for (int r = 0; r < 16; ++r) {
            int crow = (r & 3) + 8 * (r >> 2) + 4 * lhalf;
            ar0[r] = alphaS[crow];
            ar1[r] = alphaS[32 + crow];
        }
#pragma unroll
        for (int ti = 0; ti < 2; ++ti)
#pragma unroll
            for (int r = 0; r < 16; ++r) {
                o_acc[0][ti][r] *= ar0[r];
                o_acc[1][ti][r] *= ar1[r];
            }

#pragma unroll
        for (int h = 0; h < 2; ++h) {
            s8v pA0[8], pA1[8];
#pragma unroll
            for (int j = 0; j < 8; ++j) {
                pA0[j] = *(const s8v*)(Pb + lcol * 264 + (h * 8 + j) * 16 + lhalf * 8);
                pA1[j] = *(const s8v*)(Pb + (lcol + 32) * 264 + (h * 8 + j) * 16 + lhalf * 8);
            }
#pragma unroll
            for (int ti = 0; ti < 2; ++ti) {
                uint4 vb[8];
                if (h == 0 && ti == 0) {
#pragma unroll
                    for (int j = 0; j < 8; ++j) vb[j] = v0p[j];
                } else {
                    const unsigned short* vc = Vfb + (size_t)((w * 2 + ti) * 64 + (m0 >> 4) + h * 8) * 512;
#pragma unroll
                    for (int j = 0; j < 8; ++j) vb[j] = *(const uint4*)(vc + (size_t)j * 512);
                }
                __builtin_amdgcn_s_setprio(1);
#pragma unroll
                for (int j = 0; j < 8; ++j) {
                    union { uint4 u; s8v s; } bv; bv.u = vb[j];
                    o_acc[0][ti] = mfma32(pA0[j], bv.s, o_acc[0][ti]);
                    o_acc[1][ti] = mfma32(pA1[j], bv.s, o_acc[1][ti]);
                }
                __builtin_amdgcn_s_setprio(0);
            }
        }
        __syncthreads();
    }

    // ---- epilogue: out[b][c][n0..n0+63] += O / l (RMW over prologue skip) ----
    float inv0[16], inv1[16];
#pragma unroll
    for (int r = 0; r < 16; ++r) {
        int crow = (r & 3) + 8 * (r >> 2) + 4 * lhalf;
        inv0[r] = 1.0f / ssumS[crow];
        inv1[r] = 1.0f / ssumS[32 + crow];
    }
    float* OtW = OtA + w * 32 * 36;
#pragma unroll
    for (int nh = 0; nh < 2; ++nh)
#pragma unroll
        for (int ti = 0; ti < 2; ++ti) {
#pragma unroll
            for (int r = 0; r < 16; ++r) {
                int crow = (r & 3) + 8 * (r >> 2) + 4 * lhalf;
                OtW[lcol * 36 + crow] = o_acc[nh][ti][r] * (nh ? inv1[r] : inv0[r]);
            }
            int cloc = l >> 1, half = l & 1;
            int cabs = (w * 2 + ti) * 32 + cloc;
            const float* src = OtW + cloc * 36 + half * 16;
            float* op = out + ((size_t)b * Cd + cabs) * Nn + n0 + nh * 32 + half * 16;
#pragma unroll
            for (int j = 0; j < 4; ++j) {
                float4 a = *(const float4*)(src + j * 4);
                float4 g = *(const float4*)(op + j * 4);
                g.x += a.x; g.y += a.y; g.z += a.z; g.w += a.w;
                *(float4*)(op + j * 4) = g;
            }
        }
}

// ---------------------------------------------------------------------------
// Fallback VALU attention (proven) for small ws_size.
// ---------------------------------------------------------------------------
__device__ __forceinline__ float u2lo(unsigned int u) {
    union { unsigned int i; float f; } v; v.i = u << 16; return v.f;
}
__device__ __forceinline__ float u2hi(unsigned int u) {
    union { unsigned int i; float f; } v; v.i = u & 0xFFFF0000u; return v.f;
}

__global__ __launch_bounds__(256) void attn_k(const float* __restrict__ up,
                                              const float* __restrict__ Wq,
                                              const unsigned short* __restrict__ Ktb,
                                              const unsigned short* __restrict__ Vtb,
                                              float* __restrict__ out) {
    __shared__ float Qs[16][516];
    __shared__ __align__(16) unsigned char Sraw[24576];
    unsigned short (*Us)[16]  = reinterpret_cast<unsigned short(*)[16]>(Sraw);
    unsigned short (*Wt)[512] = reinterpret_cast<unsigned short(*)[512]>(Sraw + 16384);
    float (*Ps)[65] = reinterpret_cast<float(*)[65]>(Sraw);
    float* mu_s     = reinterpret_cast<float*>(Sraw + 4160);
    float* ssum_s   = reinterpret_cast<float*>(Sraw + 4224);
    float* alpha_s  = reinterpret_cast<float*>(Sraw + 4288);

    const int t = threadIdx.x;
    const int b = blockIdx.y;
    const int n0 = blockIdx.x * 16;
    const int row = t & 15;
    const int grp = t >> 4;

    for (int i = t; i < Cd * 16; i += 256) {
        int c = i >> 4, r = i & 15;
        Us[c][r] = f2b(up[((size_t)b * Cd + c) * Nn + n0 + r]);
    }
    __syncthreads();

    float acc[32];
#pragma unroll
    for (int j = 0; j < 32; ++j) acc[j] = 0.f;

    for (int k0 = 0; k0 < Cd; k0 += 8) {
        for (int i = t; i < 1024; i += 256) {
            int oc = i >> 1;
            int kc = (i & 1) * 4;
            float4 wv = *(const float4*)(Wq + (size_t)oc * Cd + k0 + kc);
            Wt[kc + 0][oc] = f2b(wv.x); Wt[kc + 1][oc] = f2b(wv.y);
            Wt[kc + 2][oc] = f2b(wv.z); Wt[kc + 3][oc] = f2b(wv.w);
        }
        __syncthreads();
#pragma unroll
        for (int k = 0; k < 8; ++k) {
            float u = b2f(Us[k0 + k][row]);
            const ushort4* wr = (const ushort4*)(&Wt[k][grp * 32]);
#pragma unroll
            for (int j4 = 0; j4 < 8; ++j4) {
                ushort4 wv = wr[j4];
                acc[j4 * 4 + 0] += u * b2f(wv.x);
                acc[j4 * 4 + 1] += u * b2f(wv.y);
                acc[j4 * 4 + 2] += u * b2f(wv.z);
                acc[j4 * 4 + 3] += u * b2f(wv.w);
            }
        }
        __syncthreads();
    }

    const float scale = 0.04419417382415922f;
#pragma unroll
    for (int j = 0; j < 32; ++j) Qs[row][grp * 32 + j] = acc[j] * scale;
    if (t < 16) { mu_s[t] = -1e30f; ssum_s[t] = 0.f; }
#pragma unroll
    for (int j = 0; j < 32; ++j) acc[j] = 0.f;
    __syncthreads();

    const float4* qr = (const float4*)(&Qs[row][0]);

    for (int m0 = 0; m0 < Mm; m0 += 64) {
        {
            int mb = m0 + grp * 4;
            const uint4* K0 = (const uint4*)(Ktb + ((size_t)b * Mm + mb + 0) * Cd);
            const uint4* K1 = (const uint4*)(Ktb + ((size_t)b * Mm + mb + 1) * Cd);
            const uint4* K2 = (const uint4*)(Ktb + ((size_t)b * Mm + mb + 2) * Cd);
            const uint4* K3 = (const uint4*)(Ktb + ((size_t)b * Mm + mb + 3) * Cd);
            float a0 = 0.f, a1 = 0.f, a2 = 0.f, a3 = 0.f;
#pragma unroll 4
            for (int c8 = 0; c8 < Cd / 8; ++c8) {
                float4 qa = qr[2 * c8], qb = qr[2 * c8 + 1];
                uint4 k0v = K0[c8], k1v = K1[c8], k2v = K2[c8], k3v = K3[c8];
                a0 += qa.x * u2lo(k0v.x) + qa.y * u2hi(k0v.x) + qa.z * u2lo(k0v.y) + qa.w * u2hi(k0v.y)
                    + qb.x * u2lo(k0v.z) + qb.y * u2hi(k0v.z) + qb.z * u2lo(k0v.w) + qb.w * u2hi(k0v.w);
                a1 += qa.x * u2lo(k1v.x) + qa.y * u2hi(k1v.x) + qa.z * u2lo(k1v.y) + qa.w * u2hi(k1v.y)
                    + qb.x * u2lo(k1v.z) + qb.y * u2hi(k1v.z) + qb.z * u2lo(k1v.w) + qb.w * u2hi(k1v.w);
                a2 += qa.x * u2lo(k2v.x) + qa.y * u2hi(k2v.x) + qa.z * u2lo(k2v.y) + qa.w * u2hi(k2v.y)
                    + qb.x * u2lo(k2v.z) + qb.y * u2hi(k2v.z) + qb.z * u2lo(k2v.w) + qb.w * u2hi(k2v.w);
                a3 += qa.x * u2lo(k3v.x) + qa.y * u2hi(k3v.x) + qa.z * u2lo(k3v.y) + qa.w * u2hi(k3v.y)
                    + qb.x * u2lo(k3v.z) + qb.y * u2hi(k3v.z) + qb.z * u2lo(k3v.w) + qb.w * u2hi(k3v.w);
            }
            Ps[row][grp * 4 + 0] = a0;
            Ps[row][grp * 4 + 1] = a1;
            Ps[row][grp * 4 + 2] = a2;
            Ps[row][grp * 4 + 3] = a3;
        }
        __syncthreads();
        if (t < 16) {
            float mold = mu_s[t];
            float mx = mold;
            for (int m = 0; m < 64; ++m) mx = fmaxf(mx, Ps[t][m]);
            float al = __expf(mold - mx);
            float s = ssum_s[t] * al;
            for (int m = 0; m < 64; ++m) {
                float p = __expf(Ps[t][m] - mx);
                Ps[t][m] = p;
                s += p;
            }
            mu_s[t] = mx; ssum_s[t] = s; alpha_s[t] = al;
        }
        __syncthreads();
        {
            float arr = alpha_s[row];
#pragma unroll
            for (int j = 0; j < 32; ++j) acc[j] *= arr;
            const unsigned short* Vbase = Vtb + (size_t)b * Mm * Cd + (size_t)grp * 32;
            for (int m = 0; m < 64; ++m) {
                float p = Ps[row][m];
                const uint4* vr = (const uint4*)(Vbase + (size_t)(m0 + m) * Cd);
#pragma unroll
                for (int j4 = 0; j4 < 4; ++j4) {
                    uint4 v = vr[j4];
                    acc[j4 * 8 + 0] += p * u2lo(v.x); acc[j4 * 8 + 1] += p * u2hi(v.x);
                    acc[j4 * 8 + 2] += p * u2lo(v.y); acc[j4 * 8 + 3] += p * u2hi(v.y);
                    acc[j4 * 8 + 4] += p * u2lo(v.z); acc[j4 * 8 + 5] += p * u2hi(v.z);
                    acc[j4 * 8 + 6] += p * u2lo(v.w); acc[j4 * 8 + 7] += p * u2hi(v.w);
                }
            }
        }
        __syncthreads();
    }

    float invv = 1.0f / ssum_s[row];
#pragma unroll
    for (int j = 0; j < 32; ++j) {
        int c = grp * 32 + j;
        size_t idx = ((size_t)b * Cd + c) * Nn + n0 + row;
        out[idx] = out[idx] + acc[j] * invv;
    }
}

// ---------------------------------------------------------------------------
extern "C" void kernel_launch(void* const* d_in, const int* in_sizes, int n_in,
                              void* d_out, int out_size, void* d_ws, size_t ws_size,
                              hipStream_t stream) {
    const float* up   = (const float*)d_in[0];
    const float* down = (const float*)d_in[1];
    const float* Wq   = (const float*)d_in[2];
    const float* Wk   = (const float*)d_in[3];
    const float* Wv   = (const float*)d_in[4];
    const float* Wsk  = (const float*)d_in[5];
    float* out = (float*)d_out;

    const size_t szK = (size_t)Bn * Mm * Cd;   // 4M bf16 elems (8 MiB)
    const size_t szW = (size_t)4 * Cd * Cd;    // 1M elems (2 MiB)

    if (ws_size >= (2 * szK + szW) * 2) {
        // 18 MiB path: [XK: Xtd->Kf 8MiB][Vf 8MiB][Wf 2MiB].
        // convwf -> convx(down) -> gemm4<0> (K/V) -> attn_f (Q+skip+attention).
        unsigned short* XK = (unsigned short*)d_ws;
        unsigned short* Vf = XK + szK;
        unsigned short* Wf = Vf + szK;
        convwf<<<dim3(32, 4), 256, 0, stream>>>(Wq, Wk, Wv, Wsk, Wf);
        convx<<<dim3(Mm / 64, Cd / 64, Bn), 256, 0, stream>>>(down, XK, Mm);
        gemm4<0><<<dim3(Bn * (Mm / 32)), 256, 0, stream>>>(Wf, XK, Vf, nullptr, Mm);
        attn_f<<<dim3((Nn / 64) * Bn), 512, 0, stream>>>(up, Wf, XK, Vf, out);
    } else {
        // Fallback (16 MiB ws): VALU attention.
        unsigned short* Ktb = (unsigned short*)d_ws;
        unsigned short* Vtb = Ktb + szK;
        gemm_mfma<2><<<dim3(Mm / 64, Cd / 64, Bn), 256, 0, stream>>>(Wk, down, nullptr, Ktb, Mm);
        gemm_mfma<2><<<dim3(Mm / 64, Cd / 64, Bn), 256, 0, stream>>>(Wv, down, nullptr, Vtb, Mm);
        gemm_mfma<0><<<dim3(Nn / 64, Cd / 64, Bn), 256, 0, stream>>>(Wsk, up, out, nullptr, Nn);
        attn_k<<<dim3(Nn / 16, Bn), 256, 0, stream>>>(up, Wq, Ktb, Vtb, out);
    }
}